// Round 8
// baseline (504.800 us; speedup 1.0000x reference)
//
#include <hip/hip_runtime.h>
#include <math.h>

// StrategistGNN forward on MI355X. Round 8: prefetch-pipelined flash attention
// (launch_bounds(256,4) frees VGPRs), fused attn epilogue (comb+proj+LN in one).
// N=4096 nodes, E=65536 edges, H=128, 4 heads x 32, L=4 GAT layers, B=1.

#define NN 4096
#define EE 65536
#define HH 128
#define NHEADS 4
#define HDIM 32
#define NLAYERS 4
#define NFEAT 16
#define GFEAT 8
#define EFEAT 4
#define KS 4     // key-splits for global attention
#define KPAD 296 // padded K stride (bf16) for edge-head GEMM
#define XSTR 136 // LDS row stride (bf16): 2-way bank aliasing only (free)

typedef short bf16x8 __attribute__((ext_vector_type(8)));
typedef float f32x4  __attribute__((ext_vector_type(4)));
union UB { uint4 u; bf16x8 v; };

__device__ __forceinline__ float gelu_f(float x){
  return 0.5f * x * (1.0f + erff(x * 0.7071067811865475f));
}
__device__ __forceinline__ float gelu_fast(float x){
  float u = 0.7978845608f * (x + 0.044715f * x * x * x);
  float t = __expf(-2.0f * fmaxf(u, -40.0f));
  float th = 1.0f - 2.0f * t / (1.0f + t);
  return 0.5f * x * (1.0f + th);
}
__device__ __forceinline__ float sigm_fast(float x){ return 1.0f / (1.0f + __expf(-x)); }
__device__ __forceinline__ float tanh_fast(float x){
  float t = __expf(-2.0f * fmaxf(x, -40.0f));
  return 1.0f - 2.0f * t / (1.0f + t);
}
__device__ __forceinline__ float softplus_f(float x){ return x > 20.0f ? x : log1pf(expf(x)); }
__device__ __forceinline__ unsigned short f2bf(float x){
  unsigned u = __float_as_uint(x);
  unsigned r = (u + 0x7FFFu + ((u >> 16) & 1u)) >> 16;
  return (unsigned short)r;
}
__device__ __forceinline__ unsigned pack2bf(float lo, float hi){
  unsigned a = (__float_as_uint(lo) + 0x8000u) >> 16;
  unsigned b = (__float_as_uint(hi) + 0x8000u) & 0xFFFF0000u;
  return a | b;
}

__device__ __forceinline__ float block_sum128(float v, float* red){
  int j = threadIdx.x;
  red[j] = v; __syncthreads();
  for (int s = 64; s > 0; s >>= 1){
    if (j < s) red[j] += red[j + s];
    __syncthreads();
  }
  float r = red[0];
  __syncthreads();
  return r;
}

// ---------------- CSR build ----------------
__global__ void k_hist(const int* __restrict__ ei, int* __restrict__ cnt){
  int e = blockIdx.x * 256 + threadIdx.x;
  if (e < EE) atomicAdd(&cnt[ei[EE + e]], 1);
}

__global__ void k_scan(const int* __restrict__ cnt, int* __restrict__ off, int* __restrict__ cur){
  __shared__ int part[256];
  int t = threadIdx.x;
  int local[16];
  int s = 0;
  #pragma unroll
  for (int i = 0; i < 16; i++){ local[i] = s; s += cnt[t * 16 + i]; }
  part[t] = s; __syncthreads();
  for (int o = 1; o < 256; o <<= 1){
    int v = (t >= o) ? part[t - o] : 0;
    __syncthreads();
    part[t] += v;
    __syncthreads();
  }
  int base = part[t] - s;
  #pragma unroll
  for (int i = 0; i < 16; i++){ int o = base + local[i]; off[t * 16 + i] = o; cur[t * 16 + i] = o; }
  if (t == 255) off[NN] = part[255];
}

__global__ void k_scatter(const int* __restrict__ ei, int* __restrict__ cur, int* __restrict__ eid){
  int e = blockIdx.x * 256 + threadIdx.x;
  if (e < EE){
    int d = ei[EE + e];
    int p = atomicAdd(&cur[d], 1);
    eid[p] = e;
  }
}

// ---------------- one-shot prep ----------------
__global__ void k_wprep(const float* __restrict__ Wih, const float* __restrict__ Whh,
                        const float* __restrict__ Wl, const float* __restrict__ Wr,
                        const float* __restrict__ Win, const float* __restrict__ Wout,
                        const float* __restrict__ tiles,
                        const float* __restrict__ bl, const float* __restrict__ br,
                        const float* __restrict__ ea,
                        const float* __restrict__ mvW1, const float* __restrict__ frW1,
                        unsigned short* __restrict__ wbuf, unsigned short* __restrict__ tilesb,
                        float* __restrict__ blrc,
                        unsigned short* __restrict__ wbE, unsigned short* __restrict__ eab,
                        int* __restrict__ cnt, float* __restrict__ gsum){
  int i = blockIdx.x * 256 + threadIdx.x;
  if (i < 49152){ wbuf[i] = f2bf(Wih[i]); }
  else if (i < 98304){ int j = i - 49152; wbuf[49152 + j] = f2bf(Whh[j]); }
  else if (i < 229376){
    int j = i - 98304;
    int l = j >> 15, rem = j & 32767, m = rem >> 7, k = rem & 127;
    float v = (m < 128) ? Wl[l * 16384 + m * 128 + k] : Wr[l * 16384 + (m - 128) * 128 + k];
    wbuf[98304 + j] = f2bf(v);
  }
  else if (i < 278528){ int j = i - 229376; wbuf[229376 + j] = f2bf(Win[j]); }
  else if (i < 294912){ int j = i - 278528; wbuf[278528 + j] = f2bf(Wout[j]); }
  else if (i < 819200){ int j = i - 294912; tilesb[j] = f2bf(tiles[j]); }
  else if (i < 820224){
    int j = i - 819200;
    int l = j >> 8, m = j & 255;
    blrc[j] = (m < 128) ? bl[l * 128 + m] : br[l * 128 + m - 128];
  }
  else if (i < 896000){
    int j = i - 820224;
    int n = j / KPAD, k = j - n * KPAD;
    float v = 0.0f;
    if (k < 2 * HH + EFEAT) v = (n < HH) ? mvW1[n * (2 * HH + EFEAT) + k]
                                         : frW1[(n - HH) * (2 * HH + EFEAT) + k];
    wbE[j] = f2bf(v);
  }
  else if (i < 1158144){
    int j = i - 896000;
    eab[j] = f2bf(ea[j]);
  }
  else if (i < 1162240){ cnt[i - 1158144] = 0; }
  else if (i < 1162497){ gsum[i - 1162240] = 0.0f; }
}

// ---------------- generic MFMA projection ----------------
template<int MTOT>
__global__ __launch_bounds__(256) void k_lin(const unsigned short* __restrict__ Xb,
                                             const unsigned short* __restrict__ Wb,
                                             const float* __restrict__ bias,
                                             float* __restrict__ Y){
  __shared__ __align__(16) unsigned short Xs[64 * XSTR];
  int t = threadIdx.x;
  int n0 = blockIdx.x * 64;
  int m0 = blockIdx.y * 128;
  #pragma unroll
  for (int k2 = 0; k2 < 4; k2++){
    int v = t + k2 * 256;
    int r = v >> 4, c8 = v & 15;
    *(uint4*)(Xs + r * XSTR + c8 * 8) = *(const uint4*)(Xb + (n0 + r) * 128 + c8 * 8);
  }
  __syncthreads();
  int ln = t & 63, w = t >> 6, lm = ln & 15, quad = ln >> 4;
  const unsigned short* abase = Xs + (16 * w + lm) * XSTR + quad * 8;
  const unsigned short* bbase = Wb + (m0 + lm) * 128 + quad * 8;
  UB af[4];
  #pragma unroll
  for (int ks = 0; ks < 4; ks++) af[ks].u = *(const uint4*)(abase + ks * 32);
  f32x4 acc[8];
  #pragma unroll
  for (int i = 0; i < 8; i++) acc[i] = (f32x4){0.f, 0.f, 0.f, 0.f};
  #pragma unroll
  for (int t2 = 0; t2 < 8; t2++){
    #pragma unroll
    for (int ks = 0; ks < 4; ks++){
      UB bu;
      bu.u = *(const uint4*)(bbase + t2 * 16 * 128 + ks * 32);
      acc[t2] = __builtin_amdgcn_mfma_f32_16x16x32_bf16(af[ks].v, bu.v, acc[t2], 0, 0, 0);
    }
  }
  #pragma unroll
  for (int t2 = 0; t2 < 8; t2++){
    float bv = bias[m0 + t2 * 16 + lm];
    #pragma unroll
    for (int r = 0; r < 4; r++){
      Y[(n0 + 16 * w + quad * 4 + r) * MTOT + m0 + t2 * 16 + lm] = acc[t2][r] + bv;
    }
  }
}

// ---------------- encoders ----------------
__global__ void k_ue(const float* __restrict__ u, const float* __restrict__ W,
                     const float* __restrict__ b, const float* __restrict__ g,
                     const float* __restrict__ be, float* __restrict__ ue){
  __shared__ float red[128];
  __shared__ float us[GFEAT];
  int j = threadIdx.x;
  if (j < GFEAT) us[j] = u[j];
  __syncthreads();
  float acc = b[j];
  #pragma unroll
  for (int k = 0; k < GFEAT; k++) acc += us[k] * W[j * GFEAT + k];
  float mu = block_sum128(acc, red) * (1.0f / HH);
  float d = acc - mu;
  float var = block_sum128(d * d, red) * (1.0f / HH);
  ue[j] = gelu_f(d * rsqrtf(var + 1e-5f) * g[j] + be[j]);
}

__global__ void k_node_enc(const float* __restrict__ x, const float* __restrict__ tf,
                           const float* __restrict__ W, const float* __restrict__ b,
                           const float* __restrict__ g, const float* __restrict__ be,
                           const float* __restrict__ ue, float* __restrict__ h,
                           unsigned short* __restrict__ hb){
  __shared__ float red[128];
  __shared__ float xs[NFEAT + 1];
  int n = blockIdx.x, j = threadIdx.x;
  if (j < NFEAT) xs[j] = x[n * NFEAT + j];
  if (j == NFEAT) xs[NFEAT] = tf[0];
  __syncthreads();
  float acc = b[j];
  #pragma unroll
  for (int k = 0; k < NFEAT + 1; k++) acc += xs[k] * W[j * (NFEAT + 1) + k];
  float mu = block_sum128(acc, red) * (1.0f / HH);
  float d = acc - mu;
  float var = block_sum128(d * d, red) * (1.0f / HH);
  float r = gelu_f(d * rsqrtf(var + 1e-5f) * g[j] + be[j]) + ue[j];
  h[n * HH + j] = r;
  hb[n * HH + j] = f2bf(r);
}

// ---------------- GRU combine ----------------
__global__ void k_gru_comb(const float* __restrict__ gi, const float* __restrict__ gh,
                           const float* __restrict__ tiles, float* __restrict__ h,
                           unsigned short* __restrict__ hb, float* __restrict__ out_tiles){
  int idx = blockIdx.x * 256 + threadIdx.x;
  int n = idx >> 7, j = idx & 127;
  float ir = gi[n * 384 + j], iz = gi[n * 384 + 128 + j], inn = gi[n * 384 + 256 + j];
  float hr = gh[n * 384 + j], hz = gh[n * 384 + 128 + j], hn = gh[n * 384 + 256 + j];
  float r = sigm_fast(ir + hr), z = sigm_fast(iz + hz);
  float nn2 = tanh_fast(inn + r * hn);
  float ts = tiles[idx];
  float hnew = (1.0f - z) * nn2 + z * ts;
  h[idx] = hnew;
  hb[idx] = f2bf(hnew);
  out_tiles[idx] = hnew;
}

// ---------------- GAT score ----------------
__global__ __launch_bounds__(256) void k_score(const int* __restrict__ ei, const float* __restrict__ ea,
                        const float* __restrict__ xlr,
                        const float* __restrict__ We, const float* __restrict__ att,
                        float* __restrict__ ex){
  __shared__ float4 We4[128];
  __shared__ float atts[128];
  int t = threadIdx.x;
  if (t < 128){ We4[t] = ((const float4*)We)[t]; atts[t] = att[t]; }
  __syncthreads();
  int el = t >> 4, g = t & 15;
  int e = blockIdx.x * 16 + el;
  int s = ei[e], d = ei[EE + e];
  float4 a = *(const float4*)(ea + e * 4);
  float xls[8], xrs[8];
  *(float4*)(xls)     = *(const float4*)(xlr + s * 256 + g * 8);
  *(float4*)(xls + 4) = *(const float4*)(xlr + s * 256 + g * 8 + 4);
  *(float4*)(xrs)     = *(const float4*)(xlr + d * 256 + 128 + g * 8);
  *(float4*)(xrs + 4) = *(const float4*)(xlr + d * 256 + 128 + g * 8 + 4);
  float sc = 0.0f;
  #pragma unroll
  for (int i = 0; i < 8; i++){
    int j = g * 8 + i;
    float4 w = We4[j];
    float v = xls[i] + xrs[i] + a.x * w.x + a.y * w.y + a.z * w.z + a.w * w.w;
    v = v > 0.0f ? v : 0.2f * v;
    sc += v * atts[j];
  }
  sc += __shfl_xor(sc, 1);
  sc += __shfl_xor(sc, 2);
  if ((g & 3) == 0) ex[e * 4 + (g >> 2)] = __expf(sc);
}

// ---------------- aggregate + residual + LN ----------------
__global__ void k_aggln(const float* __restrict__ xlr, const float* __restrict__ ex,
                        const int* __restrict__ off, const int* __restrict__ eid,
                        const int* __restrict__ ei,
                        const float* __restrict__ bias, const float* __restrict__ g,
                        const float* __restrict__ b, float* __restrict__ h,
                        unsigned short* __restrict__ hb){
  __shared__ float red[128];
  __shared__ float den[NHEADS];
  int n = blockIdx.x, j = threadIdx.x;
  int p0 = off[n], p1 = off[n + 1];
  {
    int hh4 = j & 3, es = j >> 2;
    float s = 0.0f;
    for (int p = p0 + es; p < p1; p += 32) s += ex[eid[p] * 4 + hh4];
    red[j] = s; __syncthreads();
    #pragma unroll
    for (int st = 16; st > 0; st >>= 1){
      if (es < st) red[j] += red[j + st * 4];
      __syncthreads();
    }
    if (j < 4) den[j] = red[j];
    __syncthreads();
  }
  int hh = j >> 5;
  float dinv = 1.0f / (den[hh] + 1e-16f);
  float agg = 0.0f;
  int p = p0;
  for (; p + 2 <= p1; p += 2){
    int e0 = eid[p], e1 = eid[p + 1];
    int s0 = ei[e0], s1 = ei[e1];
    float w0 = ex[e0 * 4 + hh], w1 = ex[e1 * 4 + hh];
    float x0 = xlr[s0 * 256 + j], x1 = xlr[s1 * 256 + j];
    agg += w0 * x0 + w1 * x1;
  }
  if (p < p1){ int e2 = eid[p]; agg += ex[e2 * 4 + hh] * xlr[ei[e2] * 256 + j]; }
  agg *= dinv;
  float val = h[n * HH + j] + agg + bias[j];
  float mu = block_sum128(val, red) * (1.0f / HH);
  float d2 = val - mu;
  float var = block_sum128(d2 * d2, red) * (1.0f / HH);
  float r = d2 * rsqrtf(var + 1e-5f) * g[j] + b[j];
  h[n * HH + j] = r;
  hb[n * HH + j] = f2bf(r);
}

// ---------------- global attention ----------------
__global__ __launch_bounds__(256) void k_qkv_post(const float* __restrict__ qkvf,
                                                  unsigned short* __restrict__ qb,
                                                  unsigned short* __restrict__ kb,
                                                  unsigned short* __restrict__ vt){
  __shared__ unsigned short Vls[128 * 66];
  int t = threadIdx.x;
  int n0 = blockIdx.x * 64;
  const float scale = 0.17677669529663687f;
  for (int idx = t; idx < 64 * 384; idx += 256){
    int nl = idx / 384, col = idx - nl * 384;
    float fv = qkvf[(n0 + nl) * 384 + col];
    if (col < 128) qb[(n0 + nl) * 128 + col] = f2bf(fv);
    else if (col < 256) kb[(n0 + nl) * 128 + col - 128] = f2bf(fv * scale);
    else Vls[(col - 256) * 66 + nl] = f2bf(fv);
  }
  __syncthreads();
  for (int idx = t; idx < 128 * 64; idx += 256){
    int j = idx >> 6, nl = idx & 63;
    vt[j * NN + n0 + nl] = Vls[j * 66 + nl];
  }
}

struct KVFrag { UB k0f, k1f, v0f, v1f; };

// prefetch-pipelined LDS-free flash attention partial.
__global__ __launch_bounds__(256, 4) void k_attn_flash(
    const unsigned short* __restrict__ qb, const unsigned short* __restrict__ kb,
    const unsigned short* __restrict__ vt,
    float* __restrict__ pden, float* __restrict__ pacc){
  int t = threadIdx.x, w = t >> 6, ln = t & 63;
  int c = ln & 15, qd = ln >> 4;
  int hh = blockIdx.y, ks = blockIdx.z;
  int q0 = blockIdx.x * 64 + w * 16;
  UB qf; qf.u = *(const uint4*)(qb + (q0 + c) * HH + hh * HDIM + qd * 8);
  f32x4 o0a = {0,0,0,0}, o1a = {0,0,0,0}, o0b = {0,0,0,0}, o1b = {0,0,0,0};
  float denp = 0.f;
  const unsigned short* vrow0 = vt + (hh * HDIM + c) * NN;
  const unsigned short* vrow1 = vt + (hh * HDIM + 16 + c) * NN;
  const unsigned short* kcol = kb + c * HH + hh * HDIM + qd * 8;
  int srcA = c + ((qd & 1) << 5);
  int srcB = srcA + 16;
  bool hi = qd >= 2;

  auto loadf = [&](int k0, KVFrag& f){
    f.k0f.u = *(const uint4*)(kcol + k0 * HH);
    f.k1f.u = *(const uint4*)(kcol + (k0 + 16) * HH);
    f.v0f.u = *(const uint4*)(vrow0 + k0 + qd * 8);
    f.v1f.u = *(const uint4*)(vrow1 + k0 + qd * 8);
  };
  auto comp = [&](const KVFrag& f, f32x4& O0, f32x4& O1){
    f32x4 s0 = {0,0,0,0}, s1 = {0,0,0,0};
    s0 = __builtin_amdgcn_mfma_f32_16x16x32_bf16(f.k0f.v, qf.v, s0, 0, 0, 0);
    s1 = __builtin_amdgcn_mfma_f32_16x16x32_bf16(f.k1f.v, qf.v, s1, 0, 0, 0);
    float e00 = __expf(s0[0]), e01 = __expf(s0[1]), e02 = __expf(s0[2]), e03 = __expf(s0[3]);
    float e10 = __expf(s1[0]), e11 = __expf(s1[1]), e12 = __expf(s1[2]), e13 = __expf(s1[3]);
    denp += (e00 + e01) + (e02 + e03) + (e10 + e11) + (e12 + e13);
    int p00 = (int)pack2bf(e00, e01), p01 = (int)pack2bf(e02, e03);
    int p10 = (int)pack2bf(e10, e11), p11 = (int)pack2bf(e12, e13);
    int a00 = __shfl(p00, srcA), a01 = __shfl(p01, srcA);
    int b00 = __shfl(p00, srcB), b01 = __shfl(p01, srcB);
    int a10 = __shfl(p10, srcA), a11 = __shfl(p11, srcA);
    int b10 = __shfl(p10, srcB), b11 = __shfl(p11, srcB);
    UB pt;
    pt.u.x = (unsigned)(hi ? a10 : a00);
    pt.u.y = (unsigned)(hi ? a11 : a01);
    pt.u.z = (unsigned)(hi ? b10 : b00);
    pt.u.w = (unsigned)(hi ? b11 : b01);
    O0 = __builtin_amdgcn_mfma_f32_16x16x32_bf16(f.v0f.v, pt.v, O0, 0, 0, 0);
    O1 = __builtin_amdgcn_mfma_f32_16x16x32_bf16(f.v1f.v, pt.v, O1, 0, 0, 0);
  };

  const int kbeg = ks * (NN / KS);
  const int NIT = (NN / KS) / 64;   // 16
  KVFrag A, B, nA, nB;
  loadf(kbeg, A);
  loadf(kbeg + 32, B);
  for (int it = 0; it < NIT - 1; it++){
    int kn = kbeg + (it + 1) * 64;
    loadf(kn, nA);          // issue next-iter loads before current compute
    loadf(kn + 32, nB);
    comp(A, o0a, o1a);
    comp(B, o0b, o1b);
    A = nA; B = nB;
  }
  comp(A, o0a, o1a);
  comp(B, o0b, o1b);

  f32x4 o0 = o0a + o0b, o1 = o1a + o1b;
  denp += __shfl_xor(denp, 16);
  denp += __shfl_xor(denp, 32);
  int pi = ((q0 + c) * NHEADS + hh) * KS + ks;
  if (qd == 0) pden[pi] = denp;
  #pragma unroll
  for (int r = 0; r < 4; r++){
    pacc[pi * HDIM + qd * 4 + r]      = o0[r];
    pacc[pi * HDIM + 16 + qd * 4 + r] = o1[r];
  }
}

// fused: combine key-split partials -> A-tile in LDS -> MFMA proj (Wout) -> +bout
// -> residual + LN (in-register shfl row-reduce) -> h, hb
__global__ __launch_bounds__(256) void k_attn_out(
    const float* __restrict__ pden, const float* __restrict__ pacc,
    const unsigned short* __restrict__ Wb, const float* __restrict__ bout,
    const float* __restrict__ g, const float* __restrict__ b,
    float* __restrict__ h, unsigned short* __restrict__ hb){
  __shared__ __align__(16) unsigned short Xs[64 * XSTR];
  int t = threadIdx.x;
  int n0 = blockIdx.x * 64;
  for (int idx = t; idx < 64 * 128; idx += 256){
    int r = idx >> 7, j = idx & 127;
    int n = n0 + r, hh = j >> 5, d = j & 31;
    float ds = 0.f, as = 0.f;
    #pragma unroll
    for (int ks2 = 0; ks2 < KS; ks2++){
      int pi = (n * NHEADS + hh) * KS + ks2;
      ds += pden[pi];
      as += pacc[pi * HDIM + d];
    }
    Xs[r * XSTR + j] = f2bf(as / ds);
  }
  __syncthreads();
  int ln = t & 63, w = t >> 6, lm = ln & 15, quad = ln >> 4;
  const unsigned short* abase = Xs + (16 * w + lm) * XSTR + quad * 8;
  const unsigned short* bbase = Wb + lm * 128 + quad * 8;
  UB af[4];
  #pragma unroll
  for (int ks2 = 0; ks2 < 4; ks2++) af[ks2].u = *(const uint4*)(abase + ks2 * 32);
  f32x4 acc[8];
  #pragma unroll
  for (int i = 0; i < 8; i++) acc[i] = (f32x4){0.f, 0.f, 0.f, 0.f};
  #pragma unroll
  for (int t2 = 0; t2 < 8; t2++){
    #pragma unroll
    for (int ks2 = 0; ks2 < 4; ks2++){
      UB bu;
      bu.u = *(const uint4*)(bbase + t2 * 16 * 128 + ks2 * 32);
      acc[t2] = __builtin_amdgcn_mfma_f32_16x16x32_bf16(af[ks2].v, bu.v, acc[t2], 0, 0, 0);
    }
  }
  // epilogue: rows n = n0 + 16w + quad*4 + r; cols m = t2*16 + lm
  int nb = n0 + 16 * w + quad * 4;
  float val[8][4];
  #pragma unroll
  for (int t2 = 0; t2 < 8; t2++){
    int m = t2 * 16 + lm;
    float bv = bout[m];
    #pragma unroll
    for (int r = 0; r < 4; r++)
      val[t2][r] = acc[t2][r] + bv + h[(nb + r) * HH + m];
  }
  float mu[4], rs[4];
  #pragma unroll
  for (int r = 0; r < 4; r++){
    float s = 0.f;
    #pragma unroll
    for (int t2 = 0; t2 < 8; t2++) s += val[t2][r];
    s += __shfl_xor(s, 1); s += __shfl_xor(s, 2);
    s += __shfl_xor(s, 4); s += __shfl_xor(s, 8);
    mu[r] = s * (1.0f / HH);
  }
  #pragma unroll
  for (int r = 0; r < 4; r++){
    float s = 0.f;
    #pragma unroll
    for (int t2 = 0; t2 < 8; t2++){ float d2 = val[t2][r] - mu[r]; s += d2 * d2; }
    s += __shfl_xor(s, 1); s += __shfl_xor(s, 2);
    s += __shfl_xor(s, 4); s += __shfl_xor(s, 8);
    rs[r] = rsqrtf(s * (1.0f / HH) + 1e-5f);
  }
  #pragma unroll
  for (int t2 = 0; t2 < 8; t2++){
    int m = t2 * 16 + lm;
    float gm = g[m], bm = b[m];
    #pragma unroll
    for (int r = 0; r < 4; r++){
      float o = (val[t2][r] - mu[r]) * rs[r] * gm + bm;
      h[(nb + r) * HH + m] = o;
      hb[(nb + r) * HH + m] = f2bf(o);
    }
  }
}

// ---------------- edge heads via MFMA (col-split waves) ----------------
__global__ __launch_bounds__(256) void k_edge_mfma(
    const unsigned short* __restrict__ hb, const unsigned short* __restrict__ eab,
    const int* __restrict__ ei, const unsigned short* __restrict__ wb,
    const float* __restrict__ mvb1, const float* __restrict__ frb1,
    const float* __restrict__ mvW2, const float* __restrict__ mvb2,
    const float* __restrict__ frW2, const float* __restrict__ frb2,
    float* __restrict__ out){
  __shared__ __align__(16) unsigned short As[64 * KPAD];
  __shared__ float am[64], a0[64], a1[64];
  int t = threadIdx.x;
  int e0 = blockIdx.x * 64;
  if (t < 64){ am[t] = 0.f; a0[t] = 0.f; a1[t] = 0.f; }
  {
    int el = t >> 2, p = t & 3;
    int e = e0 + el;
    int node = (p < 2) ? ei[e] : ei[EE + e];
    int half = p & 1;
    const uint4* srcp = (const uint4*)(hb + node * HH + half * 64);
    uint4* dstp = (uint4*)(As + el * KPAD + (p >> 1) * 128 + half * 64);
    #pragma unroll
    for (int i = 0; i < 8; i++) dstp[i] = srcp[i];
    if (p == 0){
      unsigned short* tail = As + el * KPAD + 256;
      tail[0] = eab[e * 4];     tail[1] = eab[e * 4 + 1];
      tail[2] = eab[e * 4 + 2]; tail[3] = eab[e * 4 + 3];
      #pragma unroll
      for (int i = 4; i < KPAD - 256; i++) tail[i] = 0;
    }
  }
  int ln = t & 63, w = t >> 6, lm = ln & 15, quad = ln >> 4;
  const unsigned short* bbase = wb + (w * 64 + lm) * KPAD + quad * 8;
  f32x4 acc[4][4];
  #pragma unroll
  for (int rt = 0; rt < 4; rt++)
    #pragma unroll
    for (int t2 = 0; t2 < 4; t2++) acc[rt][t2] = (f32x4){0.f, 0.f, 0.f, 0.f};
  __syncthreads();
  for (int ks = 0; ks < 9; ks++){
    UB bf[4], af[4];
    #pragma unroll
    for (int t2 = 0; t2 < 4; t2++) bf[t2].u = *(const uint4*)(bbase + t2 * 16 * KPAD + ks * 32);
    #pragma unroll
    for (int rt = 0; rt < 4; rt++) af[rt].u = *(const uint4*)(As + (16 * rt + lm) * KPAD + quad * 8 + ks * 32);
    #pragma unroll
    for (int rt = 0; rt < 4; rt++)
      #pragma unroll
      for (int t2 = 0; t2 < 4; t2++)
        acc[rt][t2] = __builtin_amdgcn_mfma_f32_16x16x32_bf16(af[rt].v, bf[t2].v, acc[rt][t2], 0, 0, 0);
  }
  if (w < 2){
    #pragma unroll
    for (int rt = 0; rt < 4; rt++){
      #pragma unroll
      for (int r = 0; r < 4; r++){
        float s = 0.f;
        #pragma unroll
        for (int t2 = 0; t2 < 4; t2++){
          int n = w * 64 + t2 * 16 + lm;
          s += gelu_fast(acc[rt][t2][r] + mvb1[n]) * mvW2[n];
        }
        #pragma unroll
        for (int d = 1; d < 16; d <<= 1) s += __shfl_xor(s, d);
        if (lm == 0) atomicAdd(&am[16 * rt + 4 * quad + r], s);
      }
    }
  } else {
    #pragma unroll
    for (int rt = 0; rt < 4; rt++){
      #pragma unroll
      for (int r = 0; r < 4; r++){
        float s0 = 0.f, s1 = 0.f;
        #pragma unroll
        for (int t2 = 0; t2 < 4; t2++){
          int n = (w - 2) * 64 + t2 * 16 + lm;
          float g = gelu_fast(acc[rt][t2][r] + frb1[n]);
          s0 += g * frW2[n];
          s1 += g * frW2[128 + n];
        }
        #pragma unroll
        for (int d = 1; d < 16; d <<= 1){ s0 += __shfl_xor(s0, d); s1 += __shfl_xor(s1, d); }
        if (lm == 0){
          atomicAdd(&a0[16 * rt + 4 * quad + r], s0);
          atomicAdd(&a1[16 * rt + 4 * quad + r], s1);
        }
      }
    }
  }
  __syncthreads();
  if (t < 64){
    int e = e0 + t;
    out[e]          = am[t] + mvb2[0];
    out[EE + e]     = softplus_f(a0[t] + frb2[0]) + 1e-4f;
    out[2 * EE + e] = softplus_f(a1[t] + frb2[1]) + 1e-4f;
  }
}

// ---------------- value head ----------------
__global__ void k_pool(const float* __restrict__ h, const unsigned char* __restrict__ mask,
                       float* __restrict__ gsum, float* __restrict__ msum, float* __restrict__ mcnt){
  int bb = blockIdx.x, j = threadIdx.x;
  float ga = 0.0f, ma = 0.0f;
  int n0 = bb * 32;
  for (int i = 0; i < 32; i++){
    int n = n0 + i;
    float v = h[n * HH + j];
    ga += v;
    if (mask[n]) ma += v;
  }
  atomicAdd(&gsum[j], ga);
  atomicAdd(&msum[j], ma);
  if (j == 0){
    float c = 0.0f;
    for (int i = 0; i < 32; i++) c += mask[n0 + i] ? 1.0f : 0.0f;
    atomicAdd(mcnt, c);
  }
}

__global__ void k_value(const float* __restrict__ gsum, const float* __restrict__ msum,
                        const float* __restrict__ mcnt,
                        const float* __restrict__ W1, const float* __restrict__ b1,
                        const float* __restrict__ W2, const float* __restrict__ b2,
                        float* __restrict__ out_val){
  __shared__ float red[128];
  __shared__ float vin[256];
  int j = threadIdx.x;
  float gp = gsum[j] * (1.0f / NN);
  float as = msum[j] * (1.0f / NN);
  float ac = fmaxf(mcnt[0] * (1.0f / NN), 1e-6f);
  vin[j] = gp; vin[HH + j] = as / ac;
  __syncthreads();
  float acc = b1[j];
  const float* w = &W1[j * 256];
  #pragma unroll 4
  for (int k = 0; k < 256; k++) acc += vin[k] * w[k];
  float hv = gelu_f(acc) * W2[j];
  float s = block_sum128(hv, red);
  if (j == 0) out_val[0] = s + b2[0];
}

extern "C" void kernel_launch(void* const* d_in, const int* in_sizes, int n_in,
                              void* d_out, int out_size, void* d_ws, size_t ws_size,
                              hipStream_t stream){
  (void)in_sizes; (void)n_in; (void)out_size; (void)ws_size;
  const float* x        = (const float*)d_in[0];
  const int*   ei       = (const int*)d_in[1];
  const float* ea       = (const float*)d_in[2];
  const float* u        = (const float*)d_in[3];
  const unsigned char* mask = (const unsigned char*)d_in[4];
  const float* tiles    = (const float*)d_in[5];
  const float* tf       = (const float*)d_in[7];
  const float* ne_W  = (const float*)d_in[8];
  const float* ne_b  = (const float*)d_in[9];
  const float* ne_g  = (const float*)d_in[10];
  const float* ne_be = (const float*)d_in[11];
  const float* ge_W  = (const float*)d_in[12];
  const float* ge_b  = (const float*)d_in[13];
  const float* ge_g  = (const float*)d_in[14];
  const float* ge_be = (const float*)d_in[15];
  const float* gru_Wih = (const float*)d_in[16];
  const float* gru_bih = (const float*)d_in[17];
  const float* gru_Whh = (const float*)d_in[18];
  const float* gru_bhh = (const float*)d_in[19];
  const float* gat_Wl  = (const float*)d_in[20];
  const float* gat_bl  = (const float*)d_in[21];
  const float* gat_Wr  = (const float*)d_in[22];
  const float* gat_br  = (const float*)d_in[23];
  const float* gat_We  = (const float*)d_in[24];
  const float* gat_att = (const float*)d_in[25];
  const float* gat_bias= (const float*)d_in[26];
  const float* ln_g    = (const float*)d_in[27];
  const float* ln_b    = (const float*)d_in[28];
  const float* attn_Win = (const float*)d_in[29];
  const float* attn_bin = (const float*)d_in[30];
  const float* attn_Wout= (const float*)d_in[31];
  const float* attn_bout= (const float*)d_in[32];
  const float* lng_g    = (const float*)d_in[33];
  const float* lng_b    = (const float*)d_in[34];
  const float* mv_W1 = (const float*)d_in[35];
  const float* mv_b1 = (const float*)d_in[36];
  const float* mv_W2 = (const float*)d_in[37];
  const float* mv_b2 = (const float*)d_in[38];
  const float* fr_W1 = (const float*)d_in[39];
  const float* fr_b1 = (const float*)d_in[40];
  const float* fr_W2 = (const float*)d_in[41];
  const float* fr_b2 = (const float*)d_in[42];
  const float* vl_W1 = (const float*)d_in[43];
  const float* vl_b1 = (const float*)d_in[44];
  const float* vl_W2 = (const float*)d_in[45];
  const float* vl_b2 = (const float*)d_in[46];

  // ---- workspace layout (f32 elem offsets), total ~22.55 MB ----
  float* ws = (float*)d_ws;
  float* h      = ws;                         // 524288
  float* xlr    = ws + 524288;                // 1048576 ([N][256]); attn-phase: qb/kb/vt
  unsigned short* hb     = (unsigned short*)(ws + 1572864);
  unsigned short* tilesb = (unsigned short*)(ws + 1835008);
  unsigned short* wbuf   = (unsigned short*)(ws + 2097152);
  unsigned short* Wihb  = wbuf;
  unsigned short* Whhb  = wbuf + 49152;
  unsigned short* Wlrb  = wbuf + 98304;
  unsigned short* Winb  = wbuf + 229376;
  unsigned short* Woutb = wbuf + 278528;
  float* blrc   = ws + 2244608;
  float* ue     = ws + 2245632;
  float* gsum   = ws + 2245760;
  float* msum   = ws + 2245888;
  float* mcnt   = ws + 2246016;
  int*   cnt    = (int*)(ws + 2246032);
  int*   off    = cnt + NN;
  int*   cur    = off + NN + 1;
  int*   eid    = cur + NN;
  unsigned short* eab = (unsigned short*)(ws + 2323904);
  unsigned short* wbE = (unsigned short*)(ws + 2454976);
  float* S      = ws + 2492864;               // 3145728 scratch (multi-phase)
  float* gi = S;
  float* gh = S + 1572864;
  float* ex = S;
  float* qkvf = S;
  unsigned short* qb = (unsigned short*)xlr;
  unsigned short* kb = (unsigned short*)(xlr + 262144);
  unsigned short* vt = (unsigned short*)(xlr + 524288);
  float* pacc = S;                                        // NN*4*KS*32 = 2097152 f32
  float* pden = S + 2097152;                              // NN*4*KS = 65536

  float* out       = (float*)d_out;
  float* out_val   = out + 3 * EE;
  float* out_tiles = out + 3 * EE + 1;

  // one-shot bf16 prep + zero-init
  k_wprep<<<(1162497 + 255) / 256, 256, 0, stream>>>(gru_Wih, gru_Whh, gat_Wl, gat_Wr,
                                                     attn_Win, attn_Wout, tiles,
                                                     gat_bl, gat_br, ea, mv_W1, fr_W1,
                                                     wbuf, tilesb, blrc, wbE, eab,
                                                     cnt, gsum);

  // CSR of incoming edges
  k_hist   <<<EE / 256, 256, 0, stream>>>(ei, cnt);
  k_scan   <<<1, 256, 0, stream>>>(cnt, off, cur);
  k_scatter<<<EE / 256, 256, 0, stream>>>(ei, cur, eid);

  // encoders
  k_ue      <<<1, 128, 0, stream>>>(u, ge_W, ge_b, ge_g, ge_be, ue);
  k_node_enc<<<NN, 128, 0, stream>>>(x, tf, ne_W, ne_b, ne_g, ne_be, ue, h, hb);

  // GRU via MFMA
  { dim3 g(NN / 64, 3);
    k_lin<384><<<g, 256, 0, stream>>>(hb, Wihb, gru_bih, gi);
    k_lin<384><<<g, 256, 0, stream>>>(tilesb, Whhb, gru_bhh, gh); }
  k_gru_comb<<<NN * HH / 256, 256, 0, stream>>>(gi, gh, tiles, h, hb, out_tiles);

  // GATv2 stack
  for (int l = 0; l < NLAYERS; l++){
    { dim3 g(NN / 64, 2);
      k_lin<256><<<g, 256, 0, stream>>>(hb, Wlrb + l * 32768, blrc + l * 256, xlr); }
    k_score<<<EE / 16, 256, 0, stream>>>(ei, ea, xlr,
                                         gat_We + l * HH * EFEAT,
                                         gat_att + l * NHEADS * HDIM, ex);
    k_aggln<<<NN, 128, 0, stream>>>(xlr, ex, off, eid, ei,
                                    gat_bias + l * HH, ln_g + l * HH, ln_b + l * HH, h, hb);
  }

  // global attention (KS=4, prefetch-pipelined flash + fused epilogue)
  { dim3 g(NN / 64, 3);
    k_lin<384><<<g, 256, 0, stream>>>(hb, Winb, attn_bin, qkvf); }
  k_qkv_post<<<NN / 64, 256, 0, stream>>>(qkvf, qb, kb, vt);
  { dim3 gattn(NN / 64, NHEADS, KS);
    k_attn_flash<<<gattn, 256, 0, stream>>>(qb, kb, vt, pden, pacc); }
  k_attn_out<<<NN / 64, 256, 0, stream>>>(pden, pacc, Woutb, attn_bout, lng_g, lng_b, h, hb);

  // edge heads (bf16 MFMA, col-split waves)
  k_edge_mfma<<<EE / 64, 256, 0, stream>>>(hb, eab, ei, wbE, mv_b1, fr_b1,
                                           mv_W2, mv_b2, fr_W2, fr_b2, out);

  // value head
  k_pool <<<128, 128, 0, stream>>>(h, mask, gsum, msum, mcnt);
  k_value<<<1, 128, 0, stream>>>(gsum, msum, mcnt, vl_W1, vl_b1, vl_W2, vl_b2, out_val);
}

// Round 9
// 464.684 us; speedup vs baseline: 1.0863x; 1.0863x over previous
//
#include <hip/hip_runtime.h>
#include <math.h>

// StrategistGNN forward on MI355X. Round 9: block-cooperative double-buffered
// LDS staging for flash attention (coalesced K/V, ds_read fragments, store-late
// pipeline); k_ue folded into k_node_enc.
// N=4096 nodes, E=65536 edges, H=128, 4 heads x 32, L=4 GAT layers, B=1.

#define NN 4096
#define EE 65536
#define HH 128
#define NHEADS 4
#define HDIM 32
#define NLAYERS 4
#define NFEAT 16
#define GFEAT 8
#define EFEAT 4
#define KS 4     // key-splits for global attention
#define KPAD 296 // padded K stride (bf16) for edge-head GEMM
#define XSTR 136 // LDS row stride (bf16): 2-way bank aliasing only (free)
#define KSTR 40  // flash K-tile LDS row stride (bank-uniform, 16B-aligned)
#define VSTR 72  // flash V-tile LDS row stride (bank-uniform, 16B-aligned)

typedef short bf16x8 __attribute__((ext_vector_type(8)));
typedef float f32x4  __attribute__((ext_vector_type(4)));
union UB { uint4 u; bf16x8 v; };

__device__ __forceinline__ float gelu_f(float x){
  return 0.5f * x * (1.0f + erff(x * 0.7071067811865475f));
}
__device__ __forceinline__ float gelu_fast(float x){
  float u = 0.7978845608f * (x + 0.044715f * x * x * x);
  float t = __expf(-2.0f * fmaxf(u, -40.0f));
  float th = 1.0f - 2.0f * t / (1.0f + t);
  return 0.5f * x * (1.0f + th);
}
__device__ __forceinline__ float sigm_fast(float x){ return 1.0f / (1.0f + __expf(-x)); }
__device__ __forceinline__ float tanh_fast(float x){
  float t = __expf(-2.0f * fmaxf(x, -40.0f));
  return 1.0f - 2.0f * t / (1.0f + t);
}
__device__ __forceinline__ float softplus_f(float x){ return x > 20.0f ? x : log1pf(expf(x)); }
__device__ __forceinline__ unsigned short f2bf(float x){
  unsigned u = __float_as_uint(x);
  unsigned r = (u + 0x7FFFu + ((u >> 16) & 1u)) >> 16;
  return (unsigned short)r;
}
__device__ __forceinline__ unsigned pack2bf(float lo, float hi){
  unsigned a = (__float_as_uint(lo) + 0x8000u) >> 16;
  unsigned b = (__float_as_uint(hi) + 0x8000u) & 0xFFFF0000u;
  return a | b;
}

__device__ __forceinline__ float block_sum128(float v, float* red){
  int j = threadIdx.x;
  red[j] = v; __syncthreads();
  for (int s = 64; s > 0; s >>= 1){
    if (j < s) red[j] += red[j + s];
    __syncthreads();
  }
  float r = red[0];
  __syncthreads();
  return r;
}

// ---------------- CSR build ----------------
__global__ void k_hist(const int* __restrict__ ei, int* __restrict__ cnt){
  int e = blockIdx.x * 256 + threadIdx.x;
  if (e < EE) atomicAdd(&cnt[ei[EE + e]], 1);
}

__global__ void k_scan(const int* __restrict__ cnt, int* __restrict__ off, int* __restrict__ cur){
  __shared__ int part[256];
  int t = threadIdx.x;
  int local[16];
  int s = 0;
  #pragma unroll
  for (int i = 0; i < 16; i++){ local[i] = s; s += cnt[t * 16 + i]; }
  part[t] = s; __syncthreads();
  for (int o = 1; o < 256; o <<= 1){
    int v = (t >= o) ? part[t - o] : 0;
    __syncthreads();
    part[t] += v;
    __syncthreads();
  }
  int base = part[t] - s;
  #pragma unroll
  for (int i = 0; i < 16; i++){ int o = base + local[i]; off[t * 16 + i] = o; cur[t * 16 + i] = o; }
  if (t == 255) off[NN] = part[255];
}

__global__ void k_scatter(const int* __restrict__ ei, int* __restrict__ cur, int* __restrict__ eid){
  int e = blockIdx.x * 256 + threadIdx.x;
  if (e < EE){
    int d = ei[EE + e];
    int p = atomicAdd(&cur[d], 1);
    eid[p] = e;
  }
}

// ---------------- one-shot prep ----------------
__global__ void k_wprep(const float* __restrict__ Wih, const float* __restrict__ Whh,
                        const float* __restrict__ Wl, const float* __restrict__ Wr,
                        const float* __restrict__ Win, const float* __restrict__ Wout,
                        const float* __restrict__ tiles,
                        const float* __restrict__ bl, const float* __restrict__ br,
                        const float* __restrict__ ea,
                        const float* __restrict__ mvW1, const float* __restrict__ frW1,
                        unsigned short* __restrict__ wbuf, unsigned short* __restrict__ tilesb,
                        float* __restrict__ blrc,
                        unsigned short* __restrict__ wbE, unsigned short* __restrict__ eab,
                        int* __restrict__ cnt, float* __restrict__ gsum){
  int i = blockIdx.x * 256 + threadIdx.x;
  if (i < 49152){ wbuf[i] = f2bf(Wih[i]); }
  else if (i < 98304){ int j = i - 49152; wbuf[49152 + j] = f2bf(Whh[j]); }
  else if (i < 229376){
    int j = i - 98304;
    int l = j >> 15, rem = j & 32767, m = rem >> 7, k = rem & 127;
    float v = (m < 128) ? Wl[l * 16384 + m * 128 + k] : Wr[l * 16384 + (m - 128) * 128 + k];
    wbuf[98304 + j] = f2bf(v);
  }
  else if (i < 278528){ int j = i - 229376; wbuf[229376 + j] = f2bf(Win[j]); }
  else if (i < 294912){ int j = i - 278528; wbuf[278528 + j] = f2bf(Wout[j]); }
  else if (i < 819200){ int j = i - 294912; tilesb[j] = f2bf(tiles[j]); }
  else if (i < 820224){
    int j = i - 819200;
    int l = j >> 8, m = j & 255;
    blrc[j] = (m < 128) ? bl[l * 128 + m] : br[l * 128 + m - 128];
  }
  else if (i < 896000){
    int j = i - 820224;
    int n = j / KPAD, k = j - n * KPAD;
    float v = 0.0f;
    if (k < 2 * HH + EFEAT) v = (n < HH) ? mvW1[n * (2 * HH + EFEAT) + k]
                                         : frW1[(n - HH) * (2 * HH + EFEAT) + k];
    wbE[j] = f2bf(v);
  }
  else if (i < 1158144){
    int j = i - 896000;
    eab[j] = f2bf(ea[j]);
  }
  else if (i < 1162240){ cnt[i - 1158144] = 0; }
  else if (i < 1162497){ gsum[i - 1162240] = 0.0f; }
}

// ---------------- generic MFMA projection ----------------
template<int MTOT>
__global__ __launch_bounds__(256) void k_lin(const unsigned short* __restrict__ Xb,
                                             const unsigned short* __restrict__ Wb,
                                             const float* __restrict__ bias,
                                             float* __restrict__ Y){
  __shared__ __align__(16) unsigned short Xs[64 * XSTR];
  int t = threadIdx.x;
  int n0 = blockIdx.x * 64;
  int m0 = blockIdx.y * 128;
  #pragma unroll
  for (int k2 = 0; k2 < 4; k2++){
    int v = t + k2 * 256;
    int r = v >> 4, c8 = v & 15;
    *(uint4*)(Xs + r * XSTR + c8 * 8) = *(const uint4*)(Xb + (n0 + r) * 128 + c8 * 8);
  }
  __syncthreads();
  int ln = t & 63, w = t >> 6, lm = ln & 15, quad = ln >> 4;
  const unsigned short* abase = Xs + (16 * w + lm) * XSTR + quad * 8;
  const unsigned short* bbase = Wb + (m0 + lm) * 128 + quad * 8;
  UB af[4];
  #pragma unroll
  for (int ks = 0; ks < 4; ks++) af[ks].u = *(const uint4*)(abase + ks * 32);
  f32x4 acc[8];
  #pragma unroll
  for (int i = 0; i < 8; i++) acc[i] = (f32x4){0.f, 0.f, 0.f, 0.f};
  #pragma unroll
  for (int t2 = 0; t2 < 8; t2++){
    #pragma unroll
    for (int ks = 0; ks < 4; ks++){
      UB bu;
      bu.u = *(const uint4*)(bbase + t2 * 16 * 128 + ks * 32);
      acc[t2] = __builtin_amdgcn_mfma_f32_16x16x32_bf16(af[ks].v, bu.v, acc[t2], 0, 0, 0);
    }
  }
  #pragma unroll
  for (int t2 = 0; t2 < 8; t2++){
    float bv = bias[m0 + t2 * 16 + lm];
    #pragma unroll
    for (int r = 0; r < 4; r++){
      Y[(n0 + 16 * w + quad * 4 + r) * MTOT + m0 + t2 * 16 + lm] = acc[t2][r] + bv;
    }
  }
}

// ---------------- node encoder (global encoder folded in) ----------------
__global__ void k_node_enc(const float* __restrict__ x, const float* __restrict__ tf,
                           const float* __restrict__ W, const float* __restrict__ b,
                           const float* __restrict__ g, const float* __restrict__ be,
                           const float* __restrict__ u, const float* __restrict__ geW,
                           const float* __restrict__ geb, const float* __restrict__ geg,
                           const float* __restrict__ gebe,
                           float* __restrict__ h, unsigned short* __restrict__ hb){
  __shared__ float red[128];
  __shared__ float xs[NFEAT + 1];
  __shared__ float us[GFEAT];
  int n = blockIdx.x, j = threadIdx.x;
  if (j < NFEAT) xs[j] = x[n * NFEAT + j];
  if (j == NFEAT) xs[NFEAT] = tf[0];
  if (j >= 32 && j < 32 + GFEAT) us[j - 32] = u[j - 32];
  __syncthreads();
  // global encoder (redundant per block; trivial cost)
  float ua = geb[j];
  #pragma unroll
  for (int k = 0; k < GFEAT; k++) ua += us[k] * geW[j * GFEAT + k];
  float umu = block_sum128(ua, red) * (1.0f / HH);
  float ud = ua - umu;
  float uvar = block_sum128(ud * ud, red) * (1.0f / HH);
  float uej = gelu_f(ud * rsqrtf(uvar + 1e-5f) * geg[j] + gebe[j]);
  // node encoder
  float acc = b[j];
  #pragma unroll
  for (int k = 0; k < NFEAT + 1; k++) acc += xs[k] * W[j * (NFEAT + 1) + k];
  float mu = block_sum128(acc, red) * (1.0f / HH);
  float d = acc - mu;
  float var = block_sum128(d * d, red) * (1.0f / HH);
  float r = gelu_f(d * rsqrtf(var + 1e-5f) * g[j] + be[j]) + uej;
  h[n * HH + j] = r;
  hb[n * HH + j] = f2bf(r);
}

// ---------------- GRU combine ----------------
__global__ void k_gru_comb(const float* __restrict__ gi, const float* __restrict__ gh,
                           const float* __restrict__ tiles, float* __restrict__ h,
                           unsigned short* __restrict__ hb, float* __restrict__ out_tiles){
  int idx = blockIdx.x * 256 + threadIdx.x;
  int n = idx >> 7, j = idx & 127;
  float ir = gi[n * 384 + j], iz = gi[n * 384 + 128 + j], inn = gi[n * 384 + 256 + j];
  float hr = gh[n * 384 + j], hz = gh[n * 384 + 128 + j], hn = gh[n * 384 + 256 + j];
  float r = sigm_fast(ir + hr), z = sigm_fast(iz + hz);
  float nn2 = tanh_fast(inn + r * hn);
  float ts = tiles[idx];
  float hnew = (1.0f - z) * nn2 + z * ts;
  h[idx] = hnew;
  hb[idx] = f2bf(hnew);
  out_tiles[idx] = hnew;
}

// ---------------- GAT score ----------------
__global__ __launch_bounds__(256) void k_score(const int* __restrict__ ei, const float* __restrict__ ea,
                        const float* __restrict__ xlr,
                        const float* __restrict__ We, const float* __restrict__ att,
                        float* __restrict__ ex){
  __shared__ float4 We4[128];
  __shared__ float atts[128];
  int t = threadIdx.x;
  if (t < 128){ We4[t] = ((const float4*)We)[t]; atts[t] = att[t]; }
  __syncthreads();
  int el = t >> 4, g = t & 15;
  int e = blockIdx.x * 16 + el;
  int s = ei[e], d = ei[EE + e];
  float4 a = *(const float4*)(ea + e * 4);
  float xls[8], xrs[8];
  *(float4*)(xls)     = *(const float4*)(xlr + s * 256 + g * 8);
  *(float4*)(xls + 4) = *(const float4*)(xlr + s * 256 + g * 8 + 4);
  *(float4*)(xrs)     = *(const float4*)(xlr + d * 256 + 128 + g * 8);
  *(float4*)(xrs + 4) = *(const float4*)(xlr + d * 256 + 128 + g * 8 + 4);
  float sc = 0.0f;
  #pragma unroll
  for (int i = 0; i < 8; i++){
    int j = g * 8 + i;
    float4 w = We4[j];
    float v = xls[i] + xrs[i] + a.x * w.x + a.y * w.y + a.z * w.z + a.w * w.w;
    v = v > 0.0f ? v : 0.2f * v;
    sc += v * atts[j];
  }
  sc += __shfl_xor(sc, 1);
  sc += __shfl_xor(sc, 2);
  if ((g & 3) == 0) ex[e * 4 + (g >> 2)] = __expf(sc);
}

// ---------------- aggregate + residual + LN ----------------
__global__ void k_aggln(const float* __restrict__ xlr, const float* __restrict__ ex,
                        const int* __restrict__ off, const int* __restrict__ eid,
                        const int* __restrict__ ei,
                        const float* __restrict__ bias, const float* __restrict__ g,
                        const float* __restrict__ b, float* __restrict__ h,
                        unsigned short* __restrict__ hb){
  __shared__ float red[128];
  __shared__ float den[NHEADS];
  int n = blockIdx.x, j = threadIdx.x;
  int p0 = off[n], p1 = off[n + 1];
  {
    int hh4 = j & 3, es = j >> 2;
    float s = 0.0f;
    for (int p = p0 + es; p < p1; p += 32) s += ex[eid[p] * 4 + hh4];
    red[j] = s; __syncthreads();
    #pragma unroll
    for (int st = 16; st > 0; st >>= 1){
      if (es < st) red[j] += red[j + st * 4];
      __syncthreads();
    }
    if (j < 4) den[j] = red[j];
    __syncthreads();
  }
  int hh = j >> 5;
  float dinv = 1.0f / (den[hh] + 1e-16f);
  float agg = 0.0f;
  int p = p0;
  for (; p + 2 <= p1; p += 2){
    int e0 = eid[p], e1 = eid[p + 1];
    int s0 = ei[e0], s1 = ei[e1];
    float w0 = ex[e0 * 4 + hh], w1 = ex[e1 * 4 + hh];
    float x0 = xlr[s0 * 256 + j], x1 = xlr[s1 * 256 + j];
    agg += w0 * x0 + w1 * x1;
  }
  if (p < p1){ int e2 = eid[p]; agg += ex[e2 * 4 + hh] * xlr[ei[e2] * 256 + j]; }
  agg *= dinv;
  float val = h[n * HH + j] + agg + bias[j];
  float mu = block_sum128(val, red) * (1.0f / HH);
  float d2 = val - mu;
  float var = block_sum128(d2 * d2, red) * (1.0f / HH);
  float r = d2 * rsqrtf(var + 1e-5f) * g[j] + b[j];
  h[n * HH + j] = r;
  hb[n * HH + j] = f2bf(r);
}

// ---------------- global attention ----------------
__global__ __launch_bounds__(256) void k_qkv_post(const float* __restrict__ qkvf,
                                                  unsigned short* __restrict__ qb,
                                                  unsigned short* __restrict__ kb,
                                                  unsigned short* __restrict__ vt){
  __shared__ unsigned short Vls[128 * 66];
  int t = threadIdx.x;
  int n0 = blockIdx.x * 64;
  const float scale = 0.17677669529663687f;
  for (int idx = t; idx < 64 * 384; idx += 256){
    int nl = idx / 384, col = idx - nl * 384;
    float fv = qkvf[(n0 + nl) * 384 + col];
    if (col < 128) qb[(n0 + nl) * 128 + col] = f2bf(fv);
    else if (col < 256) kb[(n0 + nl) * 128 + col - 128] = f2bf(fv * scale);
    else Vls[(col - 256) * 66 + nl] = f2bf(fv);
  }
  __syncthreads();
  for (int idx = t; idx < 128 * 64; idx += 256){
    int j = idx >> 6, nl = idx & 63;
    vt[j * NN + n0 + nl] = Vls[j * 66 + nl];
  }
}

// Block-cooperative double-buffered LDS flash attention.
// Per 64-key chunk: block stages K(64x32) and V^T(32x64) coalesced into LDS;
// each wave: 4 S-MFMA + exp + shfl P^T + 4 O-MFMA from LDS fragments.
// Staging stores are issued AFTER compute so global latency overlaps MFMA work.
__global__ __launch_bounds__(256, 4) void k_attn_flash(
    const unsigned short* __restrict__ qb, const unsigned short* __restrict__ kb,
    const unsigned short* __restrict__ vt,
    float* __restrict__ pden, float* __restrict__ pacc){
  __shared__ __align__(16) unsigned short Kls[2][64 * KSTR];
  __shared__ __align__(16) unsigned short Vls[2][32 * VSTR];
  int t = threadIdx.x, w = t >> 6, ln = t & 63;
  int c = ln & 15, qd = ln >> 4;
  int hh = blockIdx.y, ks = blockIdx.z;
  int q0 = blockIdx.x * 64 + w * 16;
  UB qf; qf.u = *(const uint4*)(qb + (q0 + c) * HH + hh * HDIM + qd * 8);
  f32x4 o0a = {0,0,0,0}, o1a = {0,0,0,0}, o0b = {0,0,0,0}, o1b = {0,0,0,0};
  float denp = 0.f;
  int srcA = c + ((qd & 1) << 5);
  int srcB = srcA + 16;
  bool hi = qd >= 2;
  // staging: thread t loads K[key kk][dim-part kp], V[row vr][key-part vc]
  int kk = t >> 2, kp = t & 3;
  int vr = t >> 3, vc = t & 7;
  const unsigned short* kg = kb + hh * HDIM + kp * 8;
  const unsigned short* vg = vt + (hh * HDIM + vr) * NN + vc * 8;

  auto comp = [&](int buf, int hs, f32x4& O0, f32x4& O1){
    UB kf0, kf1, vf0, vf1, pt;
    kf0.u = *(const uint4*)(&Kls[buf][(hs * 32 + c) * KSTR + qd * 8]);
    kf1.u = *(const uint4*)(&Kls[buf][(hs * 32 + 16 + c) * KSTR + qd * 8]);
    vf0.u = *(const uint4*)(&Vls[buf][c * VSTR + hs * 32 + qd * 8]);
    vf1.u = *(const uint4*)(&Vls[buf][(16 + c) * VSTR + hs * 32 + qd * 8]);
    f32x4 s0 = {0,0,0,0}, s1 = {0,0,0,0};
    s0 = __builtin_amdgcn_mfma_f32_16x16x32_bf16(kf0.v, qf.v, s0, 0, 0, 0);
    s1 = __builtin_amdgcn_mfma_f32_16x16x32_bf16(kf1.v, qf.v, s1, 0, 0, 0);
    float e00 = __expf(s0[0]), e01 = __expf(s0[1]), e02 = __expf(s0[2]), e03 = __expf(s0[3]);
    float e10 = __expf(s1[0]), e11 = __expf(s1[1]), e12 = __expf(s1[2]), e13 = __expf(s1[3]);
    denp += (e00 + e01) + (e02 + e03) + (e10 + e11) + (e12 + e13);
    int p00 = (int)pack2bf(e00, e01), p01 = (int)pack2bf(e02, e03);
    int p10 = (int)pack2bf(e10, e11), p11 = (int)pack2bf(e12, e13);
    int a00 = __shfl(p00, srcA), a01 = __shfl(p01, srcA);
    int b00 = __shfl(p00, srcB), b01 = __shfl(p01, srcB);
    int a10 = __shfl(p10, srcA), a11 = __shfl(p11, srcA);
    int b10 = __shfl(p10, srcB), b11 = __shfl(p11, srcB);
    pt.u.x = (unsigned)(hi ? a10 : a00);
    pt.u.y = (unsigned)(hi ? a11 : a01);
    pt.u.z = (unsigned)(hi ? b10 : b00);
    pt.u.w = (unsigned)(hi ? b11 : b01);
    O0 = __builtin_amdgcn_mfma_f32_16x16x32_bf16(vf0.v, pt.v, O0, 0, 0, 0);
    O1 = __builtin_amdgcn_mfma_f32_16x16x32_bf16(vf1.v, pt.v, O1, 0, 0, 0);
  };

  const int kbeg = ks * (NN / KS);
  const int NIT = (NN / KS) / 64;   // 16
  {
    uint4 kr = *(const uint4*)(kg + (kbeg + kk) * HH);
    uint4 vr4 = *(const uint4*)(vg + kbeg);
    *(uint4*)(&Kls[0][kk * KSTR + kp * 8]) = kr;
    *(uint4*)(&Vls[0][vr * VSTR + vc * 8]) = vr4;
  }
  __syncthreads();
  for (int it = 0; it < NIT; it++){
    int buf = it & 1;
    if (it + 1 < NIT){
      int kn = kbeg + (it + 1) * 64;
      uint4 kr = *(const uint4*)(kg + (kn + kk) * HH);   // loads issue early
      uint4 vr4 = *(const uint4*)(vg + kn);
      comp(buf, 0, o0a, o1a);                            // overlap with compute
      comp(buf, 1, o0b, o1b);
      *(uint4*)(&Kls[buf ^ 1][kk * KSTR + kp * 8]) = kr; // store late
      *(uint4*)(&Vls[buf ^ 1][vr * VSTR + vc * 8]) = vr4;
    } else {
      comp(buf, 0, o0a, o1a);
      comp(buf, 1, o0b, o1b);
    }
    __syncthreads();
  }

  f32x4 o0 = o0a + o0b, o1 = o1a + o1b;
  denp += __shfl_xor(denp, 16);
  denp += __shfl_xor(denp, 32);
  int pi = ((q0 + c) * NHEADS + hh) * KS + ks;
  if (qd == 0) pden[pi] = denp;
  #pragma unroll
  for (int r = 0; r < 4; r++){
    pacc[pi * HDIM + qd * 4 + r]      = o0[r];
    pacc[pi * HDIM + 16 + qd * 4 + r] = o1[r];
  }
}

// fused: combine key-split partials -> MFMA proj (Wout) -> residual + LN
__global__ __launch_bounds__(256) void k_attn_out(
    const float* __restrict__ pden, const float* __restrict__ pacc,
    const unsigned short* __restrict__ Wb, const float* __restrict__ bout,
    const float* __restrict__ g, const float* __restrict__ b,
    float* __restrict__ h, unsigned short* __restrict__ hb){
  __shared__ __align__(16) unsigned short Xs[64 * XSTR];
  int t = threadIdx.x;
  int n0 = blockIdx.x * 64;
  for (int idx = t; idx < 64 * 128; idx += 256){
    int r = idx >> 7, j = idx & 127;
    int n = n0 + r, hh = j >> 5, d = j & 31;
    float ds = 0.f, as = 0.f;
    #pragma unroll
    for (int ks2 = 0; ks2 < KS; ks2++){
      int pi = (n * NHEADS + hh) * KS + ks2;
      ds += pden[pi];
      as += pacc[pi * HDIM + d];
    }
    Xs[r * XSTR + j] = f2bf(as / ds);
  }
  __syncthreads();
  int ln = t & 63, w = t >> 6, lm = ln & 15, quad = ln >> 4;
  const unsigned short* abase = Xs + (16 * w + lm) * XSTR + quad * 8;
  const unsigned short* bbase = Wb + lm * 128 + quad * 8;
  UB af[4];
  #pragma unroll
  for (int ks2 = 0; ks2 < 4; ks2++) af[ks2].u = *(const uint4*)(abase + ks2 * 32);
  f32x4 acc[8];
  #pragma unroll
  for (int i = 0; i < 8; i++) acc[i] = (f32x4){0.f, 0.f, 0.f, 0.f};
  #pragma unroll
  for (int t2 = 0; t2 < 8; t2++){
    #pragma unroll
    for (int ks2 = 0; ks2 < 4; ks2++){
      UB bu;
      bu.u = *(const uint4*)(bbase + t2 * 16 * 128 + ks2 * 32);
      acc[t2] = __builtin_amdgcn_mfma_f32_16x16x32_bf16(af[ks2].v, bu.v, acc[t2], 0, 0, 0);
    }
  }
  int nb = n0 + 16 * w + quad * 4;
  float val[8][4];
  #pragma unroll
  for (int t2 = 0; t2 < 8; t2++){
    int m = t2 * 16 + lm;
    float bv = bout[m];
    #pragma unroll
    for (int r = 0; r < 4; r++)
      val[t2][r] = acc[t2][r] + bv + h[(nb + r) * HH + m];
  }
  float mu[4], rs[4];
  #pragma unroll
  for (int r = 0; r < 4; r++){
    float s = 0.f;
    #pragma unroll
    for (int t2 = 0; t2 < 8; t2++) s += val[t2][r];
    s += __shfl_xor(s, 1); s += __shfl_xor(s, 2);
    s += __shfl_xor(s, 4); s += __shfl_xor(s, 8);
    mu[r] = s * (1.0f / HH);
  }
  #pragma unroll
  for (int r = 0; r < 4; r++){
    float s = 0.f;
    #pragma unroll
    for (int t2 = 0; t2 < 8; t2++){ float d2 = val[t2][r] - mu[r]; s += d2 * d2; }
    s += __shfl_xor(s, 1); s += __shfl_xor(s, 2);
    s += __shfl_xor(s, 4); s += __shfl_xor(s, 8);
    rs[r] = rsqrtf(s * (1.0f / HH) + 1e-5f);
  }
  #pragma unroll
  for (int t2 = 0; t2 < 8; t2++){
    int m = t2 * 16 + lm;
    float gm = g[m], bm = b[m];
    #pragma unroll
    for (int r = 0; r < 4; r++){
      float o = (val[t2][r] - mu[r]) * rs[r] * gm + bm;
      h[(nb + r) * HH + m] = o;
      hb[(nb + r) * HH + m] = f2bf(o);
    }
  }
}

// ---------------- edge heads via MFMA (col-split waves) ----------------
__global__ __launch_bounds__(256) void k_edge_mfma(
    const unsigned short* __restrict__ hb, const unsigned short* __restrict__ eab,
    const int* __restrict__ ei, const unsigned short* __restrict__ wb,
    const float* __restrict__ mvb1, const float* __restrict__ frb1,
    const float* __restrict__ mvW2, const float* __restrict__ mvb2,
    const float* __restrict__ frW2, const float* __restrict__ frb2,
    float* __restrict__ out){
  __shared__ __align__(16) unsigned short As[64 * KPAD];
  __shared__ float am[64], a0[64], a1[64];
  int t = threadIdx.x;
  int e0 = blockIdx.x * 64;
  if (t < 64){ am[t] = 0.f; a0[t] = 0.f; a1[t] = 0.f; }
  {
    int el = t >> 2, p = t & 3;
    int e = e0 + el;
    int node = (p < 2) ? ei[e] : ei[EE + e];
    int half = p & 1;
    const uint4* srcp = (const uint4*)(hb + node * HH + half * 64);
    uint4* dstp = (uint4*)(As + el * KPAD + (p >> 1) * 128 + half * 64);
    #pragma unroll
    for (int i = 0; i < 8; i++) dstp[i] = srcp[i];
    if (p == 0){
      unsigned short* tail = As + el * KPAD + 256;
      tail[0] = eab[e * 4];     tail[1] = eab[e * 4 + 1];
      tail[2] = eab[e * 4 + 2]; tail[3] = eab[e * 4 + 3];
      #pragma unroll
      for (int i = 4; i < KPAD - 256; i++) tail[i] = 0;
    }
  }
  int ln = t & 63, w = t >> 6, lm = ln & 15, quad = ln >> 4;
  const unsigned short* bbase = wb + (w * 64 + lm) * KPAD + quad * 8;
  f32x4 acc[4][4];
  #pragma unroll
  for (int rt = 0; rt < 4; rt++)
    #pragma unroll
    for (int t2 = 0; t2 < 4; t2++) acc[rt][t2] = (f32x4){0.f, 0.f, 0.f, 0.f};
  __syncthreads();
  for (int ks = 0; ks < 9; ks++){
    UB bf[4], af[4];
    #pragma unroll
    for (int t2 = 0; t2 < 4; t2++) bf[t2].u = *(const uint4*)(bbase + t2 * 16 * KPAD + ks * 32);
    #pragma unroll
    for (int rt = 0; rt < 4; rt++) af[rt].u = *(const uint4*)(As + (16 * rt + lm) * KPAD + quad * 8 + ks * 32);
    #pragma unroll
    for (int rt = 0; rt < 4; rt++)
      #pragma unroll
      for (int t2 = 0; t2 < 4; t2++)
        acc[rt][t2] = __builtin_amdgcn_mfma_f32_16x16x32_bf16(af[rt].v, bf[t2].v, acc[rt][t2], 0, 0, 0);
  }
  if (w < 2){
    #pragma unroll
    for (int rt = 0; rt < 4; rt++){
      #pragma unroll
      for (int r = 0; r < 4; r++){
        float s = 0.f;
        #pragma unroll
        for (int t2 = 0; t2 < 4; t2++){
          int n = w * 64 + t2 * 16 + lm;
          s += gelu_fast(acc[rt][t2][r] + mvb1[n]) * mvW2[n];
        }
        #pragma unroll
        for (int d = 1; d < 16; d <<= 1) s += __shfl_xor(s, d);
        if (lm == 0) atomicAdd(&am[16 * rt + 4 * quad + r], s);
      }
    }
  } else {
    #pragma unroll
    for (int rt = 0; rt < 4; rt++){
      #pragma unroll
      for (int r = 0; r < 4; r++){
        float s0 = 0.f, s1 = 0.f;
        #pragma unroll
        for (int t2 = 0; t2 < 4; t2++){
          int n = (w - 2) * 64 + t2 * 16 + lm;
          float g = gelu_fast(acc[rt][t2][r] + frb1[n]);
          s0 += g * frW2[n];
          s1 += g * frW2[128 + n];
        }
        #pragma unroll
        for (int d = 1; d < 16; d <<= 1){ s0 += __shfl_xor(s0, d); s1 += __shfl_xor(s1, d); }
        if (lm == 0){
          atomicAdd(&a0[16 * rt + 4 * quad + r], s0);
          atomicAdd(&a1[16 * rt + 4 * quad + r], s1);
        }
      }
    }
  }
  __syncthreads();
  if (t < 64){
    int e = e0 + t;
    out[e]          = am[t] + mvb2[0];
    out[EE + e]     = softplus_f(a0[t] + frb2[0]) + 1e-4f;
    out[2 * EE + e] = softplus_f(a1[t] + frb2[1]) + 1e-4f;
  }
}

// ---------------- value head ----------------
__global__ void k_pool(const float* __restrict__ h, const unsigned char* __restrict__ mask,
                       float* __restrict__ gsum, float* __restrict__ msum, float* __restrict__ mcnt){
  int bb = blockIdx.x, j = threadIdx.x;
  float ga = 0.0f, ma = 0.0f;
  int n0 = bb * 32;
  for (int i = 0; i < 32; i++){
    int n = n0 + i;
    float v = h[n * HH + j];
    ga += v;
    if (mask[n]) ma += v;
  }
  atomicAdd(&gsum[j], ga);
  atomicAdd(&msum[j], ma);
  if (j == 0){
    float c = 0.0f;
    for (int i = 0; i < 32; i++) c += mask[n0 + i] ? 1.0f : 0.0f;
    atomicAdd(mcnt, c);
  }
}

__global__ void k_value(const float* __restrict__ gsum, const float* __restrict__ msum,
                        const float* __restrict__ mcnt,
                        const float* __restrict__ W1, const float* __restrict__ b1,
                        const float* __restrict__ W2, const float* __restrict__ b2,
                        float* __restrict__ out_val){
  __shared__ float red[128];
  __shared__ float vin[256];
  int j = threadIdx.x;
  float gp = gsum[j] * (1.0f / NN);
  float as = msum[j] * (1.0f / NN);
  float ac = fmaxf(mcnt[0] * (1.0f / NN), 1e-6f);
  vin[j] = gp; vin[HH + j] = as / ac;
  __syncthreads();
  float acc = b1[j];
  const float* w = &W1[j * 256];
  #pragma unroll 4
  for (int k = 0; k < 256; k++) acc += vin[k] * w[k];
  float hv = gelu_f(acc) * W2[j];
  float s = block_sum128(hv, red);
  if (j == 0) out_val[0] = s + b2[0];
}

extern "C" void kernel_launch(void* const* d_in, const int* in_sizes, int n_in,
                              void* d_out, int out_size, void* d_ws, size_t ws_size,
                              hipStream_t stream){
  (void)in_sizes; (void)n_in; (void)out_size; (void)ws_size;
  const float* x        = (const float*)d_in[0];
  const int*   ei       = (const int*)d_in[1];
  const float* ea       = (const float*)d_in[2];
  const float* u        = (const float*)d_in[3];
  const unsigned char* mask = (const unsigned char*)d_in[4];
  const float* tiles    = (const float*)d_in[5];
  const float* tf       = (const float*)d_in[7];
  const float* ne_W  = (const float*)d_in[8];
  const float* ne_b  = (const float*)d_in[9];
  const float* ne_g  = (const float*)d_in[10];
  const float* ne_be = (const float*)d_in[11];
  const float* ge_W  = (const float*)d_in[12];
  const float* ge_b  = (const float*)d_in[13];
  const float* ge_g  = (const float*)d_in[14];
  const float* ge_be = (const float*)d_in[15];
  const float* gru_Wih = (const float*)d_in[16];
  const float* gru_bih = (const float*)d_in[17];
  const float* gru_Whh = (const float*)d_in[18];
  const float* gru_bhh = (const float*)d_in[19];
  const float* gat_Wl  = (const float*)d_in[20];
  const float* gat_bl  = (const float*)d_in[21];
  const float* gat_Wr  = (const float*)d_in[22];
  const float* gat_br  = (const float*)d_in[23];
  const float* gat_We  = (const float*)d_in[24];
  const float* gat_att = (const float*)d_in[25];
  const float* gat_bias= (const float*)d_in[26];
  const float* ln_g    = (const float*)d_in[27];
  const float* ln_b    = (const float*)d_in[28];
  const float* attn_Win = (const float*)d_in[29];
  const float* attn_bin = (const float*)d_in[30];
  const float* attn_Wout= (const float*)d_in[31];
  const float* attn_bout= (const float*)d_in[32];
  const float* lng_g    = (const float*)d_in[33];
  const float* lng_b    = (const float*)d_in[34];
  const float* mv_W1 = (const float*)d_in[35];
  const float* mv_b1 = (const float*)d_in[36];
  const float* mv_W2 = (const float*)d_in[37];
  const float* mv_b2 = (const float*)d_in[38];
  const float* fr_W1 = (const float*)d_in[39];
  const float* fr_b1 = (const float*)d_in[40];
  const float* fr_W2 = (const float*)d_in[41];
  const float* fr_b2 = (const float*)d_in[42];
  const float* vl_W1 = (const float*)d_in[43];
  const float* vl_b1 = (const float*)d_in[44];
  const float* vl_W2 = (const float*)d_in[45];
  const float* vl_b2 = (const float*)d_in[46];

  // ---- workspace layout (f32 elem offsets), total ~22.55 MB ----
  float* ws = (float*)d_ws;
  float* h      = ws;                         // 524288
  float* xlr    = ws + 524288;                // 1048576; attn-phase: qb/kb/vt
  unsigned short* hb     = (unsigned short*)(ws + 1572864);
  unsigned short* tilesb = (unsigned short*)(ws + 1835008);
  unsigned short* wbuf   = (unsigned short*)(ws + 2097152);
  unsigned short* Wihb  = wbuf;
  unsigned short* Whhb  = wbuf + 49152;
  unsigned short* Wlrb  = wbuf + 98304;
  unsigned short* Winb  = wbuf + 229376;
  unsigned short* Woutb = wbuf + 278528;
  float* blrc   = ws + 2244608;
  float* ue     = ws + 2245632;  (void)ue;
  float* gsum   = ws + 2245760;
  float* msum   = ws + 2245888;
  float* mcnt   = ws + 2246016;
  int*   cnt    = (int*)(ws + 2246032);
  int*   off    = cnt + NN;
  int*   cur    = off + NN + 1;
  int*   eid    = cur + NN;
  unsigned short* eab = (unsigned short*)(ws + 2323904);
  unsigned short* wbE = (unsigned short*)(ws + 2454976);
  float* S      = ws + 2492864;               // 3145728 scratch (multi-phase)
  float* gi = S;
  float* gh = S + 1572864;
  float* ex = S;
  float* qkvf = S;
  unsigned short* qb = (unsigned short*)xlr;
  unsigned short* kb = (unsigned short*)(xlr + 262144);
  unsigned short* vt = (unsigned short*)(xlr + 524288);
  float* pacc = S;                                        // NN*4*KS*32 f32
  float* pden = S + 2097152;                              // NN*4*KS

  float* out       = (float*)d_out;
  float* out_val   = out + 3 * EE;
  float* out_tiles = out + 3 * EE + 1;

  // one-shot bf16 prep + zero-init
  k_wprep<<<(1162497 + 255) / 256, 256, 0, stream>>>(gru_Wih, gru_Whh, gat_Wl, gat_Wr,
                                                     attn_Win, attn_Wout, tiles,
                                                     gat_bl, gat_br, ea, mv_W1, fr_W1,
                                                     wbuf, tilesb, blrc, wbE, eab,
                                                     cnt, gsum);

  // CSR of incoming edges
  k_hist   <<<EE / 256, 256, 0, stream>>>(ei, cnt);
  k_scan   <<<1, 256, 0, stream>>>(cnt, off, cur);
  k_scatter<<<EE / 256, 256, 0, stream>>>(ei, cur, eid);

  // encoders (global encoder folded into node encoder)
  k_node_enc<<<NN, 128, 0, stream>>>(x, tf, ne_W, ne_b, ne_g, ne_be,
                                     u, ge_W, ge_b, ge_g, ge_be, h, hb);

  // GRU via MFMA
  { dim3 g(NN / 64, 3);
    k_lin<384><<<g, 256, 0, stream>>>(hb, Wihb, gru_bih, gi);
    k_lin<384><<<g, 256, 0, stream>>>(tilesb, Whhb, gru_bhh, gh); }
  k_gru_comb<<<NN * HH / 256, 256, 0, stream>>>(gi, gh, tiles, h, hb, out_tiles);

  // GATv2 stack
  for (int l = 0; l < NLAYERS; l++){
    { dim3 g(NN / 64, 2);
      k_lin<256><<<g, 256, 0, stream>>>(hb, Wlrb + l * 32768, blrc + l * 256, xlr); }
    k_score<<<EE / 16, 256, 0, stream>>>(ei, ea, xlr,
                                         gat_We + l * HH * EFEAT,
                                         gat_att + l * NHEADS * HDIM, ex);
    k_aggln<<<NN, 128, 0, stream>>>(xlr, ex, off, eid, ei,
                                    gat_bias + l * HH, ln_g + l * HH, ln_b + l * HH, h, hb);
  }

  // global attention (KS=4, LDS-staged double-buffered flash + fused epilogue)
  { dim3 g(NN / 64, 3);
    k_lin<384><<<g, 256, 0, stream>>>(hb, Winb, attn_bin, qkvf); }
  k_qkv_post<<<NN / 64, 256, 0, stream>>>(qkvf, qb, kb, vt);
  { dim3 gattn(NN / 64, NHEADS, KS);
    k_attn_flash<<<gattn, 256, 0, stream>>>(qb, kb, vt, pden, pacc); }
  k_attn_out<<<NN / 64, 256, 0, stream>>>(pden, pacc, Woutb, attn_bout, lng_g, lng_b, h, hb);

  // edge heads (bf16 MFMA, col-split waves)
  k_edge_mfma<<<EE / 64, 256, 0, stream>>>(hb, eab, ei, wbE, mv_b1, fr_b1,
                                           mv_W2, mv_b2, fr_W2, fr_b2, out);

  // value head
  k_pool <<<128, 128, 0, stream>>>(h, mask, gsum, msum, mcnt);
  k_value<<<1, 128, 0, stream>>>(gsum, msum, mcnt, vl_W1, vl_b1, vl_W2, vl_b2, out_val);
}

// Round 10
// 461.121 us; speedup vs baseline: 1.0947x; 1.0077x over previous
//
#include <hip/hip_runtime.h>
#include <math.h>

// StrategistGNN forward on MI355X. Round 10: bf16 GAT projections (xlrb),
// den-via-atomics in k_score (aggln den phase removed).
// N=4096 nodes, E=65536 edges, H=128, 4 heads x 32, L=4 GAT layers, B=1.

#define NN 4096
#define EE 65536
#define HH 128
#define NHEADS 4
#define HDIM 32
#define NLAYERS 4
#define NFEAT 16
#define GFEAT 8
#define EFEAT 4
#define KS 4     // key-splits for global attention
#define KPAD 296 // padded K stride (bf16) for edge-head GEMM
#define XSTR 136 // LDS row stride (bf16): 2-way bank aliasing only (free)
#define KSTR 40  // flash K-tile LDS row stride
#define VSTR 72  // flash V-tile LDS row stride

typedef short bf16x8 __attribute__((ext_vector_type(8)));
typedef float f32x4  __attribute__((ext_vector_type(4)));
union UB { uint4 u; bf16x8 v; };

__device__ __forceinline__ float gelu_f(float x){
  return 0.5f * x * (1.0f + erff(x * 0.7071067811865475f));
}
__device__ __forceinline__ float gelu_fast(float x){
  float u = 0.7978845608f * (x + 0.044715f * x * x * x);
  float t = __expf(-2.0f * fmaxf(u, -40.0f));
  float th = 1.0f - 2.0f * t / (1.0f + t);
  return 0.5f * x * (1.0f + th);
}
__device__ __forceinline__ float sigm_fast(float x){ return 1.0f / (1.0f + __expf(-x)); }
__device__ __forceinline__ float tanh_fast(float x){
  float t = __expf(-2.0f * fmaxf(x, -40.0f));
  return 1.0f - 2.0f * t / (1.0f + t);
}
__device__ __forceinline__ float softplus_f(float x){ return x > 20.0f ? x : log1pf(expf(x)); }
__device__ __forceinline__ unsigned short f2bf(float x){
  unsigned u = __float_as_uint(x);
  unsigned r = (u + 0x7FFFu + ((u >> 16) & 1u)) >> 16;
  return (unsigned short)r;
}
__device__ __forceinline__ float bf2f(unsigned short x){
  return __uint_as_float(((unsigned)x) << 16);
}
__device__ __forceinline__ unsigned pack2bf(float lo, float hi){
  unsigned a = (__float_as_uint(lo) + 0x8000u) >> 16;
  unsigned b = (__float_as_uint(hi) + 0x8000u) & 0xFFFF0000u;
  return a | b;
}

__device__ __forceinline__ float block_sum128(float v, float* red){
  int j = threadIdx.x;
  red[j] = v; __syncthreads();
  for (int s = 64; s > 0; s >>= 1){
    if (j < s) red[j] += red[j + s];
    __syncthreads();
  }
  float r = red[0];
  __syncthreads();
  return r;
}

// ---------------- CSR build ----------------
__global__ void k_hist(const int* __restrict__ ei, int* __restrict__ cnt){
  int e = blockIdx.x * 256 + threadIdx.x;
  if (e < EE) atomicAdd(&cnt[ei[EE + e]], 1);
}

__global__ void k_scan(const int* __restrict__ cnt, int* __restrict__ off, int* __restrict__ cur){
  __shared__ int part[256];
  int t = threadIdx.x;
  int local[16];
  int s = 0;
  #pragma unroll
  for (int i = 0; i < 16; i++){ local[i] = s; s += cnt[t * 16 + i]; }
  part[t] = s; __syncthreads();
  for (int o = 1; o < 256; o <<= 1){
    int v = (t >= o) ? part[t - o] : 0;
    __syncthreads();
    part[t] += v;
    __syncthreads();
  }
  int base = part[t] - s;
  #pragma unroll
  for (int i = 0; i < 16; i++){ int o = base + local[i]; off[t * 16 + i] = o; cur[t * 16 + i] = o; }
  if (t == 255) off[NN] = part[255];
}

__global__ void k_scatter(const int* __restrict__ ei, int* __restrict__ cur, int* __restrict__ eid){
  int e = blockIdx.x * 256 + threadIdx.x;
  if (e < EE){
    int d = ei[EE + e];
    int p = atomicAdd(&cur[d], 1);
    eid[p] = e;
  }
}

// ---------------- one-shot prep ----------------
__global__ void k_wprep(const float* __restrict__ Wih, const float* __restrict__ Whh,
                        const float* __restrict__ Wl, const float* __restrict__ Wr,
                        const float* __restrict__ Win, const float* __restrict__ Wout,
                        const float* __restrict__ tiles,
                        const float* __restrict__ bl, const float* __restrict__ br,
                        const float* __restrict__ ea,
                        const float* __restrict__ mvW1, const float* __restrict__ frW1,
                        unsigned short* __restrict__ wbuf, unsigned short* __restrict__ tilesb,
                        float* __restrict__ blrc,
                        unsigned short* __restrict__ wbE, unsigned short* __restrict__ eab,
                        int* __restrict__ cnt, float* __restrict__ gsum){
  int i = blockIdx.x * 256 + threadIdx.x;
  if (i < 49152){ wbuf[i] = f2bf(Wih[i]); }
  else if (i < 98304){ int j = i - 49152; wbuf[49152 + j] = f2bf(Whh[j]); }
  else if (i < 229376){
    int j = i - 98304;
    int l = j >> 15, rem = j & 32767, m = rem >> 7, k = rem & 127;
    float v = (m < 128) ? Wl[l * 16384 + m * 128 + k] : Wr[l * 16384 + (m - 128) * 128 + k];
    wbuf[98304 + j] = f2bf(v);
  }
  else if (i < 278528){ int j = i - 229376; wbuf[229376 + j] = f2bf(Win[j]); }
  else if (i < 294912){ int j = i - 278528; wbuf[278528 + j] = f2bf(Wout[j]); }
  else if (i < 819200){ int j = i - 294912; tilesb[j] = f2bf(tiles[j]); }
  else if (i < 820224){
    int j = i - 819200;
    int l = j >> 8, m = j & 255;
    blrc[j] = (m < 128) ? bl[l * 128 + m] : br[l * 128 + m - 128];
  }
  else if (i < 896000){
    int j = i - 820224;
    int n = j / KPAD, k = j - n * KPAD;
    float v = 0.0f;
    if (k < 2 * HH + EFEAT) v = (n < HH) ? mvW1[n * (2 * HH + EFEAT) + k]
                                         : frW1[(n - HH) * (2 * HH + EFEAT) + k];
    wbE[j] = f2bf(v);
  }
  else if (i < 1158144){
    int j = i - 896000;
    eab[j] = f2bf(ea[j]);
  }
  else if (i < 1162240){ cnt[i - 1158144] = 0; }
  else if (i < 1162497){ gsum[i - 1162240] = 0.0f; }
}

// ---------------- generic MFMA projection (f32 out) ----------------
template<int MTOT>
__global__ __launch_bounds__(256) void k_lin(const unsigned short* __restrict__ Xb,
                                             const unsigned short* __restrict__ Wb,
                                             const float* __restrict__ bias,
                                             float* __restrict__ Y){
  __shared__ __align__(16) unsigned short Xs[64 * XSTR];
  int t = threadIdx.x;
  int n0 = blockIdx.x * 64;
  int m0 = blockIdx.y * 128;
  #pragma unroll
  for (int k2 = 0; k2 < 4; k2++){
    int v = t + k2 * 256;
    int r = v >> 4, c8 = v & 15;
    *(uint4*)(Xs + r * XSTR + c8 * 8) = *(const uint4*)(Xb + (n0 + r) * 128 + c8 * 8);
  }
  __syncthreads();
  int ln = t & 63, w = t >> 6, lm = ln & 15, quad = ln >> 4;
  const unsigned short* abase = Xs + (16 * w + lm) * XSTR + quad * 8;
  const unsigned short* bbase = Wb + (m0 + lm) * 128 + quad * 8;
  UB af[4];
  #pragma unroll
  for (int ks = 0; ks < 4; ks++) af[ks].u = *(const uint4*)(abase + ks * 32);
  f32x4 acc[8];
  #pragma unroll
  for (int i = 0; i < 8; i++) acc[i] = (f32x4){0.f, 0.f, 0.f, 0.f};
  #pragma unroll
  for (int t2 = 0; t2 < 8; t2++){
    #pragma unroll
    for (int ks = 0; ks < 4; ks++){
      UB bu;
      bu.u = *(const uint4*)(bbase + t2 * 16 * 128 + ks * 32);
      acc[t2] = __builtin_amdgcn_mfma_f32_16x16x32_bf16(af[ks].v, bu.v, acc[t2], 0, 0, 0);
    }
  }
  #pragma unroll
  for (int t2 = 0; t2 < 8; t2++){
    float bv = bias[m0 + t2 * 16 + lm];
    #pragma unroll
    for (int r = 0; r < 4; r++){
      Y[(n0 + 16 * w + quad * 4 + r) * MTOT + m0 + t2 * 16 + lm] = acc[t2][r] + bv;
    }
  }
}

// ---------------- GAT projection: bf16 out + den zeroing ----------------
__global__ __launch_bounds__(256) void k_lin_gat(const unsigned short* __restrict__ Xb,
                                                 const unsigned short* __restrict__ Wb,
                                                 const float* __restrict__ bias,
                                                 unsigned short* __restrict__ Y,
                                                 float* __restrict__ den){
  __shared__ __align__(16) unsigned short Xs[64 * XSTR];
  int t = threadIdx.x;
  int gid = (blockIdx.y * gridDim.x + blockIdx.x) * 256 + t;
  if (gid < NN * NHEADS) den[gid] = 0.0f;
  int n0 = blockIdx.x * 64;
  int m0 = blockIdx.y * 128;
  #pragma unroll
  for (int k2 = 0; k2 < 4; k2++){
    int v = t + k2 * 256;
    int r = v >> 4, c8 = v & 15;
    *(uint4*)(Xs + r * XSTR + c8 * 8) = *(const uint4*)(Xb + (n0 + r) * 128 + c8 * 8);
  }
  __syncthreads();
  int ln = t & 63, w = t >> 6, lm = ln & 15, quad = ln >> 4;
  const unsigned short* abase = Xs + (16 * w + lm) * XSTR + quad * 8;
  const unsigned short* bbase = Wb + (m0 + lm) * 128 + quad * 8;
  UB af[4];
  #pragma unroll
  for (int ks = 0; ks < 4; ks++) af[ks].u = *(const uint4*)(abase + ks * 32);
  f32x4 acc[8];
  #pragma unroll
  for (int i = 0; i < 8; i++) acc[i] = (f32x4){0.f, 0.f, 0.f, 0.f};
  #pragma unroll
  for (int t2 = 0; t2 < 8; t2++){
    #pragma unroll
    for (int ks = 0; ks < 4; ks++){
      UB bu;
      bu.u = *(const uint4*)(bbase + t2 * 16 * 128 + ks * 32);
      acc[t2] = __builtin_amdgcn_mfma_f32_16x16x32_bf16(af[ks].v, bu.v, acc[t2], 0, 0, 0);
    }
  }
  #pragma unroll
  for (int t2 = 0; t2 < 8; t2++){
    float bv = bias[m0 + t2 * 16 + lm];
    #pragma unroll
    for (int r = 0; r < 4; r++){
      Y[(n0 + 16 * w + quad * 4 + r) * 256 + m0 + t2 * 16 + lm] = f2bf(acc[t2][r] + bv);
    }
  }
}

// ---------------- node encoder (global encoder folded in) ----------------
__global__ void k_node_enc(const float* __restrict__ x, const float* __restrict__ tf,
                           const float* __restrict__ W, const float* __restrict__ b,
                           const float* __restrict__ g, const float* __restrict__ be,
                           const float* __restrict__ u, const float* __restrict__ geW,
                           const float* __restrict__ geb, const float* __restrict__ geg,
                           const float* __restrict__ gebe,
                           float* __restrict__ h, unsigned short* __restrict__ hb){
  __shared__ float red[128];
  __shared__ float xs[NFEAT + 1];
  __shared__ float us[GFEAT];
  int n = blockIdx.x, j = threadIdx.x;
  if (j < NFEAT) xs[j] = x[n * NFEAT + j];
  if (j == NFEAT) xs[NFEAT] = tf[0];
  if (j >= 32 && j < 32 + GFEAT) us[j - 32] = u[j - 32];
  __syncthreads();
  float ua = geb[j];
  #pragma unroll
  for (int k = 0; k < GFEAT; k++) ua += us[k] * geW[j * GFEAT + k];
  float umu = block_sum128(ua, red) * (1.0f / HH);
  float ud = ua - umu;
  float uvar = block_sum128(ud * ud, red) * (1.0f / HH);
  float uej = gelu_f(ud * rsqrtf(uvar + 1e-5f) * geg[j] + gebe[j]);
  float acc = b[j];
  #pragma unroll
  for (int k = 0; k < NFEAT + 1; k++) acc += xs[k] * W[j * (NFEAT + 1) + k];
  float mu = block_sum128(acc, red) * (1.0f / HH);
  float d = acc - mu;
  float var = block_sum128(d * d, red) * (1.0f / HH);
  float r = gelu_f(d * rsqrtf(var + 1e-5f) * g[j] + be[j]) + uej;
  h[n * HH + j] = r;
  hb[n * HH + j] = f2bf(r);
}

// ---------------- GRU combine ----------------
__global__ void k_gru_comb(const float* __restrict__ gi, const float* __restrict__ gh,
                           const float* __restrict__ tiles, float* __restrict__ h,
                           unsigned short* __restrict__ hb, float* __restrict__ out_tiles){
  int idx = blockIdx.x * 256 + threadIdx.x;
  int n = idx >> 7, j = idx & 127;
  float ir = gi[n * 384 + j], iz = gi[n * 384 + 128 + j], inn = gi[n * 384 + 256 + j];
  float hr = gh[n * 384 + j], hz = gh[n * 384 + 128 + j], hn = gh[n * 384 + 256 + j];
  float r = sigm_fast(ir + hr), z = sigm_fast(iz + hz);
  float nn2 = tanh_fast(inn + r * hn);
  float ts = tiles[idx];
  float hnew = (1.0f - z) * nn2 + z * ts;
  h[idx] = hnew;
  hb[idx] = f2bf(hnew);
  out_tiles[idx] = hnew;
}

// ---------------- GAT score (bf16 xlrb, den via atomics) ----------------
__global__ __launch_bounds__(256) void k_score(const int* __restrict__ ei, const float* __restrict__ ea,
                        const unsigned short* __restrict__ xlrb,
                        const float* __restrict__ We, const float* __restrict__ att,
                        float* __restrict__ ex, float* __restrict__ den){
  __shared__ float4 We4[128];
  __shared__ float atts[128];
  int t = threadIdx.x;
  if (t < 128){ We4[t] = ((const float4*)We)[t]; atts[t] = att[t]; }
  __syncthreads();
  int el = t >> 4, g = t & 15;
  int e = blockIdx.x * 16 + el;
  int s = ei[e], d = ei[EE + e];
  float4 a = *(const float4*)(ea + e * 4);
  UB xlu, xru;
  xlu.u = *(const uint4*)(xlrb + s * 256 + g * 8);
  xru.u = *(const uint4*)(xlrb + d * 256 + 128 + g * 8);
  float sc = 0.0f;
  #pragma unroll
  for (int i = 0; i < 8; i++){
    int j = g * 8 + i;
    float4 w = We4[j];
    float v = bf2f((unsigned short)xlu.v[i]) + bf2f((unsigned short)xru.v[i])
            + a.x * w.x + a.y * w.y + a.z * w.z + a.w * w.w;
    v = v > 0.0f ? v : 0.2f * v;
    sc += v * atts[j];
  }
  sc += __shfl_xor(sc, 1);
  sc += __shfl_xor(sc, 2);
  if ((g & 3) == 0){
    float ev = __expf(sc);
    ex[e * 4 + (g >> 2)] = ev;
    atomicAdd(&den[d * 4 + (g >> 2)], ev);
  }
}

// ---------------- aggregate + residual + LN (den precomputed) ----------------
__global__ void k_aggln(const unsigned short* __restrict__ xlrb, const float* __restrict__ ex,
                        const float* __restrict__ den,
                        const int* __restrict__ off, const int* __restrict__ eid,
                        const int* __restrict__ ei,
                        const float* __restrict__ bias, const float* __restrict__ g,
                        const float* __restrict__ b, float* __restrict__ h,
                        unsigned short* __restrict__ hb){
  __shared__ float red[128];
  int n = blockIdx.x, j = threadIdx.x;
  int p0 = off[n], p1 = off[n + 1];
  int hh = j >> 5;
  float dinv = 1.0f / (den[n * 4 + hh] + 1e-16f);
  float agg = 0.0f;
  int p = p0;
  for (; p + 2 <= p1; p += 2){
    int e0 = eid[p], e1 = eid[p + 1];
    int s0 = ei[e0], s1 = ei[e1];
    float w0 = ex[e0 * 4 + hh], w1 = ex[e1 * 4 + hh];
    float x0 = bf2f(xlrb[s0 * 256 + j]);
    float x1 = bf2f(xlrb[s1 * 256 + j]);
    agg += w0 * x0 + w1 * x1;
  }
  if (p < p1){ int e2 = eid[p]; agg += ex[e2 * 4 + hh] * bf2f(xlrb[ei[e2] * 256 + j]); }
  agg *= dinv;
  float val = h[n * HH + j] + agg + bias[j];
  float mu = block_sum128(val, red) * (1.0f / HH);
  float d2 = val - mu;
  float var = block_sum128(d2 * d2, red) * (1.0f / HH);
  float r = d2 * rsqrtf(var + 1e-5f) * g[j] + b[j];
  h[n * HH + j] = r;
  hb[n * HH + j] = f2bf(r);
}

// ---------------- global attention ----------------
__global__ __launch_bounds__(256) void k_qkv_post(const float* __restrict__ qkvf,
                                                  unsigned short* __restrict__ qb,
                                                  unsigned short* __restrict__ kb,
                                                  unsigned short* __restrict__ vt){
  __shared__ unsigned short Vls[128 * 66];
  int t = threadIdx.x;
  int n0 = blockIdx.x * 64;
  const float scale = 0.17677669529663687f;
  for (int idx = t; idx < 64 * 384; idx += 256){
    int nl = idx / 384, col = idx - nl * 384;
    float fv = qkvf[(n0 + nl) * 384 + col];
    if (col < 128) qb[(n0 + nl) * 128 + col] = f2bf(fv);
    else if (col < 256) kb[(n0 + nl) * 128 + col - 128] = f2bf(fv * scale);
    else Vls[(col - 256) * 66 + nl] = f2bf(fv);
  }
  __syncthreads();
  for (int idx = t; idx < 128 * 64; idx += 256){
    int j = idx >> 6, nl = idx & 63;
    vt[j * NN + n0 + nl] = Vls[j * 66 + nl];
  }
}

// Block-cooperative double-buffered LDS flash attention.
__global__ __launch_bounds__(256, 4) void k_attn_flash(
    const unsigned short* __restrict__ qb, const unsigned short* __restrict__ kb,
    const unsigned short* __restrict__ vt,
    float* __restrict__ pden, float* __restrict__ pacc){
  __shared__ __align__(16) unsigned short Kls[2][64 * KSTR];
  __shared__ __align__(16) unsigned short Vls[2][32 * VSTR];
  int t = threadIdx.x, w = t >> 6, ln = t & 63;
  int c = ln & 15, qd = ln >> 4;
  int hh = blockIdx.y, ks = blockIdx.z;
  int q0 = blockIdx.x * 64 + w * 16;
  UB qf; qf.u = *(const uint4*)(qb + (q0 + c) * HH + hh * HDIM + qd * 8);
  f32x4 o0a = {0,0,0,0}, o1a = {0,0,0,0}, o0b = {0,0,0,0}, o1b = {0,0,0,0};
  float denp = 0.f;
  int srcA = c + ((qd & 1) << 5);
  int srcB = srcA + 16;
  bool hi = qd >= 2;
  int kk = t >> 2, kp = t & 3;
  int vr = t >> 3, vc = t & 7;
  const unsigned short* kg = kb + hh * HDIM + kp * 8;
  const unsigned short* vg = vt + (hh * HDIM + vr) * NN + vc * 8;

  auto comp = [&](int buf, int hs, f32x4& O0, f32x4& O1){
    UB kf0, kf1, vf0, vf1, pt;
    kf0.u = *(const uint4*)(&Kls[buf][(hs * 32 + c) * KSTR + qd * 8]);
    kf1.u = *(const uint4*)(&Kls[buf][(hs * 32 + 16 + c) * KSTR + qd * 8]);
    vf0.u = *(const uint4*)(&Vls[buf][c * VSTR + hs * 32 + qd * 8]);
    vf1.u = *(const uint4*)(&Vls[buf][(16 + c) * VSTR + hs * 32 + qd * 8]);
    f32x4 s0 = {0,0,0,0}, s1 = {0,0,0,0};
    s0 = __builtin_amdgcn_mfma_f32_16x16x32_bf16(kf0.v, qf.v, s0, 0, 0, 0);
    s1 = __builtin_amdgcn_mfma_f32_16x16x32_bf16(kf1.v, qf.v, s1, 0, 0, 0);
    float e00 = __expf(s0[0]), e01 = __expf(s0[1]), e02 = __expf(s0[2]), e03 = __expf(s0[3]);
    float e10 = __expf(s1[0]), e11 = __expf(s1[1]), e12 = __expf(s1[2]), e13 = __expf(s1[3]);
    denp += (e00 + e01) + (e02 + e03) + (e10 + e11) + (e12 + e13);
    int p00 = (int)pack2bf(e00, e01), p01 = (int)pack2bf(e02, e03);
    int p10 = (int)pack2bf(e10, e11), p11 = (int)pack2bf(e12, e13);
    int a00 = __shfl(p00, srcA), a01 = __shfl(p01, srcA);
    int b00 = __shfl(p00, srcB), b01 = __shfl(p01, srcB);
    int a10 = __shfl(p10, srcA), a11 = __shfl(p11, srcA);
    int b10 = __shfl(p10, srcB), b11 = __shfl(p11, srcB);
    pt.u.x = (unsigned)(hi ? a10 : a00);
    pt.u.y = (unsigned)(hi ? a11 : a01);
    pt.u.z = (unsigned)(hi ? b10 : b00);
    pt.u.w = (unsigned)(hi ? b11 : b01);
    O0 = __builtin_amdgcn_mfma_f32_16x16x32_bf16(vf0.v, pt.v, O0, 0, 0, 0);
    O1 = __builtin_amdgcn_mfma_f32_16x16x32_bf16(vf1.v, pt.v, O1, 0, 0, 0);
  };

  const int kbeg = ks * (NN / KS);
  const int NIT = (NN / KS) / 64;   // 16
  {
    uint4 kr = *(const uint4*)(kg + (kbeg + kk) * HH);
    uint4 vr4 = *(const uint4*)(vg + kbeg);
    *(uint4*)(&Kls[0][kk * KSTR + kp * 8]) = kr;
    *(uint4*)(&Vls[0][vr * VSTR + vc * 8]) = vr4;
  }
  __syncthreads();
  for (int it = 0; it < NIT; it++){
    int buf = it & 1;
    if (it + 1 < NIT){
      int kn = kbeg + (it + 1) * 64;
      uint4 kr = *(const uint4*)(kg + (kn + kk) * HH);
      uint4 vr4 = *(const uint4*)(vg + kn);
      comp(buf, 0, o0a, o1a);
      comp(buf, 1, o0b, o1b);
      *(uint4*)(&Kls[buf ^ 1][kk * KSTR + kp * 8]) = kr;
      *(uint4*)(&Vls[buf ^ 1][vr * VSTR + vc * 8]) = vr4;
    } else {
      comp(buf, 0, o0a, o1a);
      comp(buf, 1, o0b, o1b);
    }
    __syncthreads();
  }

  f32x4 o0 = o0a + o0b, o1 = o1a + o1b;
  denp += __shfl_xor(denp, 16);
  denp += __shfl_xor(denp, 32);
  int pi = ((q0 + c) * NHEADS + hh) * KS + ks;
  if (qd == 0) pden[pi] = denp;
  #pragma unroll
  for (int r = 0; r < 4; r++){
    pacc[pi * HDIM + qd * 4 + r]      = o0[r];
    pacc[pi * HDIM + 16 + qd * 4 + r] = o1[r];
  }
}

// fused: combine key-split partials -> MFMA proj (Wout) -> residual + LN
__global__ __launch_bounds__(256) void k_attn_out(
    const float* __restrict__ pden, const float* __restrict__ pacc,
    const unsigned short* __restrict__ Wb, const float* __restrict__ bout,
    const float* __restrict__ g, const float* __restrict__ b,
    float* __restrict__ h, unsigned short* __restrict__ hb){
  __shared__ __align__(16) unsigned short Xs[64 * XSTR];
  int t = threadIdx.x;
  int n0 = blockIdx.x * 64;
  for (int idx = t; idx < 64 * 128; idx += 256){
    int r = idx >> 7, j = idx & 127;
    int n = n0 + r, hh = j >> 5, d = j & 31;
    float ds = 0.f, as = 0.f;
    #pragma unroll
    for (int ks2 = 0; ks2 < KS; ks2++){
      int pi = (n * NHEADS + hh) * KS + ks2;
      ds += pden[pi];
      as += pacc[pi * HDIM + d];
    }
    Xs[r * XSTR + j] = f2bf(as / ds);
  }
  __syncthreads();
  int ln = t & 63, w = t >> 6, lm = ln & 15, quad = ln >> 4;
  const unsigned short* abase = Xs + (16 * w + lm) * XSTR + quad * 8;
  const unsigned short* bbase = Wb + lm * 128 + quad * 8;
  UB af[4];
  #pragma unroll
  for (int ks2 = 0; ks2 < 4; ks2++) af[ks2].u = *(const uint4*)(abase + ks2 * 32);
  f32x4 acc[8];
  #pragma unroll
  for (int i = 0; i < 8; i++) acc[i] = (f32x4){0.f, 0.f, 0.f, 0.f};
  #pragma unroll
  for (int t2 = 0; t2 < 8; t2++){
    #pragma unroll
    for (int ks2 = 0; ks2 < 4; ks2++){
      UB bu;
      bu.u = *(const uint4*)(bbase + t2 * 16 * 128 + ks2 * 32);
      acc[t2] = __builtin_amdgcn_mfma_f32_16x16x32_bf16(af[ks2].v, bu.v, acc[t2], 0, 0, 0);
    }
  }
  int nb = n0 + 16 * w + quad * 4;
  float val[8][4];
  #pragma unroll
  for (int t2 = 0; t2 < 8; t2++){
    int m = t2 * 16 + lm;
    float bv = bout[m];
    #pragma unroll
    for (int r = 0; r < 4; r++)
      val[t2][r] = acc[t2][r] + bv + h[(nb + r) * HH + m];
  }
  float mu[4], rs[4];
  #pragma unroll
  for (int r = 0; r < 4; r++){
    float s = 0.f;
    #pragma unroll
    for (int t2 = 0; t2 < 8; t2++) s += val[t2][r];
    s += __shfl_xor(s, 1); s += __shfl_xor(s, 2);
    s += __shfl_xor(s, 4); s += __shfl_xor(s, 8);
    mu[r] = s * (1.0f / HH);
  }
  #pragma unroll
  for (int r = 0; r < 4; r++){
    float s = 0.f;
    #pragma unroll
    for (int t2 = 0; t2 < 8; t2++){ float d2 = val[t2][r] - mu[r]; s += d2 * d2; }
    s += __shfl_xor(s, 1); s += __shfl_xor(s, 2);
    s += __shfl_xor(s, 4); s += __shfl_xor(s, 8);
    rs[r] = rsqrtf(s * (1.0f / HH) + 1e-5f);
  }
  #pragma unroll
  for (int t2 = 0; t2 < 8; t2++){
    int m = t2 * 16 + lm;
    float gm = g[m], bm = b[m];
    #pragma unroll
    for (int r = 0; r < 4; r++){
      float o = (val[t2][r] - mu[r]) * rs[r] * gm + bm;
      h[(nb + r) * HH + m] = o;
      hb[(nb + r) * HH + m] = f2bf(o);
    }
  }
}

// ---------------- edge heads via MFMA (col-split waves) ----------------
__global__ __launch_bounds__(256) void k_edge_mfma(
    const unsigned short* __restrict__ hb, const unsigned short* __restrict__ eab,
    const int* __restrict__ ei, const unsigned short* __restrict__ wb,
    const float* __restrict__ mvb1, const float* __restrict__ frb1,
    const float* __restrict__ mvW2, const float* __restrict__ mvb2,
    const float* __restrict__ frW2, const float* __restrict__ frb2,
    float* __restrict__ out){
  __shared__ __align__(16) unsigned short As[64 * KPAD];
  __shared__ float am[64], a0[64], a1[64];
  int t = threadIdx.x;
  int e0 = blockIdx.x * 64;
  if (t < 64){ am[t] = 0.f; a0[t] = 0.f; a1[t] = 0.f; }
  {
    int el = t >> 2, p = t & 3;
    int e = e0 + el;
    int node = (p < 2) ? ei[e] : ei[EE + e];
    int half = p & 1;
    const uint4* srcp = (const uint4*)(hb + node * HH + half * 64);
    uint4* dstp = (uint4*)(As + el * KPAD + (p >> 1) * 128 + half * 64);
    #pragma unroll
    for (int i = 0; i < 8; i++) dstp[i] = srcp[i];
    if (p == 0){
      unsigned short* tail = As + el * KPAD + 256;
      tail[0] = eab[e * 4];     tail[1] = eab[e * 4 + 1];
      tail[2] = eab[e * 4 + 2]; tail[3] = eab[e * 4 + 3];
      #pragma unroll
      for (int i = 4; i < KPAD - 256; i++) tail[i] = 0;
    }
  }
  int ln = t & 63, w = t >> 6, lm = ln & 15, quad = ln >> 4;
  const unsigned short* bbase = wb + (w * 64 + lm) * KPAD + quad * 8;
  f32x4 acc[4][4];
  #pragma unroll
  for (int rt = 0; rt < 4; rt++)
    #pragma unroll
    for (int t2 = 0; t2 < 4; t2++) acc[rt][t2] = (f32x4){0.f, 0.f, 0.f, 0.f};
  __syncthreads();
  for (int ks = 0; ks < 9; ks++){
    UB bf[4], af[4];
    #pragma unroll
    for (int t2 = 0; t2 < 4; t2++) bf[t2].u = *(const uint4*)(bbase + t2 * 16 * KPAD + ks * 32);
    #pragma unroll
    for (int rt = 0; rt < 4; rt++) af[rt].u = *(const uint4*)(As + (16 * rt + lm) * KPAD + quad * 8 + ks * 32);
    #pragma unroll
    for (int rt = 0; rt < 4; rt++)
      #pragma unroll
      for (int t2 = 0; t2 < 4; t2++)
        acc[rt][t2] = __builtin_amdgcn_mfma_f32_16x16x32_bf16(af[rt].v, bf[t2].v, acc[rt][t2], 0, 0, 0);
  }
  if (w < 2){
    #pragma unroll
    for (int rt = 0; rt < 4; rt++){
      #pragma unroll
      for (int r = 0; r < 4; r++){
        float s = 0.f;
        #pragma unroll
        for (int t2 = 0; t2 < 4; t2++){
          int n = w * 64 + t2 * 16 + lm;
          s += gelu_fast(acc[rt][t2][r] + mvb1[n]) * mvW2[n];
        }
        #pragma unroll
        for (int d = 1; d < 16; d <<= 1) s += __shfl_xor(s, d);
        if (lm == 0) atomicAdd(&am[16 * rt + 4 * quad + r], s);
      }
    }
  } else {
    #pragma unroll
    for (int rt = 0; rt < 4; rt++){
      #pragma unroll
      for (int r = 0; r < 4; r++){
        float s0 = 0.f, s1 = 0.f;
        #pragma unroll
        for (int t2 = 0; t2 < 4; t2++){
          int n = (w - 2) * 64 + t2 * 16 + lm;
          float g = gelu_fast(acc[rt][t2][r] + frb1[n]);
          s0 += g * frW2[n];
          s1 += g * frW2[128 + n];
        }
        #pragma unroll
        for (int d = 1; d < 16; d <<= 1){ s0 += __shfl_xor(s0, d); s1 += __shfl_xor(s1, d); }
        if (lm == 0){
          atomicAdd(&a0[16 * rt + 4 * quad + r], s0);
          atomicAdd(&a1[16 * rt + 4 * quad + r], s1);
        }
      }
    }
  }
  __syncthreads();
  if (t < 64){
    int e = e0 + t;
    out[e]          = am[t] + mvb2[0];
    out[EE + e]     = softplus_f(a0[t] + frb2[0]) + 1e-4f;
    out[2 * EE + e] = softplus_f(a1[t] + frb2[1]) + 1e-4f;
  }
}

// ---------------- value head ----------------
__global__ void k_pool(const float* __restrict__ h, const unsigned char* __restrict__ mask,
                       float* __restrict__ gsum, float* __restrict__ msum, float* __restrict__ mcnt){
  int bb = blockIdx.x, j = threadIdx.x;
  float ga = 0.0f, ma = 0.0f;
  int n0 = bb * 32;
  for (int i = 0; i < 32; i++){
    int n = n0 + i;
    float v = h[n * HH + j];
    ga += v;
    if (mask[n]) ma += v;
  }
  atomicAdd(&gsum[j], ga);
  atomicAdd(&msum[j], ma);
  if (j == 0){
    float c = 0.0f;
    for (int i = 0; i < 32; i++) c += mask[n0 + i] ? 1.0f : 0.0f;
    atomicAdd(mcnt, c);
  }
}

__global__ void k_value(const float* __restrict__ gsum, const float* __restrict__ msum,
                        const float* __restrict__ mcnt,
                        const float* __restrict__ W1, const float* __restrict__ b1,
                        const float* __restrict__ W2, const float* __restrict__ b2,
                        float* __restrict__ out_val){
  __shared__ float red[128];
  __shared__ float vin[256];
  int j = threadIdx.x;
  float gp = gsum[j] * (1.0f / NN);
  float as = msum[j] * (1.0f / NN);
  float ac = fmaxf(mcnt[0] * (1.0f / NN), 1e-6f);
  vin[j] = gp; vin[HH + j] = as / ac;
  __syncthreads();
  float acc = b1[j];
  const float* w = &W1[j * 256];
  #pragma unroll 4
  for (int k = 0; k < 256; k++) acc += vin[k] * w[k];
  float hv = gelu_f(acc) * W2[j];
  float s = block_sum128(hv, red);
  if (j == 0) out_val[0] = s + b2[0];
}

extern "C" void kernel_launch(void* const* d_in, const int* in_sizes, int n_in,
                              void* d_out, int out_size, void* d_ws, size_t ws_size,
                              hipStream_t stream){
  (void)in_sizes; (void)n_in; (void)out_size; (void)ws_size;
  const float* x        = (const float*)d_in[0];
  const int*   ei       = (const int*)d_in[1];
  const float* ea       = (const float*)d_in[2];
  const float* u        = (const float*)d_in[3];
  const unsigned char* mask = (const unsigned char*)d_in[4];
  const float* tiles    = (const float*)d_in[5];
  const float* tf       = (const float*)d_in[7];
  const float* ne_W  = (const float*)d_in[8];
  const float* ne_b  = (const float*)d_in[9];
  const float* ne_g  = (const float*)d_in[10];
  const float* ne_be = (const float*)d_in[11];
  const float* ge_W  = (const float*)d_in[12];
  const float* ge_b  = (const float*)d_in[13];
  const float* ge_g  = (const float*)d_in[14];
  const float* ge_be = (const float*)d_in[15];
  const float* gru_Wih = (const float*)d_in[16];
  const float* gru_bih = (const float*)d_in[17];
  const float* gru_Whh = (const float*)d_in[18];
  const float* gru_bhh = (const float*)d_in[19];
  const float* gat_Wl  = (const float*)d_in[20];
  const float* gat_bl  = (const float*)d_in[21];
  const float* gat_Wr  = (const float*)d_in[22];
  const float* gat_br  = (const float*)d_in[23];
  const float* gat_We  = (const float*)d_in[24];
  const float* gat_att = (const float*)d_in[25];
  const float* gat_bias= (const float*)d_in[26];
  const float* ln_g    = (const float*)d_in[27];
  const float* ln_b    = (const float*)d_in[28];
  const float* attn_Win = (const float*)d_in[29];
  const float* attn_bin = (const float*)d_in[30];
  const float* attn_Wout= (const float*)d_in[31];
  const float* attn_bout= (const float*)d_in[32];
  const float* lng_g    = (const float*)d_in[33];
  const float* lng_b    = (const float*)d_in[34];
  const float* mv_W1 = (const float*)d_in[35];
  const float* mv_b1 = (const float*)d_in[36];
  const float* mv_W2 = (const float*)d_in[37];
  const float* mv_b2 = (const float*)d_in[38];
  const float* fr_W1 = (const float*)d_in[39];
  const float* fr_b1 = (const float*)d_in[40];
  const float* fr_W2 = (const float*)d_in[41];
  const float* fr_b2 = (const float*)d_in[42];
  const float* vl_W1 = (const float*)d_in[43];
  const float* vl_b1 = (const float*)d_in[44];
  const float* vl_W2 = (const float*)d_in[45];
  const float* vl_b2 = (const float*)d_in[46];

  // ---- workspace layout (f32 elem offsets) ----
  float* ws = (float*)d_ws;
  float* h      = ws;                         // 524288
  float* xlr    = ws + 524288;                // region reused: GAT xlrb/den, attn qb/kb/vt
  unsigned short* hb     = (unsigned short*)(ws + 1572864);
  unsigned short* tilesb = (unsigned short*)(ws + 1835008);
  unsigned short* wbuf   = (unsigned short*)(ws + 2097152);
  unsigned short* Wihb  = wbuf;
  unsigned short* Whhb  = wbuf + 49152;
  unsigned short* Wlrb  = wbuf + 98304;
  unsigned short* Winb  = wbuf + 229376;
  unsigned short* Woutb = wbuf + 278528;
  float* blrc   = ws + 2244608;
  float* gsum   = ws + 2245760;
  float* msum   = ws + 2245888;
  float* mcnt   = ws + 2246016;
  int*   cnt    = (int*)(ws + 2246032);
  int*   off    = cnt + NN;
  int*   cur    = off + NN + 1;
  int*   eid    = cur + NN;
  unsigned short* eab = (unsigned short*)(ws + 2323904);
  unsigned short* wbE = (unsigned short*)(ws + 2454976);
  float* S      = ws + 2492864;               // 3145728 scratch (multi-phase)
  float* gi = S;
  float* gh = S + 1572864;
  float* ex = S;
  float* qkvf = S;
  // GAT phase (xlr region):
  unsigned short* xlrb = (unsigned short*)xlr;            // NN*256 bf16 (= 524288 f32)
  float* den = xlr + 524288;                              // NN*4 f32
  // attn phase (xlr region, after GAT):
  unsigned short* qb = (unsigned short*)xlr;
  unsigned short* kb = (unsigned short*)(xlr + 262144);
  unsigned short* vt = (unsigned short*)(xlr + 524288 + 16384);
  float* pacc = S;                                        // NN*4*KS*32 f32
  float* pden = S + 2097152;                              // NN*4*KS

  float* out       = (float*)d_out;
  float* out_val   = out + 3 * EE;
  float* out_tiles = out + 3 * EE + 1;

  // one-shot bf16 prep + zero-init
  k_wprep<<<(1162497 + 255) / 256, 256, 0, stream>>>(gru_Wih, gru_Whh, gat_Wl, gat_Wr,
                                                     attn_Win, attn_Wout, tiles,
                                                     gat_bl, gat_br, ea, mv_W1, fr_W1,
                                                     wbuf, tilesb, blrc, wbE, eab,
                                                     cnt, gsum);

  // CSR of incoming edges
  k_hist   <<<EE / 256, 256, 0, stream>>>(ei, cnt);
  k_scan   <<<1, 256, 0, stream>>>(cnt, off, cur);
  k_scatter<<<EE / 256, 256, 0, stream>>>(ei, cur, eid);

  // encoders
  k_node_enc<<<NN, 128, 0, stream>>>(x, tf, ne_W, ne_b, ne_g, ne_be,
                                     u, ge_W, ge_b, ge_g, ge_be, h, hb);

  // GRU via MFMA
  { dim3 g(NN / 64, 3);
    k_lin<384><<<g, 256, 0, stream>>>(hb, Wihb, gru_bih, gi);
    k_lin<384><<<g, 256, 0, stream>>>(tilesb, Whhb, gru_bhh, gh); }
  k_gru_comb<<<NN * HH / 256, 256, 0, stream>>>(gi, gh, tiles, h, hb, out_tiles);

  // GATv2 stack (bf16 xlrb + den atomics)
  for (int l = 0; l < NLAYERS; l++){
    { dim3 g(NN / 64, 2);
      k_lin_gat<<<g, 256, 0, stream>>>(hb, Wlrb + l * 32768, blrc + l * 256, xlrb, den); }
    k_score<<<EE / 16, 256, 0, stream>>>(ei, ea, xlrb,
                                         gat_We + l * HH * EFEAT,
                                         gat_att + l * NHEADS * HDIM, ex, den);
    k_aggln<<<NN, 128, 0, stream>>>(xlrb, ex, den, off, eid, ei,
                                    gat_bias + l * HH, ln_g + l * HH, ln_b + l * HH, h, hb);
  }

  // global attention (KS=4, LDS-staged double-buffered flash + fused epilogue)
  { dim3 g(NN / 64, 3);
    k_lin<384><<<g, 256, 0, stream>>>(hb, Winb, attn_bin, qkvf); }
  k_qkv_post<<<NN / 64, 256, 0, stream>>>(qkvf, qb, kb, vt);
  { dim3 gattn(NN / 64, NHEADS, KS);
    k_attn_flash<<<gattn, 256, 0, stream>>>(qb, kb, vt, pden, pacc); }
  k_attn_out<<<NN / 64, 256, 0, stream>>>(pden, pacc, Woutb, attn_bout, lng_g, lng_b, h, hb);

  // edge heads (bf16 MFMA, col-split waves)
  k_edge_mfma<<<EE / 64, 256, 0, stream>>>(hb, eab, ei, wbE, mv_b1, fr_b1,
                                           mv_W2, mv_b2, fr_W2, fr_b2, out);

  // value head
  k_pool <<<128, 128, 0, stream>>>(h, mask, gsum, msum, mcnt);
  k_value<<<1, 128, 0, stream>>>(gsum, msum, mcnt, vl_W1, vl_b1, vl_W2, vl_b2, out_val);
}

// Round 11
// 410.553 us; speedup vs baseline: 1.2296x; 1.1232x over previous
//
#include <hip/hip_runtime.h>
#include <math.h>

// StrategistGNN forward on MI355X. Round 11: concurrent GRU GEMMs (z=2),
// QKV transpose fused into GEMM epilogue, CSR-ordered edge weights
// (srcs/rank) removing aggln's double indirection.
// N=4096 nodes, E=65536 edges, H=128, 4 heads x 32, L=4 GAT layers, B=1.

#define NN 4096
#define EE 65536
#define HH 128
#define NHEADS 4
#define HDIM 32
#define NLAYERS 4
#define NFEAT 16
#define GFEAT 8
#define EFEAT 4
#define KS 4     // key-splits for global attention
#define KPAD 296 // padded K stride (bf16) for edge-head GEMM
#define XSTR 136 // LDS row stride (bf16): 2-way bank aliasing only (free)
#define KSTR 40  // flash K-tile LDS row stride
#define VSTR 72  // flash V-tile LDS row stride

typedef short bf16x8 __attribute__((ext_vector_type(8)));
typedef float f32x4  __attribute__((ext_vector_type(4)));
union UB { uint4 u; bf16x8 v; };

__device__ __forceinline__ float gelu_f(float x){
  return 0.5f * x * (1.0f + erff(x * 0.7071067811865475f));
}
__device__ __forceinline__ float gelu_fast(float x){
  float u = 0.7978845608f * (x + 0.044715f * x * x * x);
  float t = __expf(-2.0f * fmaxf(u, -40.0f));
  float th = 1.0f - 2.0f * t / (1.0f + t);
  return 0.5f * x * (1.0f + th);
}
__device__ __forceinline__ float sigm_fast(float x){ return 1.0f / (1.0f + __expf(-x)); }
__device__ __forceinline__ float tanh_fast(float x){
  float t = __expf(-2.0f * fmaxf(x, -40.0f));
  return 1.0f - 2.0f * t / (1.0f + t);
}
__device__ __forceinline__ float softplus_f(float x){ return x > 20.0f ? x : log1pf(expf(x)); }
__device__ __forceinline__ unsigned short f2bf(float x){
  unsigned u = __float_as_uint(x);
  unsigned r = (u + 0x7FFFu + ((u >> 16) & 1u)) >> 16;
  return (unsigned short)r;
}
__device__ __forceinline__ float bf2f(unsigned short x){
  return __uint_as_float(((unsigned)x) << 16);
}
__device__ __forceinline__ unsigned pack2bf(float lo, float hi){
  unsigned a = (__float_as_uint(lo) + 0x8000u) >> 16;
  unsigned b = (__float_as_uint(hi) + 0x8000u) & 0xFFFF0000u;
  return a | b;
}

__device__ __forceinline__ float block_sum128(float v, float* red){
  int j = threadIdx.x;
  red[j] = v; __syncthreads();
  for (int s = 64; s > 0; s >>= 1){
    if (j < s) red[j] += red[j + s];
    __syncthreads();
  }
  float r = red[0];
  __syncthreads();
  return r;
}

// ---------------- CSR build ----------------
__global__ void k_hist(const int* __restrict__ ei, int* __restrict__ cnt){
  int e = blockIdx.x * 256 + threadIdx.x;
  if (e < EE) atomicAdd(&cnt[ei[EE + e]], 1);
}

__global__ void k_scan(const int* __restrict__ cnt, int* __restrict__ off, int* __restrict__ cur){
  __shared__ int part[256];
  int t = threadIdx.x;
  int local[16];
  int s = 0;
  #pragma unroll
  for (int i = 0; i < 16; i++){ local[i] = s; s += cnt[t * 16 + i]; }
  part[t] = s; __syncthreads();
  for (int o = 1; o < 256; o <<= 1){
    int v = (t >= o) ? part[t - o] : 0;
    __syncthreads();
    part[t] += v;
    __syncthreads();
  }
  int base = part[t] - s;
  #pragma unroll
  for (int i = 0; i < 16; i++){ int o = base + local[i]; off[t * 16 + i] = o; cur[t * 16 + i] = o; }
  if (t == 255) off[NN] = part[255];
}

// scatter: srcs[p] = src node of the edge landing at CSR slot p; rank[e] = p
__global__ void k_scatter(const int* __restrict__ ei, int* __restrict__ cur,
                          int* __restrict__ srcs, int* __restrict__ rank){
  int e = blockIdx.x * 256 + threadIdx.x;
  if (e < EE){
    int d = ei[EE + e];
    int p = atomicAdd(&cur[d], 1);
    srcs[p] = ei[e];
    rank[e] = p;
  }
}

// ---------------- one-shot prep ----------------
__global__ void k_wprep(const float* __restrict__ Wih, const float* __restrict__ Whh,
                        const float* __restrict__ Wl, const float* __restrict__ Wr,
                        const float* __restrict__ Win, const float* __restrict__ Wout,
                        const float* __restrict__ tiles,
                        const float* __restrict__ bl, const float* __restrict__ br,
                        const float* __restrict__ ea,
                        const float* __restrict__ mvW1, const float* __restrict__ frW1,
                        unsigned short* __restrict__ wbuf, unsigned short* __restrict__ tilesb,
                        float* __restrict__ blrc,
                        unsigned short* __restrict__ wbE, unsigned short* __restrict__ eab,
                        int* __restrict__ cnt, float* __restrict__ gsum){
  int i = blockIdx.x * 256 + threadIdx.x;
  if (i < 49152){ wbuf[i] = f2bf(Wih[i]); }
  else if (i < 98304){ int j = i - 49152; wbuf[49152 + j] = f2bf(Whh[j]); }
  else if (i < 229376){
    int j = i - 98304;
    int l = j >> 15, rem = j & 32767, m = rem >> 7, k = rem & 127;
    float v = (m < 128) ? Wl[l * 16384 + m * 128 + k] : Wr[l * 16384 + (m - 128) * 128 + k];
    wbuf[98304 + j] = f2bf(v);
  }
  else if (i < 278528){ int j = i - 229376; wbuf[229376 + j] = f2bf(Win[j]); }
  else if (i < 294912){ int j = i - 278528; wbuf[278528 + j] = f2bf(Wout[j]); }
  else if (i < 819200){ int j = i - 294912; tilesb[j] = f2bf(tiles[j]); }
  else if (i < 820224){
    int j = i - 819200;
    int l = j >> 8, m = j & 255;
    blrc[j] = (m < 128) ? bl[l * 128 + m] : br[l * 128 + m - 128];
  }
  else if (i < 896000){
    int j = i - 820224;
    int n = j / KPAD, k = j - n * KPAD;
    float v = 0.0f;
    if (k < 2 * HH + EFEAT) v = (n < HH) ? mvW1[n * (2 * HH + EFEAT) + k]
                                         : frW1[(n - HH) * (2 * HH + EFEAT) + k];
    wbE[j] = f2bf(v);
  }
  else if (i < 1158144){
    int j = i - 896000;
    eab[j] = f2bf(ea[j]);
  }
  else if (i < 1162240){ cnt[i - 1158144] = 0; }
  else if (i < 1162497){ gsum[i - 1162240] = 0.0f; }
}

// ---------------- shared GEMM core (64 rows x 128 cols, K=128) ----------------
__device__ __forceinline__ void gemm_core(const unsigned short* __restrict__ Xb, int n0,
                                          const unsigned short* __restrict__ Wb, int m0,
                                          unsigned short* Xs, f32x4 acc[8]){
  int t = threadIdx.x;
  #pragma unroll
  for (int k2 = 0; k2 < 4; k2++){
    int v = t + k2 * 256;
    int r = v >> 4, c8 = v & 15;
    *(uint4*)(Xs + r * XSTR + c8 * 8) = *(const uint4*)(Xb + (n0 + r) * 128 + c8 * 8);
  }
  __syncthreads();
  int ln = t & 63, w = t >> 6, lm = ln & 15, quad = ln >> 4;
  const unsigned short* abase = Xs + (16 * w + lm) * XSTR + quad * 8;
  const unsigned short* bbase = Wb + (m0 + lm) * 128 + quad * 8;
  UB af[4];
  #pragma unroll
  for (int ks = 0; ks < 4; ks++) af[ks].u = *(const uint4*)(abase + ks * 32);
  #pragma unroll
  for (int i = 0; i < 8; i++) acc[i] = (f32x4){0.f, 0.f, 0.f, 0.f};
  #pragma unroll
  for (int t2 = 0; t2 < 8; t2++){
    #pragma unroll
    for (int ks = 0; ks < 4; ks++){
      UB bu;
      bu.u = *(const uint4*)(bbase + t2 * 16 * 128 + ks * 32);
      acc[t2] = __builtin_amdgcn_mfma_f32_16x16x32_bf16(af[ks].v, bu.v, acc[t2], 0, 0, 0);
    }
  }
}

// generic f32-out projection
template<int MTOT>
__global__ __launch_bounds__(256) void k_lin(const unsigned short* __restrict__ Xb,
                                             const unsigned short* __restrict__ Wb,
                                             const float* __restrict__ bias,
                                             float* __restrict__ Y){
  __shared__ __align__(16) unsigned short Xs[64 * XSTR];
  int t = threadIdx.x;
  int n0 = blockIdx.x * 64, m0 = blockIdx.y * 128;
  f32x4 acc[8];
  gemm_core(Xb, n0, Wb, m0, Xs, acc);
  int ln = t & 63, w = t >> 6, lm = ln & 15, quad = ln >> 4;
  #pragma unroll
  for (int t2 = 0; t2 < 8; t2++){
    float bv = bias[m0 + t2 * 16 + lm];
    #pragma unroll
    for (int r = 0; r < 4; r++){
      Y[(n0 + 16 * w + quad * 4 + r) * MTOT + m0 + t2 * 16 + lm] = acc[t2][r] + bv;
    }
  }
}

// GRU: both projections in one launch (z=0: gi from hb/Wih; z=1: gh from tilesb/Whh)
__global__ __launch_bounds__(256) void k_gru_lin(const unsigned short* __restrict__ hb,
                                                 const unsigned short* __restrict__ tilesb,
                                                 const unsigned short* __restrict__ Wihb,
                                                 const unsigned short* __restrict__ Whhb,
                                                 const float* __restrict__ bih,
                                                 const float* __restrict__ bhh,
                                                 float* __restrict__ gi, float* __restrict__ gh){
  __shared__ __align__(16) unsigned short Xs[64 * XSTR];
  int z = blockIdx.z;
  const unsigned short* Xb = z ? tilesb : hb;
  const unsigned short* Wb = z ? Whhb : Wihb;
  const float* bias = z ? bhh : bih;
  float* Y = z ? gh : gi;
  int t = threadIdx.x;
  int n0 = blockIdx.x * 64, m0 = blockIdx.y * 128;
  f32x4 acc[8];
  gemm_core(Xb, n0, Wb, m0, Xs, acc);
  int ln = t & 63, w = t >> 6, lm = ln & 15, quad = ln >> 4;
  #pragma unroll
  for (int t2 = 0; t2 < 8; t2++){
    float bv = bias[m0 + t2 * 16 + lm];
    #pragma unroll
    for (int r = 0; r < 4; r++){
      Y[(n0 + 16 * w + quad * 4 + r) * 384 + m0 + t2 * 16 + lm] = acc[t2][r] + bv;
    }
  }
}

// GAT projection: bf16 out + den zeroing
__global__ __launch_bounds__(256) void k_lin_gat(const unsigned short* __restrict__ Xb,
                                                 const unsigned short* __restrict__ Wb,
                                                 const float* __restrict__ bias,
                                                 unsigned short* __restrict__ Y,
                                                 float* __restrict__ den){
  __shared__ __align__(16) unsigned short Xs[64 * XSTR];
  int t = threadIdx.x;
  int gid = (blockIdx.y * gridDim.x + blockIdx.x) * 256 + t;
  if (gid < NN * NHEADS) den[gid] = 0.0f;
  int n0 = blockIdx.x * 64, m0 = blockIdx.y * 128;
  f32x4 acc[8];
  gemm_core(Xb, n0, Wb, m0, Xs, acc);
  int ln = t & 63, w = t >> 6, lm = ln & 15, quad = ln >> 4;
  #pragma unroll
  for (int t2 = 0; t2 < 8; t2++){
    float bv = bias[m0 + t2 * 16 + lm];
    #pragma unroll
    for (int r = 0; r < 4; r++){
      Y[(n0 + 16 * w + quad * 4 + r) * 256 + m0 + t2 * 16 + lm] = f2bf(acc[t2][r] + bv);
    }
  }
}

// QKV projection with fused post: y=0 -> qb, y=1 -> kb (pre-scaled), y=2 -> vt (transposed)
__global__ __launch_bounds__(256) void k_lin_qkv(const unsigned short* __restrict__ Xb,
                                                 const unsigned short* __restrict__ Wb,
                                                 const float* __restrict__ bias,
                                                 unsigned short* __restrict__ qb,
                                                 unsigned short* __restrict__ kb,
                                                 unsigned short* __restrict__ vt){
  __shared__ __align__(16) unsigned short Xs[64 * XSTR];
  int t = threadIdx.x;
  int n0 = blockIdx.x * 64, m0 = blockIdx.y * 128;
  f32x4 acc[8];
  gemm_core(Xb, n0, Wb, m0, Xs, acc);
  int ln = t & 63, w = t >> 6, lm = ln & 15, quad = ln >> 4;
  int nb = n0 + 16 * w + quad * 4;
  const float scale = 0.17677669529663687f;
  if (blockIdx.y == 0){
    #pragma unroll
    for (int t2 = 0; t2 < 8; t2++){
      int m = t2 * 16 + lm;
      float bv = bias[m];
      #pragma unroll
      for (int r = 0; r < 4; r++) qb[(nb + r) * HH + m] = f2bf(acc[t2][r] + bv);
    }
  } else if (blockIdx.y == 1){
    #pragma unroll
    for (int t2 = 0; t2 < 8; t2++){
      int m = t2 * 16 + lm;
      float bv = bias[128 + m];
      #pragma unroll
      for (int r = 0; r < 4; r++) kb[(nb + r) * HH + m] = f2bf((acc[t2][r] + bv) * scale);
    }
  } else {
    #pragma unroll
    for (int t2 = 0; t2 < 8; t2++){
      int m = t2 * 16 + lm;
      float bv = bias[256 + m];
      uint2 p;
      p.x = pack2bf(acc[t2][0] + bv, acc[t2][1] + bv);
      p.y = pack2bf(acc[t2][2] + bv, acc[t2][3] + bv);
      *(uint2*)(vt + m * NN + nb) = p;   // 4 consecutive n per lane, 8B packed
    }
  }
}

// ---------------- node encoder (global encoder folded in) ----------------
__global__ void k_node_enc(const float* __restrict__ x, const float* __restrict__ tf,
                           const float* __restrict__ W, const float* __restrict__ b,
                           const float* __restrict__ g, const float* __restrict__ be,
                           const float* __restrict__ u, const float* __restrict__ geW,
                           const float* __restrict__ geb, const float* __restrict__ geg,
                           const float* __restrict__ gebe,
                           float* __restrict__ h, unsigned short* __restrict__ hb){
  __shared__ float red[128];
  __shared__ float xs[NFEAT + 1];
  __shared__ float us[GFEAT];
  int n = blockIdx.x, j = threadIdx.x;
  if (j < NFEAT) xs[j] = x[n * NFEAT + j];
  if (j == NFEAT) xs[NFEAT] = tf[0];
  if (j >= 32 && j < 32 + GFEAT) us[j - 32] = u[j - 32];
  __syncthreads();
  float ua = geb[j];
  #pragma unroll
  for (int k = 0; k < GFEAT; k++) ua += us[k] * geW[j * GFEAT + k];
  float umu = block_sum128(ua, red) * (1.0f / HH);
  float ud = ua - umu;
  float uvar = block_sum128(ud * ud, red) * (1.0f / HH);
  float uej = gelu_f(ud * rsqrtf(uvar + 1e-5f) * geg[j] + gebe[j]);
  float acc = b[j];
  #pragma unroll
  for (int k = 0; k < NFEAT + 1; k++) acc += xs[k] * W[j * (NFEAT + 1) + k];
  float mu = block_sum128(acc, red) * (1.0f / HH);
  float d = acc - mu;
  float var = block_sum128(d * d, red) * (1.0f / HH);
  float r = gelu_f(d * rsqrtf(var + 1e-5f) * g[j] + be[j]) + uej;
  h[n * HH + j] = r;
  hb[n * HH + j] = f2bf(r);
}

// ---------------- GRU combine ----------------
__global__ void k_gru_comb(const float* __restrict__ gi, const float* __restrict__ gh,
                           const float* __restrict__ tiles, float* __restrict__ h,
                           unsigned short* __restrict__ hb, float* __restrict__ out_tiles){
  int idx = blockIdx.x * 256 + threadIdx.x;
  int n = idx >> 7, j = idx & 127;
  float ir = gi[n * 384 + j], iz = gi[n * 384 + 128 + j], inn = gi[n * 384 + 256 + j];
  float hr = gh[n * 384 + j], hz = gh[n * 384 + 128 + j], hn = gh[n * 384 + 256 + j];
  float r = sigm_fast(ir + hr), z = sigm_fast(iz + hz);
  float nn2 = tanh_fast(inn + r * hn);
  float ts = tiles[idx];
  float hnew = (1.0f - z) * nn2 + z * ts;
  h[idx] = hnew;
  hb[idx] = f2bf(hnew);
  out_tiles[idx] = hnew;
}

// ---------------- GAT score (writes exp in CSR order via rank) ----------------
__global__ __launch_bounds__(256) void k_score(const int* __restrict__ ei, const float* __restrict__ ea,
                        const unsigned short* __restrict__ xlrb,
                        const float* __restrict__ We, const float* __restrict__ att,
                        const int* __restrict__ rank,
                        float* __restrict__ exs, float* __restrict__ den){
  __shared__ float4 We4[128];
  __shared__ float atts[128];
  int t = threadIdx.x;
  if (t < 128){ We4[t] = ((const float4*)We)[t]; atts[t] = att[t]; }
  __syncthreads();
  int el = t >> 4, g = t & 15;
  int e = blockIdx.x * 16 + el;
  int s = ei[e], d = ei[EE + e];
  float4 a = *(const float4*)(ea + e * 4);
  UB xlu, xru;
  xlu.u = *(const uint4*)(xlrb + s * 256 + g * 8);
  xru.u = *(const uint4*)(xlrb + d * 256 + 128 + g * 8);
  float sc = 0.0f;
  #pragma unroll
  for (int i = 0; i < 8; i++){
    int j = g * 8 + i;
    float4 w = We4[j];
    float v = bf2f((unsigned short)xlu.v[i]) + bf2f((unsigned short)xru.v[i])
            + a.x * w.x + a.y * w.y + a.z * w.z + a.w * w.w;
    v = v > 0.0f ? v : 0.2f * v;
    sc += v * atts[j];
  }
  sc += __shfl_xor(sc, 1);
  sc += __shfl_xor(sc, 2);
  if ((g & 3) == 0){
    float ev = __expf(sc);
    exs[rank[e] * 4 + (g >> 2)] = ev;
    atomicAdd(&den[d * 4 + (g >> 2)], ev);
  }
}

// ---------------- aggregate + residual + LN (sequential srcs/exs) ----------------
__global__ void k_aggln(const unsigned short* __restrict__ xlrb, const float* __restrict__ exs,
                        const float* __restrict__ den,
                        const int* __restrict__ off, const int* __restrict__ srcs,
                        const float* __restrict__ bias, const float* __restrict__ g,
                        const float* __restrict__ b, float* __restrict__ h,
                        unsigned short* __restrict__ hb){
  __shared__ float red[128];
  int n = blockIdx.x, j = threadIdx.x;
  int p0 = off[n], p1 = off[n + 1];
  int hh = j >> 5;
  float dinv = 1.0f / (den[n * 4 + hh] + 1e-16f);
  float agg = 0.0f;
  int p = p0;
  for (; p + 4 <= p1; p += 4){
    int s0 = srcs[p], s1 = srcs[p + 1], s2 = srcs[p + 2], s3 = srcs[p + 3];
    float w0 = exs[p * 4 + hh],       w1 = exs[(p + 1) * 4 + hh];
    float w2 = exs[(p + 2) * 4 + hh], w3 = exs[(p + 3) * 4 + hh];
    float x0 = bf2f(xlrb[s0 * 256 + j]);
    float x1 = bf2f(xlrb[s1 * 256 + j]);
    float x2 = bf2f(xlrb[s2 * 256 + j]);
    float x3 = bf2f(xlrb[s3 * 256 + j]);
    agg += w0 * x0 + w1 * x1 + w2 * x2 + w3 * x3;
  }
  for (; p < p1; p++){
    agg += exs[p * 4 + hh] * bf2f(xlrb[srcs[p] * 256 + j]);
  }
  agg *= dinv;
  float val = h[n * HH + j] + agg + bias[j];
  float mu = block_sum128(val, red) * (1.0f / HH);
  float d2 = val - mu;
  float var = block_sum128(d2 * d2, red) * (1.0f / HH);
  float r = d2 * rsqrtf(var + 1e-5f) * g[j] + b[j];
  h[n * HH + j] = r;
  hb[n * HH + j] = f2bf(r);
}

// ---------------- flash attention (block-cooperative double-buffered LDS) ----------------
__global__ __launch_bounds__(256, 4) void k_attn_flash(
    const unsigned short* __restrict__ qb, const unsigned short* __restrict__ kb,
    const unsigned short* __restrict__ vt,
    float* __restrict__ pden, float* __restrict__ pacc){
  __shared__ __align__(16) unsigned short Kls[2][64 * KSTR];
  __shared__ __align__(16) unsigned short Vls[2][32 * VSTR];
  int t = threadIdx.x, w = t >> 6, ln = t & 63;
  int c = ln & 15, qd = ln >> 4;
  int hh = blockIdx.y, ks = blockIdx.z;
  int q0 = blockIdx.x * 64 + w * 16;
  UB qf; qf.u = *(const uint4*)(qb + (q0 + c) * HH + hh * HDIM + qd * 8);
  f32x4 o0a = {0,0,0,0}, o1a = {0,0,0,0}, o0b = {0,0,0,0}, o1b = {0,0,0,0};
  float denp = 0.f;
  int srcA = c + ((qd & 1) << 5);
  int srcB = srcA + 16;
  bool hi = qd >= 2;
  int kk = t >> 2, kp = t & 3;
  int vr = t >> 3, vc = t & 7;
  const unsigned short* kg = kb + hh * HDIM + kp * 8;
  const unsigned short* vg = vt + (hh * HDIM + vr) * NN + vc * 8;

  auto comp = [&](int buf, int hs, f32x4& O0, f32x4& O1){
    UB kf0, kf1, vf0, vf1, pt;
    kf0.u = *(const uint4*)(&Kls[buf][(hs * 32 + c) * KSTR + qd * 8]);
    kf1.u = *(const uint4*)(&Kls[buf][(hs * 32 + 16 + c) * KSTR + qd * 8]);
    vf0.u = *(const uint4*)(&Vls[buf][c * VSTR + hs * 32 + qd * 8]);
    vf1.u = *(const uint4*)(&Vls[buf][(16 + c) * VSTR + hs * 32 + qd * 8]);
    f32x4 s0 = {0,0,0,0}, s1 = {0,0,0,0};
    s0 = __builtin_amdgcn_mfma_f32_16x16x32_bf16(kf0.v, qf.v, s0, 0, 0, 0);
    s1 = __builtin_amdgcn_mfma_f32_16x16x32_bf16(kf1.v, qf.v, s1, 0, 0, 0);
    float e00 = __expf(s0[0]), e01 = __expf(s0[1]), e02 = __expf(s0[2]), e03 = __expf(s0[3]);
    float e10 = __expf(s1[0]), e11 = __expf(s1[1]), e12 = __expf(s1[2]), e13 = __expf(s1[3]);
    denp += (e00 + e01) + (e02 + e03) + (e10 + e11) + (e12 + e13);
    int p00 = (int)pack2bf(e00, e01), p01 = (int)pack2bf(e02, e03);
    int p10 = (int)pack2bf(e10, e11), p11 = (int)pack2bf(e12, e13);
    int a00 = __shfl(p00, srcA), a01 = __shfl(p01, srcA);
    int b00 = __shfl(p00, srcB), b01 = __shfl(p01, srcB);
    int a10 = __shfl(p10, srcA), a11 = __shfl(p11, srcA);
    int b10 = __shfl(p10, srcB), b11 = __shfl(p11, srcB);
    pt.u.x = (unsigned)(hi ? a10 : a00);
    pt.u.y = (unsigned)(hi ? a11 : a01);
    pt.u.z = (unsigned)(hi ? b10 : b00);
    pt.u.w = (unsigned)(hi ? b11 : b01);
    O0 = __builtin_amdgcn_mfma_f32_16x16x32_bf16(vf0.v, pt.v, O0, 0, 0, 0);
    O1 = __builtin_amdgcn_mfma_f32_16x16x32_bf16(vf1.v, pt.v, O1, 0, 0, 0);
  };

  const int kbeg = ks * (NN / KS);
  const int NIT = (NN / KS) / 64;   // 16
  {
    uint4 kr = *(const uint4*)(kg + (kbeg + kk) * HH);
    uint4 vr4 = *(const uint4*)(vg + kbeg);
    *(uint4*)(&Kls[0][kk * KSTR + kp * 8]) = kr;
    *(uint4*)(&Vls[0][vr * VSTR + vc * 8]) = vr4;
  }
  __syncthreads();
  for (int it = 0; it < NIT; it++){
    int buf = it & 1;
    if (it + 1 < NIT){
      int kn = kbeg + (it + 1) * 64;
      uint4 kr = *(const uint4*)(kg + (kn + kk) * HH);
      uint4 vr4 = *(const uint4*)(vg + kn);
      comp(buf, 0, o0a, o1a);
      comp(buf, 1, o0b, o1b);
      *(uint4*)(&Kls[buf ^ 1][kk * KSTR + kp * 8]) = kr;
      *(uint4*)(&Vls[buf ^ 1][vr * VSTR + vc * 8]) = vr4;
    } else {
      comp(buf, 0, o0a, o1a);
      comp(buf, 1, o0b, o1b);
    }
    __syncthreads();
  }

  f32x4 o0 = o0a + o0b, o1 = o1a + o1b;
  denp += __shfl_xor(denp, 16);
  denp += __shfl_xor(denp, 32);
  int pi = ((q0 + c) * NHEADS + hh) * KS + ks;
  if (qd == 0) pden[pi] = denp;
  #pragma unroll
  for (int r = 0; r < 4; r++){
    pacc[pi * HDIM + qd * 4 + r]      = o0[r];
    pacc[pi * HDIM + 16 + qd * 4 + r] = o1[r];
  }
}

// fused: combine key-split partials -> MFMA proj (Wout) -> residual + LN
__global__ __launch_bounds__(256) void k_attn_out(
    const float* __restrict__ pden, const float* __restrict__ pacc,
    const unsigned short* __restrict__ Wb, const float* __restrict__ bout,
    const float* __restrict__ g, const float* __restrict__ b,
    float* __restrict__ h, unsigned short* __restrict__ hb){
  __shared__ __align__(16) unsigned short Xs[64 * XSTR];
  int t = threadIdx.x;
  int n0 = blockIdx.x * 64;
  for (int idx = t; idx < 64 * 128; idx += 256){
    int r = idx >> 7, j = idx & 127;
    int n = n0 + r, hh = j >> 5, d = j & 31;
    float ds = 0.f, as = 0.f;
    #pragma unroll
    for (int ks2 = 0; ks2 < KS; ks2++){
      int pi = (n * NHEADS + hh) * KS + ks2;
      ds += pden[pi];
      as += pacc[pi * HDIM + d];
    }
    Xs[r * XSTR + j] = f2bf(as / ds);
  }
  __syncthreads();
  int ln = t & 63, w = t >> 6, lm = ln & 15, quad = ln >> 4;
  const unsigned short* abase = Xs + (16 * w + lm) * XSTR + quad * 8;
  const unsigned short* bbase = Wb + lm * 128 + quad * 8;
  UB af[4];
  #pragma unroll
  for (int ks2 = 0; ks2 < 4; ks2++) af[ks2].u = *(const uint4*)(abase + ks2 * 32);
  f32x4 acc[8];
  #pragma unroll
  for (int i = 0; i < 8; i++) acc[i] = (f32x4){0.f, 0.f, 0.f, 0.f};
  #pragma unroll
  for (int t2 = 0; t2 < 8; t2++){
    #pragma unroll
    for (int ks2 = 0; ks2 < 4; ks2++){
      UB bu;
      bu.u = *(const uint4*)(bbase + t2 * 16 * 128 + ks2 * 32);
      acc[t2] = __builtin_amdgcn_mfma_f32_16x16x32_bf16(af[ks2].v, bu.v, acc[t2], 0, 0, 0);
    }
  }
  int nb = n0 + 16 * w + quad * 4;
  float val[8][4];
  #pragma unroll
  for (int t2 = 0; t2 < 8; t2++){
    int m = t2 * 16 + lm;
    float bv = bout[m];
    #pragma unroll
    for (int r = 0; r < 4; r++)
      val[t2][r] = acc[t2][r] + bv + h[(nb + r) * HH + m];
  }
  float mu[4], rs[4];
  #pragma unroll
  for (int r = 0; r < 4; r++){
    float s = 0.f;
    #pragma unroll
    for (int t2 = 0; t2 < 8; t2++) s += val[t2][r];
    s += __shfl_xor(s, 1); s += __shfl_xor(s, 2);
    s += __shfl_xor(s, 4); s += __shfl_xor(s, 8);
    mu[r] = s * (1.0f / HH);
  }
  #pragma unroll
  for (int r = 0; r < 4; r++){
    float s = 0.f;
    #pragma unroll
    for (int t2 = 0; t2 < 8; t2++){ float d2 = val[t2][r] - mu[r]; s += d2 * d2; }
    s += __shfl_xor(s, 1); s += __shfl_xor(s, 2);
    s += __shfl_xor(s, 4); s += __shfl_xor(s, 8);
    rs[r] = rsqrtf(s * (1.0f / HH) + 1e-5f);
  }
  #pragma unroll
  for (int t2 = 0; t2 < 8; t2++){
    int m = t2 * 16 + lm;
    float gm = g[m], bm = b[m];
    #pragma unroll
    for (int r = 0; r < 4; r++){
      float o = (val[t2][r] - mu[r]) * rs[r] * gm + bm;
      h[(nb + r) * HH + m] = o;
      hb[(nb + r) * HH + m] = f2bf(o);
    }
  }
}

// ---------------- edge heads via MFMA (col-split waves) ----------------
__global__ __launch_bounds__(256) void k_edge_mfma(
    const unsigned short* __restrict__ hb, const unsigned short* __restrict__ eab,
    const int* __restrict__ ei, const unsigned short* __restrict__ wb,
    const float* __restrict__ mvb1, const float* __restrict__ frb1,
    const float* __restrict__ mvW2, const float* __restrict__ mvb2,
    const float* __restrict__ frW2, const float* __restrict__ frb2,
    float* __restrict__ out){
  __shared__ __align__(16) unsigned short As[64 * KPAD];
  __shared__ float am[64], a0[64], a1[64];
  int t = threadIdx.x;
  int e0 = blockIdx.x * 64;
  if (t < 64){ am[t] = 0.f; a0[t] = 0.f; a1[t] = 0.f; }
  {
    int el = t >> 2, p = t & 3;
    int e = e0 + el;
    int node = (p < 2) ? ei[e] : ei[EE + e];
    int half = p & 1;
    const uint4* srcp = (const uint4*)(hb + node * HH + half * 64);
    uint4* dstp = (uint4*)(As + el * KPAD + (p >> 1) * 128 + half * 64);
    #pragma unroll
    for (int i = 0; i < 8; i++) dstp[i] = srcp[i];
    if (p == 0){
      unsigned short* tail = As + el * KPAD + 256;
      tail[0] = eab[e * 4];     tail[1] = eab[e * 4 + 1];
      tail[2] = eab[e * 4 + 2]; tail[3] = eab[e * 4 + 3];
      #pragma unroll
      for (int i = 4; i < KPAD - 256; i++) tail[i] = 0;
    }
  }
  int ln = t & 63, w = t >> 6, lm = ln & 15, quad = ln >> 4;
  const unsigned short* bbase = wb + (w * 64 + lm) * KPAD + quad * 8;
  f32x4 acc[4][4];
  #pragma unroll
  for (int rt = 0; rt < 4; rt++)
    #pragma unroll
    for (int t2 = 0; t2 < 4; t2++) acc[rt][t2] = (f32x4){0.f, 0.f, 0.f, 0.f};
  __syncthreads();
  for (int ks = 0; ks < 9; ks++){
    UB bf[4], af[4];
    #pragma unroll
    for (int t2 = 0; t2 < 4; t2++) bf[t2].u = *(const uint4*)(bbase + t2 * 16 * KPAD + ks * 32);
    #pragma unroll
    for (int rt = 0; rt < 4; rt++) af[rt].u = *(const uint4*)(As + (16 * rt + lm) * KPAD + quad * 8 + ks * 32);
    #pragma unroll
    for (int rt = 0; rt < 4; rt++)
      #pragma unroll
      for (int t2 = 0; t2 < 4; t2++)
        acc[rt][t2] = __builtin_amdgcn_mfma_f32_16x16x32_bf16(af[rt].v, bf[t2].v, acc[rt][t2], 0, 0, 0);
  }
  if (w < 2){
    #pragma unroll
    for (int rt = 0; rt < 4; rt++){
      #pragma unroll
      for (int r = 0; r < 4; r++){
        float s = 0.f;
        #pragma unroll
        for (int t2 = 0; t2 < 4; t2++){
          int n = w * 64 + t2 * 16 + lm;
          s += gelu_fast(acc[rt][t2][r] + mvb1[n]) * mvW2[n];
        }
        #pragma unroll
        for (int d = 1; d < 16; d <<= 1) s += __shfl_xor(s, d);
        if (lm == 0) atomicAdd(&am[16 * rt + 4 * quad + r], s);
      }
    }
  } else {
    #pragma unroll
    for (int rt = 0; rt < 4; rt++){
      #pragma unroll
      for (int r = 0; r < 4; r++){
        float s0 = 0.f, s1 = 0.f;
        #pragma unroll
        for (int t2 = 0; t2 < 4; t2++){
          int n = (w - 2) * 64 + t2 * 16 + lm;
          float g = gelu_fast(acc[rt][t2][r] + frb1[n]);
          s0 += g * frW2[n];
          s1 += g * frW2[128 + n];
        }
        #pragma unroll
        for (int d = 1; d < 16; d <<= 1){ s0 += __shfl_xor(s0, d); s1 += __shfl_xor(s1, d); }
        if (lm == 0){
          atomicAdd(&a0[16 * rt + 4 * quad + r], s0);
          atomicAdd(&a1[16 * rt + 4 * quad + r], s1);
        }
      }
    }
  }
  __syncthreads();
  if (t < 64){
    int e = e0 + t;
    out[e]          = am[t] + mvb2[0];
    out[EE + e]     = softplus_f(a0[t] + frb2[0]) + 1e-4f;
    out[2 * EE + e] = softplus_f(a1[t] + frb2[1]) + 1e-4f;
  }
}

// ---------------- value head ----------------
__global__ void k_pool(const float* __restrict__ h, const unsigned char* __restrict__ mask,
                       float* __restrict__ gsum, float* __restrict__ msum, float* __restrict__ mcnt){
  int bb = blockIdx.x, j = threadIdx.x;
  float ga = 0.0f, ma = 0.0f;
  int n0 = bb * 32;
  for (int i = 0; i < 32; i++){
    int n = n0 + i;
    float v = h[n * HH + j];
    ga += v;
    if (mask[n]) ma += v;
  }
  atomicAdd(&gsum[j], ga);
  atomicAdd(&msum[j], ma);
  if (j == 0){
    float c = 0.0f;
    for (int i = 0; i < 32; i++) c += mask[n0 + i] ? 1.0f : 0.0f;
    atomicAdd(mcnt, c);
  }
}

__global__ void k_value(const float* __restrict__ gsum, const float* __restrict__ msum,
                        const float* __restrict__ mcnt,
                        const float* __restrict__ W1, const float* __restrict__ b1,
                        const float* __restrict__ W2, const float* __restrict__ b2,
                        float* __restrict__ out_val){
  __shared__ float red[128];
  __shared__ float vin[256];
  int j = threadIdx.x;
  float gp = gsum[j] * (1.0f / NN);
  float as = msum[j] * (1.0f / NN);
  float ac = fmaxf(mcnt[0] * (1.0f / NN), 1e-6f);
  vin[j] = gp; vin[HH + j] = as / ac;
  __syncthreads();
  float acc = b1[j];
  const float* w = &W1[j * 256];
  #pragma unroll 4
  for (int k = 0; k < 256; k++) acc += vin[k] * w[k];
  float hv = gelu_f(acc) * W2[j];
  float s = block_sum128(hv, red);
  if (j == 0) out_val[0] = s + b2[0];
}

extern "C" void kernel_launch(void* const* d_in, const int* in_sizes, int n_in,
                              void* d_out, int out_size, void* d_ws, size_t ws_size,
                              hipStream_t stream){
  (void)in_sizes; (void)n_in; (void)out_size; (void)ws_size;
  const float* x        = (const float*)d_in[0];
  const int*   ei       = (const int*)d_in[1];
  const float* ea       = (const float*)d_in[2];
  const float* u        = (const float*)d_in[3];
  const unsigned char* mask = (const unsigned char*)d_in[4];
  const float* tiles    = (const float*)d_in[5];
  const float* tf       = (const float*)d_in[7];
  const float* ne_W  = (const float*)d_in[8];
  const float* ne_b  = (const float*)d_in[9];
  const float* ne_g  = (const float*)d_in[10];
  const float* ne_be = (const float*)d_in[11];
  const float* ge_W  = (const float*)d_in[12];
  const float* ge_b  = (const float*)d_in[13];
  const float* ge_g  = (const float*)d_in[14];
  const float* ge_be = (const float*)d_in[15];
  const float* gru_Wih = (const float*)d_in[16];
  const float* gru_bih = (const float*)d_in[17];
  const float* gru_Whh = (const float*)d_in[18];
  const float* gru_bhh = (const float*)d_in[19];
  const float* gat_Wl  = (const float*)d_in[20];
  const float* gat_bl  = (const float*)d_in[21];
  const float* gat_Wr  = (const float*)d_in[22];
  const float* gat_br  = (const float*)d_in[23];
  const float* gat_We  = (const float*)d_in[24];
  const float* gat_att = (const float*)d_in[25];
  const float* gat_bias= (const float*)d_in[26];
  const float* ln_g    = (const float*)d_in[27];
  const float* ln_b    = (const float*)d_in[28];
  const float* attn_Win = (const float*)d_in[29];
  const float* attn_bin = (const float*)d_in[30];
  const float* attn_Wout= (const float*)d_in[31];
  const float* attn_bout= (const float*)d_in[32];
  const float* lng_g    = (const float*)d_in[33];
  const float* lng_b    = (const float*)d_in[34];
  const float* mv_W1 = (const float*)d_in[35];
  const float* mv_b1 = (const float*)d_in[36];
  const float* mv_W2 = (const float*)d_in[37];
  const float* mv_b2 = (const float*)d_in[38];
  const float* fr_W1 = (const float*)d_in[39];
  const float* fr_b1 = (const float*)d_in[40];
  const float* fr_W2 = (const float*)d_in[41];
  const float* fr_b2 = (const float*)d_in[42];
  const float* vl_W1 = (const float*)d_in[43];
  const float* vl_b1 = (const float*)d_in[44];
  const float* vl_W2 = (const float*)d_in[45];
  const float* vl_b2 = (const float*)d_in[46];

  // ---- workspace layout (f32 elem offsets) ----
  float* ws = (float*)d_ws;
  float* h      = ws;                         // 524288
  float* xlr    = ws + 524288;                // region reused: GAT xlrb/den, attn qb/kb/vt
  unsigned short* hb     = (unsigned short*)(ws + 1572864);
  unsigned short* tilesb = (unsigned short*)(ws + 1835008);
  unsigned short* wbuf   = (unsigned short*)(ws + 2097152);
  unsigned short* Wihb  = wbuf;
  unsigned short* Whhb  = wbuf + 49152;
  unsigned short* Wlrb  = wbuf + 98304;
  unsigned short* Winb  = wbuf + 229376;
  unsigned short* Woutb = wbuf + 278528;
  float* blrc   = ws + 2244608;
  float* gsum   = ws + 2245760;
  float* msum   = ws + 2245888;
  float* mcnt   = ws + 2246016;
  int*   cnt    = (int*)(ws + 2246032);
  int*   off    = cnt + NN;                   // NN+1
  int*   cur    = off + NN + 1;               // NN
  unsigned short* eab = (unsigned short*)(ws + 2323904);
  unsigned short* wbE = (unsigned short*)(ws + 2454976);
  float* S      = ws + 2492864;               // 3145728 scratch (multi-phase)
  // GRU phase:
  float* gi = S;
  float* gh = S + 1572864;
  // GAT phase (S dead after gru_comb):
  float* exs = S;                                         // EE*4 f32 CSR-ordered
  int*   srcs = (int*)(S + 262144);                       // EE
  int*   rank = (int*)(S + 327680);                       // EE
  // GAT phase (xlr region):
  unsigned short* xlrb = (unsigned short*)xlr;            // NN*256 bf16
  float* den = xlr + 524288;                              // NN*4
  // attn phase:
  unsigned short* qb = (unsigned short*)xlr;
  unsigned short* kb = (unsigned short*)(xlr + 262144);
  unsigned short* vt = (unsigned short*)(xlr + 524288 + 16384);
  float* pacc = S;                                        // NN*4*KS*32 f32
  float* pden = S + 2097152;                              // NN*4*KS

  float* out       = (float*)d_out;
  float* out_val   = out + 3 * EE;
  float* out_tiles = out + 3 * EE + 1;

  // one-shot bf16 prep + zero-init
  k_wprep<<<(1162497 + 255) / 256, 256, 0, stream>>>(gru_Wih, gru_Whh, gat_Wl, gat_Wr,
                                                     attn_Win, attn_Wout, tiles,
                                                     gat_bl, gat_br, ea, mv_W1, fr_W1,
                                                     wbuf, tilesb, blrc, wbE, eab,
                                                     cnt, gsum);

  // encoders
  k_node_enc<<<NN, 128, 0, stream>>>(x, tf, ne_W, ne_b, ne_g, ne_be,
                                     u, ge_W, ge_b, ge_g, ge_be, h, hb);

  // GRU via MFMA (both projections in one launch)
  { dim3 g(NN / 64, 3, 2);
    k_gru_lin<<<g, 256, 0, stream>>>(hb, tilesb, Wihb, Whhb, gru_bih, gru_bhh, gi, gh); }
  k_gru_comb<<<NN * HH / 256, 256, 0, stream>>>(gi, gh, tiles, h, hb, out_tiles);

  // CSR of incoming edges (after GRU so srcs/rank can live in S)
  k_hist   <<<EE / 256, 256, 0, stream>>>(ei, cnt);
  k_scan   <<<1, 256, 0, stream>>>(cnt, off, cur);
  k_scatter<<<EE / 256, 256, 0, stream>>>(ei, cur, srcs, rank);

  // GATv2 stack
  for (int l = 0; l < NLAYERS; l++){
    { dim3 g(NN / 64, 2);
      k_lin_gat<<<g, 256, 0, stream>>>(hb, Wlrb + l * 32768, blrc + l * 256, xlrb, den); }
    k_score<<<EE / 16, 256, 0, stream>>>(ei, ea, xlrb,
                                         gat_We + l * HH * EFEAT,
                                         gat_att + l * NHEADS * HDIM, rank, exs, den);
    k_aggln<<<NN, 128, 0, stream>>>(xlrb, exs, den, off, srcs,
                                    gat_bias + l * HH, ln_g + l * HH, ln_b + l * HH, h, hb);
  }

  // global attention (QKV transpose fused into GEMM epilogue)
  { dim3 g(NN / 64, 3);
    k_lin_qkv<<<g, 256, 0, stream>>>(hb, Winb, attn_bin, qb, kb, vt); }
  { dim3 gattn(NN / 64, NHEADS, KS);
    k_attn_flash<<<gattn, 256, 0, stream>>>(qb, kb, vt, pden, pacc); }
  k_attn_out<<<NN / 64, 256, 0, stream>>>(pden, pacc, Woutb, attn_bout, lng_g, lng_b, h, hb);

  // edge heads (bf16 MFMA, col-split waves)
  k_edge_mfma<<<EE / 64, 256, 0, stream>>>(hb, eab, ei, wbE, mv_b1, fr_b1,
                                           mv_W2, mv_b2, fr_W2, fr_b2, out);

  // value head
  k_pool <<<128, 128, 0, stream>>>(h, mask, gsum, msum, mcnt);
  k_value<<<1, 128, 0, stream>>>(gsum, msum, mcnt, vl_W1, vl_b1, vl_W2, vl_b2, out_val);
}

// Round 12
// 397.155 us; speedup vs baseline: 1.2710x; 1.0337x over previous
//
#include <hip/hip_runtime.h>
#include <math.h>

// StrategistGNN forward on MI355X. Round 12: unrolled+pipelined edge-head K-loop
// (launch_bounds(256,4)), streamlined exact-tanh-form gelu, pool fused into attn_out.
// N=4096 nodes, E=65536 edges, H=128, 4 heads x 32, L=4 GAT layers, B=1.

#define NN 4096
#define EE 65536
#define HH 128
#define NHEADS 4
#define HDIM 32
#define NLAYERS 4
#define NFEAT 16
#define GFEAT 8
#define EFEAT 4
#define KS 4     // key-splits for global attention
#define KPAD 296 // padded K stride (bf16) for edge-head GEMM
#define XSTR 136 // LDS row stride (bf16): 2-way bank aliasing only (free)
#define KSTR 40  // flash K-tile LDS row stride
#define VSTR 72  // flash V-tile LDS row stride

typedef short bf16x8 __attribute__((ext_vector_type(8)));
typedef float f32x4  __attribute__((ext_vector_type(4)));
union UB { uint4 u; bf16x8 v; };

__device__ __forceinline__ float gelu_f(float x){
  return 0.5f * x * (1.0f + erff(x * 0.7071067811865475f));
}
// tanh-approx GELU, sigmoid form: x*sigma(2u) == 0.5x(1+tanh(u)), u=0.79788(x+0.044715x^3).
// Identical values to the tanh form; no clamp needed (exp overflow -> x/inf -> 0, correct limit).
__device__ __forceinline__ float gelu_fast(float x){
  float u = x + 0.044715f * x * x * x;
  float t = __expf(-1.5957691216f * u);
  return x / (1.0f + t);
}
__device__ __forceinline__ float sigm_fast(float x){ return 1.0f / (1.0f + __expf(-x)); }
__device__ __forceinline__ float tanh_fast(float x){
  float t = __expf(-2.0f * fmaxf(x, -40.0f));
  return 1.0f - 2.0f * t / (1.0f + t);
}
__device__ __forceinline__ float softplus_f(float x){ return x > 20.0f ? x : log1pf(expf(x)); }
__device__ __forceinline__ unsigned short f2bf(float x){
  unsigned u = __float_as_uint(x);
  unsigned r = (u + 0x7FFFu + ((u >> 16) & 1u)) >> 16;
  return (unsigned short)r;
}
__device__ __forceinline__ float bf2f(unsigned short x){
  return __uint_as_float(((unsigned)x) << 16);
}
__device__ __forceinline__ unsigned pack2bf(float lo, float hi){
  unsigned a = (__float_as_uint(lo) + 0x8000u) >> 16;
  unsigned b = (__float_as_uint(hi) + 0x8000u) & 0xFFFF0000u;
  return a | b;
}

__device__ __forceinline__ float block_sum128(float v, float* red){
  int j = threadIdx.x;
  red[j] = v; __syncthreads();
  for (int s = 64; s > 0; s >>= 1){
    if (j < s) red[j] += red[j + s];
    __syncthreads();
  }
  float r = red[0];
  __syncthreads();
  return r;
}

// ---------------- CSR build ----------------
__global__ void k_hist(const int* __restrict__ ei, int* __restrict__ cnt){
  int e = blockIdx.x * 256 + threadIdx.x;
  if (e < EE) atomicAdd(&cnt[ei[EE + e]], 1);
}

__global__ void k_scan(const int* __restrict__ cnt, int* __restrict__ off, int* __restrict__ cur){
  __shared__ int part[256];
  int t = threadIdx.x;
  int local[16];
  int s = 0;
  #pragma unroll
  for (int i = 0; i < 16; i++){ local[i] = s; s += cnt[t * 16 + i]; }
  part[t] = s; __syncthreads();
  for (int o = 1; o < 256; o <<= 1){
    int v = (t >= o) ? part[t - o] : 0;
    __syncthreads();
    part[t] += v;
    __syncthreads();
  }
  int base = part[t] - s;
  #pragma unroll
  for (int i = 0; i < 16; i++){ int o = base + local[i]; off[t * 16 + i] = o; cur[t * 16 + i] = o; }
  if (t == 255) off[NN] = part[255];
}

__global__ void k_scatter(const int* __restrict__ ei, int* __restrict__ cur,
                          int* __restrict__ srcs, int* __restrict__ rank){
  int e = blockIdx.x * 256 + threadIdx.x;
  if (e < EE){
    int d = ei[EE + e];
    int p = atomicAdd(&cur[d], 1);
    srcs[p] = ei[e];
    rank[e] = p;
  }
}

// ---------------- one-shot prep ----------------
__global__ void k_wprep(const float* __restrict__ Wih, const float* __restrict__ Whh,
                        const float* __restrict__ Wl, const float* __restrict__ Wr,
                        const float* __restrict__ Win, const float* __restrict__ Wout,
                        const float* __restrict__ tiles,
                        const float* __restrict__ bl, const float* __restrict__ br,
                        const float* __restrict__ ea,
                        const float* __restrict__ mvW1, const float* __restrict__ frW1,
                        unsigned short* __restrict__ wbuf, unsigned short* __restrict__ tilesb,
                        float* __restrict__ blrc,
                        unsigned short* __restrict__ wbE, unsigned short* __restrict__ eab,
                        int* __restrict__ cnt, float* __restrict__ gsum){
  int i = blockIdx.x * 256 + threadIdx.x;
  if (i < 49152){ wbuf[i] = f2bf(Wih[i]); }
  else if (i < 98304){ int j = i - 49152; wbuf[49152 + j] = f2bf(Whh[j]); }
  else if (i < 229376){
    int j = i - 98304;
    int l = j >> 15, rem = j & 32767, m = rem >> 7, k = rem & 127;
    float v = (m < 128) ? Wl[l * 16384 + m * 128 + k] : Wr[l * 16384 + (m - 128) * 128 + k];
    wbuf[98304 + j] = f2bf(v);
  }
  else if (i < 278528){ int j = i - 229376; wbuf[229376 + j] = f2bf(Win[j]); }
  else if (i < 294912){ int j = i - 278528; wbuf[278528 + j] = f2bf(Wout[j]); }
  else if (i < 819200){ int j = i - 294912; tilesb[j] = f2bf(tiles[j]); }
  else if (i < 820224){
    int j = i - 819200;
    int l = j >> 8, m = j & 255;
    blrc[j] = (m < 128) ? bl[l * 128 + m] : br[l * 128 + m - 128];
  }
  else if (i < 896000){
    int j = i - 820224;
    int n = j / KPAD, k = j - n * KPAD;
    float v = 0.0f;
    if (k < 2 * HH + EFEAT) v = (n < HH) ? mvW1[n * (2 * HH + EFEAT) + k]
                                         : frW1[(n - HH) * (2 * HH + EFEAT) + k];
    wbE[j] = f2bf(v);
  }
  else if (i < 1158144){
    int j = i - 896000;
    eab[j] = f2bf(ea[j]);
  }
  else if (i < 1162240){ cnt[i - 1158144] = 0; }
  else if (i < 1162497){ gsum[i - 1162240] = 0.0f; }
}

// ---------------- shared GEMM core (64 rows x 128 cols, K=128) ----------------
__device__ __forceinline__ void gemm_core(const unsigned short* __restrict__ Xb, int n0,
                                          const unsigned short* __restrict__ Wb, int m0,
                                          unsigned short* Xs, f32x4 acc[8]){
  int t = threadIdx.x;
  #pragma unroll
  for (int k2 = 0; k2 < 4; k2++){
    int v = t + k2 * 256;
    int r = v >> 4, c8 = v & 15;
    *(uint4*)(Xs + r * XSTR + c8 * 8) = *(const uint4*)(Xb + (n0 + r) * 128 + c8 * 8);
  }
  __syncthreads();
  int ln = t & 63, w = t >> 6, lm = ln & 15, quad = ln >> 4;
  const unsigned short* abase = Xs + (16 * w + lm) * XSTR + quad * 8;
  const unsigned short* bbase = Wb + (m0 + lm) * 128 + quad * 8;
  UB af[4];
  #pragma unroll
  for (int ks = 0; ks < 4; ks++) af[ks].u = *(const uint4*)(abase + ks * 32);
  #pragma unroll
  for (int i = 0; i < 8; i++) acc[i] = (f32x4){0.f, 0.f, 0.f, 0.f};
  #pragma unroll
  for (int t2 = 0; t2 < 8; t2++){
    #pragma unroll
    for (int ks = 0; ks < 4; ks++){
      UB bu;
      bu.u = *(const uint4*)(bbase + t2 * 16 * 128 + ks * 32);
      acc[t2] = __builtin_amdgcn_mfma_f32_16x16x32_bf16(af[ks].v, bu.v, acc[t2], 0, 0, 0);
    }
  }
}

// GRU: both projections in one launch
__global__ __launch_bounds__(256) void k_gru_lin(const unsigned short* __restrict__ hb,
                                                 const unsigned short* __restrict__ tilesb,
                                                 const unsigned short* __restrict__ Wihb,
                                                 const unsigned short* __restrict__ Whhb,
                                                 const float* __restrict__ bih,
                                                 const float* __restrict__ bhh,
                                                 float* __restrict__ gi, float* __restrict__ gh){
  __shared__ __align__(16) unsigned short Xs[64 * XSTR];
  int z = blockIdx.z;
  const unsigned short* Xb = z ? tilesb : hb;
  const unsigned short* Wb = z ? Whhb : Wihb;
  const float* bias = z ? bhh : bih;
  float* Y = z ? gh : gi;
  int t = threadIdx.x;
  int n0 = blockIdx.x * 64, m0 = blockIdx.y * 128;
  f32x4 acc[8];
  gemm_core(Xb, n0, Wb, m0, Xs, acc);
  int ln = t & 63, w = t >> 6, lm = ln & 15, quad = ln >> 4;
  #pragma unroll
  for (int t2 = 0; t2 < 8; t2++){
    float bv = bias[m0 + t2 * 16 + lm];
    #pragma unroll
    for (int r = 0; r < 4; r++){
      Y[(n0 + 16 * w + quad * 4 + r) * 384 + m0 + t2 * 16 + lm] = acc[t2][r] + bv;
    }
  }
}

// GAT projection: bf16 out + den zeroing
__global__ __launch_bounds__(256) void k_lin_gat(const unsigned short* __restrict__ Xb,
                                                 const unsigned short* __restrict__ Wb,
                                                 const float* __restrict__ bias,
                                                 unsigned short* __restrict__ Y,
                                                 float* __restrict__ den){
  __shared__ __align__(16) unsigned short Xs[64 * XSTR];
  int t = threadIdx.x;
  int gid = (blockIdx.y * gridDim.x + blockIdx.x) * 256 + t;
  if (gid < NN * NHEADS) den[gid] = 0.0f;
  int n0 = blockIdx.x * 64, m0 = blockIdx.y * 128;
  f32x4 acc[8];
  gemm_core(Xb, n0, Wb, m0, Xs, acc);
  int ln = t & 63, w = t >> 6, lm = ln & 15, quad = ln >> 4;
  #pragma unroll
  for (int t2 = 0; t2 < 8; t2++){
    float bv = bias[m0 + t2 * 16 + lm];
    #pragma unroll
    for (int r = 0; r < 4; r++){
      Y[(n0 + 16 * w + quad * 4 + r) * 256 + m0 + t2 * 16 + lm] = f2bf(acc[t2][r] + bv);
    }
  }
}

// QKV projection with fused post
__global__ __launch_bounds__(256) void k_lin_qkv(const unsigned short* __restrict__ Xb,
                                                 const unsigned short* __restrict__ Wb,
                                                 const float* __restrict__ bias,
                                                 unsigned short* __restrict__ qb,
                                                 unsigned short* __restrict__ kb,
                                                 unsigned short* __restrict__ vt){
  __shared__ __align__(16) unsigned short Xs[64 * XSTR];
  int t = threadIdx.x;
  int n0 = blockIdx.x * 64, m0 = blockIdx.y * 128;
  f32x4 acc[8];
  gemm_core(Xb, n0, Wb, m0, Xs, acc);
  int ln = t & 63, w = t >> 6, lm = ln & 15, quad = ln >> 4;
  int nb = n0 + 16 * w + quad * 4;
  const float scale = 0.17677669529663687f;
  if (blockIdx.y == 0){
    #pragma unroll
    for (int t2 = 0; t2 < 8; t2++){
      int m = t2 * 16 + lm;
      float bv = bias[m];
      #pragma unroll
      for (int r = 0; r < 4; r++) qb[(nb + r) * HH + m] = f2bf(acc[t2][r] + bv);
    }
  } else if (blockIdx.y == 1){
    #pragma unroll
    for (int t2 = 0; t2 < 8; t2++){
      int m = t2 * 16 + lm;
      float bv = bias[128 + m];
      #pragma unroll
      for (int r = 0; r < 4; r++) kb[(nb + r) * HH + m] = f2bf((acc[t2][r] + bv) * scale);
    }
  } else {
    #pragma unroll
    for (int t2 = 0; t2 < 8; t2++){
      int m = t2 * 16 + lm;
      float bv = bias[256 + m];
      uint2 p;
      p.x = pack2bf(acc[t2][0] + bv, acc[t2][1] + bv);
      p.y = pack2bf(acc[t2][2] + bv, acc[t2][3] + bv);
      *(uint2*)(vt + m * NN + nb) = p;
    }
  }
}

// ---------------- node encoder (global encoder folded in) ----------------
__global__ void k_node_enc(const float* __restrict__ x, const float* __restrict__ tf,
                           const float* __restrict__ W, const float* __restrict__ b,
                           const float* __restrict__ g, const float* __restrict__ be,
                           const float* __restrict__ u, const float* __restrict__ geW,
                           const float* __restrict__ geb, const float* __restrict__ geg,
                           const float* __restrict__ gebe,
                           float* __restrict__ h, unsigned short* __restrict__ hb){
  __shared__ float red[128];
  __shared__ float xs[NFEAT + 1];
  __shared__ float us[GFEAT];
  int n = blockIdx.x, j = threadIdx.x;
  if (j < NFEAT) xs[j] = x[n * NFEAT + j];
  if (j == NFEAT) xs[NFEAT] = tf[0];
  if (j >= 32 && j < 32 + GFEAT) us[j - 32] = u[j - 32];
  __syncthreads();
  float ua = geb[j];
  #pragma unroll
  for (int k = 0; k < GFEAT; k++) ua += us[k] * geW[j * GFEAT + k];
  float umu = block_sum128(ua, red) * (1.0f / HH);
  float ud = ua - umu;
  float uvar = block_sum128(ud * ud, red) * (1.0f / HH);
  float uej = gelu_f(ud * rsqrtf(uvar + 1e-5f) * geg[j] + gebe[j]);
  float acc = b[j];
  #pragma unroll
  for (int k = 0; k < NFEAT + 1; k++) acc += xs[k] * W[j * (NFEAT + 1) + k];
  float mu = block_sum128(acc, red) * (1.0f / HH);
  float d = acc - mu;
  float var = block_sum128(d * d, red) * (1.0f / HH);
  float r = gelu_f(d * rsqrtf(var + 1e-5f) * g[j] + be[j]) + uej;
  h[n * HH + j] = r;
  hb[n * HH + j] = f2bf(r);
}

// ---------------- GRU combine ----------------
__global__ void k_gru_comb(const float* __restrict__ gi, const float* __restrict__ gh,
                           const float* __restrict__ tiles, float* __restrict__ h,
                           unsigned short* __restrict__ hb, float* __restrict__ out_tiles){
  int idx = blockIdx.x * 256 + threadIdx.x;
  int n = idx >> 7, j = idx & 127;
  float ir = gi[n * 384 + j], iz = gi[n * 384 + 128 + j], inn = gi[n * 384 + 256 + j];
  float hr = gh[n * 384 + j], hz = gh[n * 384 + 128 + j], hn = gh[n * 384 + 256 + j];
  float r = sigm_fast(ir + hr), z = sigm_fast(iz + hz);
  float nn2 = tanh_fast(inn + r * hn);
  float ts = tiles[idx];
  float hnew = (1.0f - z) * nn2 + z * ts;
  h[idx] = hnew;
  hb[idx] = f2bf(hnew);
  out_tiles[idx] = hnew;
}

// ---------------- GAT score ----------------
__global__ __launch_bounds__(256) void k_score(const int* __restrict__ ei, const float* __restrict__ ea,
                        const unsigned short* __restrict__ xlrb,
                        const float* __restrict__ We, const float* __restrict__ att,
                        const int* __restrict__ rank,
                        float* __restrict__ exs, float* __restrict__ den){
  __shared__ float4 We4[128];
  __shared__ float atts[128];
  int t = threadIdx.x;
  if (t < 128){ We4[t] = ((const float4*)We)[t]; atts[t] = att[t]; }
  __syncthreads();
  int el = t >> 4, g = t & 15;
  int e = blockIdx.x * 16 + el;
  int s = ei[e], d = ei[EE + e];
  float4 a = *(const float4*)(ea + e * 4);
  UB xlu, xru;
  xlu.u = *(const uint4*)(xlrb + s * 256 + g * 8);
  xru.u = *(const uint4*)(xlrb + d * 256 + 128 + g * 8);
  float sc = 0.0f;
  #pragma unroll
  for (int i = 0; i < 8; i++){
    int j = g * 8 + i;
    float4 w = We4[j];
    float v = bf2f((unsigned short)xlu.v[i]) + bf2f((unsigned short)xru.v[i])
            + a.x * w.x + a.y * w.y + a.z * w.z + a.w * w.w;
    v = v > 0.0f ? v : 0.2f * v;
    sc += v * atts[j];
  }
  sc += __shfl_xor(sc, 1);
  sc += __shfl_xor(sc, 2);
  if ((g & 3) == 0){
    float ev = __expf(sc);
    exs[rank[e] * 4 + (g >> 2)] = ev;
    atomicAdd(&den[d * 4 + (g >> 2)], ev);
  }
}

// ---------------- aggregate + residual + LN ----------------
__global__ void k_aggln(const unsigned short* __restrict__ xlrb, const float* __restrict__ exs,
                        const float* __restrict__ den,
                        const int* __restrict__ off, const int* __restrict__ srcs,
                        const float* __restrict__ bias, const float* __restrict__ g,
                        const float* __restrict__ b, float* __restrict__ h,
                        unsigned short* __restrict__ hb){
  __shared__ float red[128];
  int n = blockIdx.x, j = threadIdx.x;
  int p0 = off[n], p1 = off[n + 1];
  int hh = j >> 5;
  float dinv = 1.0f / (den[n * 4 + hh] + 1e-16f);
  float agg = 0.0f;
  int p = p0;
  for (; p + 4 <= p1; p += 4){
    int s0 = srcs[p], s1 = srcs[p + 1], s2 = srcs[p + 2], s3 = srcs[p + 3];
    float w0 = exs[p * 4 + hh],       w1 = exs[(p + 1) * 4 + hh];
    float w2 = exs[(p + 2) * 4 + hh], w3 = exs[(p + 3) * 4 + hh];
    float x0 = bf2f(xlrb[s0 * 256 + j]);
    float x1 = bf2f(xlrb[s1 * 256 + j]);
    float x2 = bf2f(xlrb[s2 * 256 + j]);
    float x3 = bf2f(xlrb[s3 * 256 + j]);
    agg += w0 * x0 + w1 * x1 + w2 * x2 + w3 * x3;
  }
  for (; p < p1; p++){
    agg += exs[p * 4 + hh] * bf2f(xlrb[srcs[p] * 256 + j]);
  }
  agg *= dinv;
  float val = h[n * HH + j] + agg + bias[j];
  float mu = block_sum128(val, red) * (1.0f / HH);
  float d2 = val - mu;
  float var = block_sum128(d2 * d2, red) * (1.0f / HH);
  float r = d2 * rsqrtf(var + 1e-5f) * g[j] + b[j];
  h[n * HH + j] = r;
  hb[n * HH + j] = f2bf(r);
}

// ---------------- flash attention (block-cooperative double-buffered LDS) ----------------
__global__ __launch_bounds__(256, 4) void k_attn_flash(
    const unsigned short* __restrict__ qb, const unsigned short* __restrict__ kb,
    const unsigned short* __restrict__ vt,
    float* __restrict__ pden, float* __restrict__ pacc){
  __shared__ __align__(16) unsigned short Kls[2][64 * KSTR];
  __shared__ __align__(16) unsigned short Vls[2][32 * VSTR];
  int t = threadIdx.x, w = t >> 6, ln = t & 63;
  int c = ln & 15, qd = ln >> 4;
  int hh = blockIdx.y, ks = blockIdx.z;
  int q0 = blockIdx.x * 64 + w * 16;
  UB qf; qf.u = *(const uint4*)(qb + (q0 + c) * HH + hh * HDIM + qd * 8);
  f32x4 o0a = {0,0,0,0}, o1a = {0,0,0,0}, o0b = {0,0,0,0}, o1b = {0,0,0,0};
  float denp = 0.f;
  int srcA = c + ((qd & 1) << 5);
  int srcB = srcA + 16;
  bool hi = qd >= 2;
  int kk = t >> 2, kp = t & 3;
  int vr = t >> 3, vc = t & 7;
  const unsigned short* kg = kb + hh * HDIM + kp * 8;
  const unsigned short* vg = vt + (hh * HDIM + vr) * NN + vc * 8;

  auto comp = [&](int buf, int hs, f32x4& O0, f32x4& O1){
    UB kf0, kf1, vf0, vf1, pt;
    kf0.u = *(const uint4*)(&Kls[buf][(hs * 32 + c) * KSTR + qd * 8]);
    kf1.u = *(const uint4*)(&Kls[buf][(hs * 32 + 16 + c) * KSTR + qd * 8]);
    vf0.u = *(const uint4*)(&Vls[buf][c * VSTR + hs * 32 + qd * 8]);
    vf1.u = *(const uint4*)(&Vls[buf][(16 + c) * VSTR + hs * 32 + qd * 8]);
    f32x4 s0 = {0,0,0,0}, s1 = {0,0,0,0};
    s0 = __builtin_amdgcn_mfma_f32_16x16x32_bf16(kf0.v, qf.v, s0, 0, 0, 0);
    s1 = __builtin_amdgcn_mfma_f32_16x16x32_bf16(kf1.v, qf.v, s1, 0, 0, 0);
    float e00 = __expf(s0[0]), e01 = __expf(s0[1]), e02 = __expf(s0[2]), e03 = __expf(s0[3]);
    float e10 = __expf(s1[0]), e11 = __expf(s1[1]), e12 = __expf(s1[2]), e13 = __expf(s1[3]);
    denp += (e00 + e01) + (e02 + e03) + (e10 + e11) + (e12 + e13);
    int p00 = (int)pack2bf(e00, e01), p01 = (int)pack2bf(e02, e03);
    int p10 = (int)pack2bf(e10, e11), p11 = (int)pack2bf(e12, e13);
    int a00 = __shfl(p00, srcA), a01 = __shfl(p01, srcA);
    int b00 = __shfl(p00, srcB), b01 = __shfl(p01, srcB);
    int a10 = __shfl(p10, srcA), a11 = __shfl(p11, srcA);
    int b10 = __shfl(p10, srcB), b11 = __shfl(p11, srcB);
    pt.u.x = (unsigned)(hi ? a10 : a00);
    pt.u.y = (unsigned)(hi ? a11 : a01);
    pt.u.z = (unsigned)(hi ? b10 : b00);
    pt.u.w = (unsigned)(hi ? b11 : b01);
    O0 = __builtin_amdgcn_mfma_f32_16x16x32_bf16(vf0.v, pt.v, O0, 0, 0, 0);
    O1 = __builtin_amdgcn_mfma_f32_16x16x32_bf16(vf1.v, pt.v, O1, 0, 0, 0);
  };

  const int kbeg = ks * (NN / KS);
  const int NIT = (NN / KS) / 64;   // 16
  {
    uint4 kr = *(const uint4*)(kg + (kbeg + kk) * HH);
    uint4 vr4 = *(const uint4*)(vg + kbeg);
    *(uint4*)(&Kls[0][kk * KSTR + kp * 8]) = kr;
    *(uint4*)(&Vls[0][vr * VSTR + vc * 8]) = vr4;
  }
  __syncthreads();
  for (int it = 0; it < NIT; it++){
    int buf = it & 1;
    if (it + 1 < NIT){
      int kn = kbeg + (it + 1) * 64;
      uint4 kr = *(const uint4*)(kg + (kn + kk) * HH);
      uint4 vr4 = *(const uint4*)(vg + kn);
      comp(buf, 0, o0a, o1a);
      comp(buf, 1, o0b, o1b);
      *(uint4*)(&Kls[buf ^ 1][kk * KSTR + kp * 8]) = kr;
      *(uint4*)(&Vls[buf ^ 1][vr * VSTR + vc * 8]) = vr4;
    } else {
      comp(buf, 0, o0a, o1a);
      comp(buf, 1, o0b, o1b);
    }
    __syncthreads();
  }

  f32x4 o0 = o0a + o0b, o1 = o1a + o1b;
  denp += __shfl_xor(denp, 16);
  denp += __shfl_xor(denp, 32);
  int pi = ((q0 + c) * NHEADS + hh) * KS + ks;
  if (qd == 0) pden[pi] = denp;
  #pragma unroll
  for (int r = 0; r < 4; r++){
    pacc[pi * HDIM + qd * 4 + r]      = o0[r];
    pacc[pi * HDIM + 16 + qd * 4 + r] = o1[r];
  }
}

// fused: combine partials -> MFMA proj -> residual+LN -> h,hb + value-head pooling
__global__ __launch_bounds__(256) void k_attn_out(
    const float* __restrict__ pden, const float* __restrict__ pacc,
    const unsigned short* __restrict__ Wb, const float* __restrict__ bout,
    const float* __restrict__ g, const float* __restrict__ b,
    const unsigned char* __restrict__ mask,
    float* __restrict__ h, unsigned short* __restrict__ hb,
    float* __restrict__ gsum, float* __restrict__ msum, float* __restrict__ mcnt){
  __shared__ __align__(16) unsigned short Xs[64 * XSTR];
  __shared__ float colg[128], colm[128], colc;
  int t = threadIdx.x;
  int n0 = blockIdx.x * 64;
  if (t < 128){ colg[t] = 0.f; colm[t] = 0.f; }
  if (t == 128) colc = 0.f;
  for (int idx = t; idx < 64 * 128; idx += 256){
    int r = idx >> 7, j = idx & 127;
    int n = n0 + r, hh = j >> 5, d = j & 31;
    float ds = 0.f, as = 0.f;
    #pragma unroll
    for (int ks2 = 0; ks2 < KS; ks2++){
      int pi = (n * NHEADS + hh) * KS + ks2;
      ds += pden[pi];
      as += pacc[pi * HDIM + d];
    }
    Xs[r * XSTR + j] = f2bf(as / ds);
  }
  __syncthreads();
  int ln = t & 63, w = t >> 6, lm = ln & 15, quad = ln >> 4;
  const unsigned short* abase = Xs + (16 * w + lm) * XSTR + quad * 8;
  const unsigned short* bbase = Wb + lm * 128 + quad * 8;
  UB af[4];
  #pragma unroll
  for (int ks2 = 0; ks2 < 4; ks2++) af[ks2].u = *(const uint4*)(abase + ks2 * 32);
  f32x4 acc[8];
  #pragma unroll
  for (int i = 0; i < 8; i++) acc[i] = (f32x4){0.f, 0.f, 0.f, 0.f};
  #pragma unroll
  for (int t2 = 0; t2 < 8; t2++){
    #pragma unroll
    for (int ks2 = 0; ks2 < 4; ks2++){
      UB bu;
      bu.u = *(const uint4*)(bbase + t2 * 16 * 128 + ks2 * 32);
      acc[t2] = __builtin_amdgcn_mfma_f32_16x16x32_bf16(af[ks2].v, bu.v, acc[t2], 0, 0, 0);
    }
  }
  int nb = n0 + 16 * w + quad * 4;
  float val[8][4];
  #pragma unroll
  for (int t2 = 0; t2 < 8; t2++){
    int m = t2 * 16 + lm;
    float bv = bout[m];
    #pragma unroll
    for (int r = 0; r < 4; r++)
      val[t2][r] = acc[t2][r] + bv + h[(nb + r) * HH + m];
  }
  float mu[4], rs[4];
  #pragma unroll
  for (int r = 0; r < 4; r++){
    float s = 0.f;
    #pragma unroll
    for (int t2 = 0; t2 < 8; t2++) s += val[t2][r];
    s += __shfl_xor(s, 1); s += __shfl_xor(s, 2);
    s += __shfl_xor(s, 4); s += __shfl_xor(s, 8);
    mu[r] = s * (1.0f / HH);
  }
  #pragma unroll
  for (int r = 0; r < 4; r++){
    float s = 0.f;
    #pragma unroll
    for (int t2 = 0; t2 < 8; t2++){ float d2 = val[t2][r] - mu[r]; s += d2 * d2; }
    s += __shfl_xor(s, 1); s += __shfl_xor(s, 2);
    s += __shfl_xor(s, 4); s += __shfl_xor(s, 8);
    rs[r] = rsqrtf(s * (1.0f / HH) + 1e-5f);
  }
  // mask weights for the 4 rows this lane owns
  uchar4 mk = *(const uchar4*)(mask + nb);
  float mkf[4] = { mk.x ? 1.f : 0.f, mk.y ? 1.f : 0.f, mk.z ? 1.f : 0.f, mk.w ? 1.f : 0.f };
  #pragma unroll
  for (int t2 = 0; t2 < 8; t2++){
    int m = t2 * 16 + lm;
    float gm = g[m], bm = b[m];
    float sg = 0.f, sm = 0.f;
    #pragma unroll
    for (int r = 0; r < 4; r++){
      float o = (val[t2][r] - mu[r]) * rs[r] * gm + bm;
      h[(nb + r) * HH + m] = o;
      hb[(nb + r) * HH + m] = f2bf(o);
      sg += o;
      sm += mkf[r] * o;
    }
    // reduce across quads (lanes differing in bits 4-5 share column m)
    sg += __shfl_xor(sg, 16); sg += __shfl_xor(sg, 32);
    sm += __shfl_xor(sm, 16); sm += __shfl_xor(sm, 32);
    if (quad == 0){
      atomicAdd(&colg[m], sg);
      atomicAdd(&colm[m], sm);
    }
  }
  if (lm == 0){
    float c = mkf[0] + mkf[1] + mkf[2] + mkf[3];
    atomicAdd(&colc, c);
  }
  __syncthreads();
  if (t < 128){
    atomicAdd(&gsum[t], colg[t]);
    atomicAdd(&msum[t], colm[t]);
  }
  if (t == 128) atomicAdd(mcnt, colc);
}

// ---------------- edge heads via MFMA (col-split waves, unrolled K-loop) ----------------
__global__ __launch_bounds__(256, 4) void k_edge_mfma(
    const unsigned short* __restrict__ hb, const unsigned short* __restrict__ eab,
    const int* __restrict__ ei, const unsigned short* __restrict__ wb,
    const float* __restrict__ mvb1, const float* __restrict__ frb1,
    const float* __restrict__ mvW2, const float* __restrict__ mvb2,
    const float* __restrict__ frW2, const float* __restrict__ frb2,
    float* __restrict__ out){
  __shared__ __align__(16) unsigned short As[64 * KPAD];
  __shared__ float am[64], a0[64], a1[64];
  int t = threadIdx.x;
  int e0 = blockIdx.x * 64;
  if (t < 64){ am[t] = 0.f; a0[t] = 0.f; a1[t] = 0.f; }
  {
    int el = t >> 2, p = t & 3;
    int e = e0 + el;
    int node = (p < 2) ? ei[e] : ei[EE + e];
    int half = p & 1;
    const uint4* srcp = (const uint4*)(hb + node * HH + half * 64);
    uint4* dstp = (uint4*)(As + el * KPAD + (p >> 1) * 128 + half * 64);
    #pragma unroll
    for (int i = 0; i < 8; i++) dstp[i] = srcp[i];
    if (p == 0){
      unsigned short* tail = As + el * KPAD + 256;
      tail[0] = eab[e * 4];     tail[1] = eab[e * 4 + 1];
      tail[2] = eab[e * 4 + 2]; tail[3] = eab[e * 4 + 3];
      #pragma unroll
      for (int i = 4; i < KPAD - 256; i++) tail[i] = 0;
    }
  }
  int ln = t & 63, w = t >> 6, lm = ln & 15, quad = ln >> 4;
  const unsigned short* bbase = wb + (w * 64 + lm) * KPAD + quad * 8;
  f32x4 acc[4][4];
  #pragma unroll
  for (int rt = 0; rt < 4; rt++)
    #pragma unroll
    for (int t2 = 0; t2 < 4; t2++) acc[rt][t2] = (f32x4){0.f, 0.f, 0.f, 0.f};
  __syncthreads();
  #pragma unroll
  for (int ks = 0; ks < 9; ks++){
    UB bf[4], af[4];
    #pragma unroll
    for (int t2 = 0; t2 < 4; t2++) bf[t2].u = *(const uint4*)(bbase + t2 * 16 * KPAD + ks * 32);
    #pragma unroll
    for (int rt = 0; rt < 4; rt++) af[rt].u = *(const uint4*)(As + (16 * rt + lm) * KPAD + quad * 8 + ks * 32);
    #pragma unroll
    for (int rt = 0; rt < 4; rt++)
      #pragma unroll
      for (int t2 = 0; t2 < 4; t2++)
        acc[rt][t2] = __builtin_amdgcn_mfma_f32_16x16x32_bf16(af[rt].v, bf[t2].v, acc[rt][t2], 0, 0, 0);
  }
  if (w < 2){
    #pragma unroll
    for (int rt = 0; rt < 4; rt++){
      #pragma unroll
      for (int r = 0; r < 4; r++){
        float s = 0.f;
        #pragma unroll
        for (int t2 = 0; t2 < 4; t2++){
          int n = w * 64 + t2 * 16 + lm;
          s += gelu_fast(acc[rt][t2][r] + mvb1[n]) * mvW2[n];
        }
        #pragma unroll
        for (int d = 1; d < 16; d <<= 1) s += __shfl_xor(s, d);
        if (lm == 0) atomicAdd(&am[16 * rt + 4 * quad + r], s);
      }
    }
  } else {
    #pragma unroll
    for (int rt = 0; rt < 4; rt++){
      #pragma unroll
      for (int r = 0; r < 4; r++){
        float s0 = 0.f, s1 = 0.f;
        #pragma unroll
        for (int t2 = 0; t2 < 4; t2++){
          int n = (w - 2) * 64 + t2 * 16 + lm;
          float g = gelu_fast(acc[rt][t2][r] + frb1[n]);
          s0 += g * frW2[n];
          s1 += g * frW2[128 + n];
        }
        #pragma unroll
        for (int d = 1; d < 16; d <<= 1){ s0 += __shfl_xor(s0, d); s1 += __shfl_xor(s1, d); }
        if (lm == 0){
          atomicAdd(&a0[16 * rt + 4 * quad + r], s0);
          atomicAdd(&a1[16 * rt + 4 * quad + r], s1);
        }
      }
    }
  }
  __syncthreads();
  if (t < 64){
    int e = e0 + t;
    out[e]          = am[t] + mvb2[0];
    out[EE + e]     = softplus_f(a0[t] + frb2[0]) + 1e-4f;
    out[2 * EE + e] = softplus_f(a1[t] + frb2[1]) + 1e-4f;
  }
}

// ---------------- value head ----------------
__global__ void k_value(const float* __restrict__ gsum, const float* __restrict__ msum,
                        const float* __restrict__ mcnt,
                        const float* __restrict__ W1, const float* __restrict__ b1,
                        const float* __restrict__ W2, const float* __restrict__ b2,
                        float* __restrict__ out_val){
  __shared__ float red[128];
  __shared__ float vin[256];
  int j = threadIdx.x;
  float gp = gsum[j] * (1.0f / NN);
  float as = msum[j] * (1.0f / NN);
  float ac = fmaxf(mcnt[0] * (1.0f / NN), 1e-6f);
  vin[j] = gp; vin[HH + j] = as / ac;
  __syncthreads();
  float acc = b1[j];
  const float* w = &W1[j * 256];
  #pragma unroll 4
  for (int k = 0; k < 256; k++) acc += vin[k] * w[k];
  float hv = gelu_f(acc) * W2[j];
  float s = block_sum128(hv, red);
  if (j == 0) out_val[0] = s + b2[0];
}

extern "C" void kernel_launch(void* const* d_in, const int* in_sizes, int n_in,
                              void* d_out, int out_size, void* d_ws, size_t ws_size,
                              hipStream_t stream){
  (void)in_sizes; (void)n_in; (void)out_size; (void)ws_size;
  const float* x        = (const float*)d_in[0];
  const int*   ei       = (const int*)d_in[1];
  const float* ea       = (const float*)d_in[2];
  const float* u        = (const float*)d_in[3];
  const unsigned char* mask = (const unsigned char*)d_in[4];
  const float* tiles    = (const float*)d_in[5];
  const float* tf       = (const float*)d_in[7];
  const float* ne_W  = (const float*)d_in[8];
  const float* ne_b  = (const float*)d_in[9];
  const float* ne_g  = (const float*)d_in[10];
  const float* ne_be = (const float*)d_in[11];
  const float* ge_W  = (const float*)d_in[12];
  const float* ge_b  = (const float*)d_in[13];
  const float* ge_g  = (const float*)d_in[14];
  const float* ge_be = (const float*)d_in[15];
  const float* gru_Wih = (const float*)d_in[16];
  const float* gru_bih = (const float*)d_in[17];
  const float* gru_Whh = (const float*)d_in[18];
  const float* gru_bhh = (const float*)d_in[19];
  const float* gat_Wl  = (const float*)d_in[20];
  const float* gat_bl  = (const float*)d_in[21];
  const float* gat_Wr  = (const float*)d_in[22];
  const float* gat_br  = (const float*)d_in[23];
  const float* gat_We  = (const float*)d_in[24];
  const float* gat_att = (const float*)d_in[25];
  const float* gat_bias= (const float*)d_in[26];
  const float* ln_g    = (const float*)d_in[27];
  const float* ln_b    = (const float*)d_in[28];
  const float* attn_Win = (const float*)d_in[29];
  const float* attn_bin = (const float*)d_in[30];
  const float* attn_Wout= (const float*)d_in[31];
  const float* attn_bout= (const float*)d_in[32];
  const float* lng_g    = (const float*)d_in[33];
  const float* lng_b    = (const float*)d_in[34];
  const float* mv_W1 = (const float*)d_in[35];
  const float* mv_b1 = (const float*)d_in[36];
  const float* mv_W2 = (const float*)d_in[37];
  const float* mv_b2 = (const float*)d_in[38];
  const float* fr_W1 = (const float*)d_in[39];
  const float* fr_b1 = (const float*)d_in[40];
  const float* fr_W2 = (const float*)d_in[41];
  const float* fr_b2 = (const float*)d_in[42];
  const float* vl_W1 = (const float*)d_in[43];
  const float* vl_b1 = (const float*)d_in[44];
  const float* vl_W2 = (const float*)d_in[45];
  const float* vl_b2 = (const float*)d_in[46];

  // ---- workspace layout (f32 elem offsets) ----
  float* ws = (float*)d_ws;
  float* h      = ws;                         // 524288
  float* xlr    = ws + 524288;                // reused: GAT xlrb/den, attn qb/kb/vt
  unsigned short* hb     = (unsigned short*)(ws + 1572864);
  unsigned short* tilesb = (unsigned short*)(ws + 1835008);
  unsigned short* wbuf   = (unsigned short*)(ws + 2097152);
  unsigned short* Wihb  = wbuf;
  unsigned short* Whhb  = wbuf + 49152;
  unsigned short* Wlrb  = wbuf + 98304;
  unsigned short* Winb  = wbuf + 229376;
  unsigned short* Woutb = wbuf + 278528;
  float* blrc   = ws + 2244608;
  float* gsum   = ws + 2245760;
  float* msum   = ws + 2245888;
  float* mcnt   = ws + 2246016;
  int*   cnt    = (int*)(ws + 2246032);
  int*   off    = cnt + NN;
  int*   cur    = off + NN + 1;
  unsigned short* eab = (unsigned short*)(ws + 2323904);
  unsigned short* wbE = (unsigned short*)(ws + 2454976);
  float* S      = ws + 2492864;               // 3145728 scratch (multi-phase)
  float* gi = S;
  float* gh = S + 1572864;
  float* exs = S;                                         // EE*4 f32 CSR-ordered
  int*   srcs = (int*)(S + 262144);                       // EE
  int*   rank = (int*)(S + 327680);                       // EE
  unsigned short* xlrb = (unsigned short*)xlr;            // NN*256 bf16
  float* den = xlr + 524288;                              // NN*4
  unsigned short* qb = (unsigned short*)xlr;
  unsigned short* kb = (unsigned short*)(xlr + 262144);
  unsigned short* vt = (unsigned short*)(xlr + 524288 + 16384);
  float* pacc = S;                                        // NN*4*KS*32 f32
  float* pden = S + 2097152;                              // NN*4*KS

  float* out       = (float*)d_out;
  float* out_val   = out + 3 * EE;
  float* out_tiles = out + 3 * EE + 1;

  // one-shot bf16 prep + zero-init
  k_wprep<<<(1162497 + 255) / 256, 256, 0, stream>>>(gru_Wih, gru_Whh, gat_Wl, gat_Wr,
                                                     attn_Win, attn_Wout, tiles,
                                                     gat_bl, gat_br, ea, mv_W1, fr_W1,
                                                     wbuf, tilesb, blrc, wbE, eab,
                                                     cnt, gsum);

  // encoders
  k_node_enc<<<NN, 128, 0, stream>>>(x, tf, ne_W, ne_b, ne_g, ne_be,
                                     u, ge_W, ge_b, ge_g, ge_be, h, hb);

  // GRU via MFMA (both projections in one launch)
  { dim3 g(NN / 64, 3, 2);
    k_gru_lin<<<g, 256, 0, stream>>>(hb, tilesb, Wihb, Whhb, gru_bih, gru_bhh, gi, gh); }
  k_gru_comb<<<NN * HH / 256, 256, 0, stream>>>(gi, gh, tiles, h, hb, out_tiles);

  // CSR of incoming edges
  k_hist   <<<EE / 256, 256, 0, stream>>>(ei, cnt);
  k_scan   <<<1, 256, 0, stream>>>(cnt, off, cur);
  k_scatter<<<EE / 256, 256, 0, stream>>>(ei, cur, srcs, rank);

  // GATv2 stack
  for (int l = 0; l < NLAYERS; l++){
    { dim3 g(NN / 64, 2);
      k_lin_gat<<<g, 256, 0, stream>>>(hb, Wlrb + l * 32768, blrc + l * 256, xlrb, den); }
    k_score<<<EE / 16, 256, 0, stream>>>(ei, ea, xlrb,
                                         gat_We + l * HH * EFEAT,
                                         gat_att + l * NHEADS * HDIM, rank, exs, den);
    k_aggln<<<NN, 128, 0, stream>>>(xlrb, exs, den, off, srcs,
                                    gat_bias + l * HH, ln_g + l * HH, ln_b + l * HH, h, hb);
  }

  // global attention
  { dim3 g(NN / 64, 3);
    k_lin_qkv<<<g, 256, 0, stream>>>(hb, Winb, attn_bin, qb, kb, vt); }
  { dim3 gattn(NN / 64, NHEADS, KS);
    k_attn_flash<<<gattn, 256, 0, stream>>>(qb, kb, vt, pden, pacc); }
  k_attn_out<<<NN / 64, 256, 0, stream>>>(pden, pacc, Woutb, attn_bout, lng_g, lng_b,
                                          mask, h, hb, gsum, msum, mcnt);

  // edge heads (bf16 MFMA, col-split waves, unrolled K-loop)
  k_edge_mfma<<<EE / 64, 256, 0, stream>>>(hb, eab, ei, wbE, mv_b1, fr_b1,
                                           mv_W2, mv_b2, fr_W2, fr_b2, out);

  // value head
  k_value<<<1, 128, 0, stream>>>(gsum, msum, mcnt, vl_W1, vl_b1, vl_W2, vl_b2, out_val);
}